// Round 1
// 908.793 us; speedup vs baseline: 1.5940x; 1.5940x over previous
//
#include <hip/hip_runtime.h>
#include <hip/hip_bf16.h>
#include <math.h>
#include <stdint.h>

typedef unsigned short u16;
typedef __attribute__((ext_vector_type(8))) short short8;
typedef __attribute__((ext_vector_type(4))) float floatx4;

#define NB 8
#define P0 4608
#define C0 1024
#define H0 4096

// mode: 0 = inputs/outputs are float32, 1 = bf16
__global__ void detect_mode_kernel(const uint32_t* __restrict__ pe_words, int* __restrict__ mode) {
  *mode = (pe_words[64] != 0u) ? 1 : 0;
}

__device__ __forceinline__ float load_in(const void* p, size_t idx, int mode) {
  if (mode) return __bfloat162float(((const __hip_bfloat16*)p)[idx]);
  return ((const float*)p)[idx];
}

__device__ __forceinline__ float4 load4(const void* p, size_t idx, int mode) {
  float4 r;
  if (mode) {
    ushort4 u = *(const ushort4*)((const u16*)p + idx);
    r.x = __bfloat162float(*(__hip_bfloat16*)&u.x);
    r.y = __bfloat162float(*(__hip_bfloat16*)&u.y);
    r.z = __bfloat162float(*(__hip_bfloat16*)&u.z);
    r.w = __bfloat162float(*(__hip_bfloat16*)&u.w);
  } else {
    r = *(const float4*)((const float*)p + idx);
  }
  return r;
}

// ---------------- metric: mean over 16 heads of 64-dim chunks, L2 normalize ----------------
__global__ void metric_in_kernel(const void* __restrict__ x, const void* __restrict__ pos,
                                 const int* __restrict__ mode, float* __restrict__ m) {
  int tok = blockIdx.x * 4 + (threadIdx.x >> 6);
  int lane = threadIdx.x & 63;
  if (tok >= NB * P0) return;
  int b = tok / P0, t = tok - b * P0;
  int md = *mode;
  size_t xbase = ((size_t)b * P0 + t) * C0 + lane;
  size_t pbase = (size_t)t * C0 + lane;
  float s = 0.f;
#pragma unroll
  for (int h = 0; h < 16; ++h)
    s += load_in(x, xbase + h * 64, md) + load_in(pos, pbase + h * 64, md);
  s *= (1.f / 16.f);
  float sq = s * s;
#pragma unroll
  for (int off = 1; off < 64; off <<= 1) sq += __shfl_xor(sq, off, 64);
  m[(size_t)tok * 64 + lane] = s / sqrtf(sq);
}

__global__ void metric_f32_kernel(const float* __restrict__ x, float* __restrict__ m, int p) {
  int tok = blockIdx.x * 4 + (threadIdx.x >> 6);
  int lane = threadIdx.x & 63;
  if (tok >= NB * p) return;
  const float* xr = x + (size_t)tok * C0 + lane;
  float s = 0.f;
#pragma unroll
  for (int h = 0; h < 16; ++h) s += xr[h * 64];
  s *= (1.f / 16.f);
  float sq = s * s;
#pragma unroll
  for (int off = 1; off < 64; off <<= 1) sq += __shfl_xor(sq, off, 64);
  m[(size_t)tok * 64 + lane] = s / sqrtf(sq);
}

// ---------------- scores (fp32) + per-(row, j-block) argmax partials ----------------
__global__ __launch_bounds__(256) void score_kernel(const float* __restrict__ M_,
                                                    int p, int p2, int jT,
                                                    float* __restrict__ pm,
                                                    int* __restrict__ pi) {
  __shared__ __align__(16) float4 As[128 * 8];
  __shared__ __align__(16) float4 Bs[128 * 8];
  const int bi = blockIdx.x, ii = blockIdx.y, b = blockIdx.z;
  const int t = threadIdx.x;
  const float* Mb = M_ + (size_t)b * p * 64;
  const int ty = t >> 4, tx = t & 15;
  float s[8][8];
#pragma unroll
  for (int u = 0; u < 8; ++u)
#pragma unroll
    for (int v = 0; v < 8; ++v) s[u][v] = 0.f;

  const int d4 = t & 7, r0 = t >> 3;
  for (int stage = 0; stage < 2; ++stage) {
#pragma unroll
    for (int pass = 0; pass < 4; ++pass) {
      int row = r0 + pass * 32;
      int sw = (d4 + (row >> 3)) & 7;
      int ar = 2 * (ii * 128 + row);
      if (ar > p - 2) ar = p - 2;
      int br = 2 * (bi * 128 + row) + 1;
      if (br > p - 1) br = p - 1;
      As[row * 8 + sw] = *(const float4*)(Mb + (size_t)ar * 64 + stage * 32 + d4 * 4);
      Bs[row * 8 + sw] = *(const float4*)(Mb + (size_t)br * 64 + stage * 32 + d4 * 4);
    }
    __syncthreads();
    for (int k4 = 0; k4 < 8; ++k4) {
      float4 av[8], bv[8];
#pragma unroll
      for (int u = 0; u < 8; ++u) av[u] = As[(ty * 8 + u) * 8 + ((k4 + ty) & 7)];
#pragma unroll
      for (int v = 0; v < 8; ++v) bv[v] = Bs[(tx * 8 + v) * 8 + ((k4 + tx) & 7)];
#pragma unroll
      for (int u = 0; u < 8; ++u)
#pragma unroll
        for (int v = 0; v < 8; ++v) {
          s[u][v] += av[u].x * bv[v].x;
          s[u][v] += av[u].y * bv[v].y;
          s[u][v] += av[u].z * bv[v].z;
          s[u][v] += av[u].w * bv[v].w;
        }
    }
    __syncthreads();
  }

#pragma unroll
  for (int u = 0; u < 8; ++u) {
    int i = ii * 128 + ty * 8 + u;
    if (i >= p2) continue;
    float bm = -INFINITY;
    int bj = 0x7fffffff;
#pragma unroll
    for (int v = 0; v < 8; ++v) {
      int j = bi * 128 + tx * 8 + v;
      if (j < p2 && s[u][v] > bm) { bm = s[u][v]; bj = j; }
    }
#pragma unroll
    for (int mk = 1; mk < 16; mk <<= 1) {
      float om = __shfl_xor(bm, mk, 64);
      int oj = __shfl_xor(bj, mk, 64);
      if (om > bm || (om == bm && oj < bj)) { bm = om; bj = oj; }
    }
    if (tx == 0) {
      size_t o = ((size_t)b * 2304 + i) * jT + bi;
      pm[o] = bm;
      pi[o] = bj;
    }
  }
}

// argmax combine + build per-destination linked list (head[dst] -> chain via nxt[src])
__global__ void argmax_combine_kernel(const float* __restrict__ pm, const int* __restrict__ pi,
                                      int p2, int jT, float* __restrict__ nmax,
                                      int* __restrict__ nidx, int* __restrict__ head,
                                      int* __restrict__ nxt) {
  int g = blockIdx.x * 256 + threadIdx.x;
  if (g >= NB * p2) return;
  int b = g / p2, i = g - b * p2;
  const float* r = pm + ((size_t)b * 2304 + i) * jT;
  const int* ri = pi + ((size_t)b * 2304 + i) * jT;
  float best = r[0];
  int bidx = ri[0];
  for (int k = 1; k < jT; ++k) {
    if (r[k] > best || (r[k] == best && ri[k] < bidx)) { best = r[k]; bidx = ri[k]; }
  }
  nmax[g] = best;
  nidx[g] = bidx;
  int d = bidx;
  if ((unsigned)d >= (unsigned)p2) d = 0;
  nxt[g] = atomicExch(&head[(size_t)b * p2 + d], i);
}

__global__ void init_heads_kernel(int* __restrict__ h, int n) {
  int g = blockIdx.x * 256 + threadIdx.x;
  if (g < n) h[g] = -1;
}

// ---------------- fused merge (gather form): out[j] = (odd + sum(evens)) / count ----------------
__global__ __launch_bounds__(256) void merge_gather_in(const void* __restrict__ x,
                                                       const void* __restrict__ pos,
                                                       const int* __restrict__ mode,
                                                       const int* __restrict__ head,
                                                       const int* __restrict__ nxt,
                                                       float* __restrict__ xo,
                                                       float* __restrict__ so, int p2) {
  int tj = blockIdx.x;
  int b = tj / p2, j = tj - b * p2;
  int c = threadIdx.x * 4;
  int md = *mode;
  __shared__ int sl[64];
  __shared__ int s_n, s_cur;
  size_t xb = ((size_t)b * P0 + 2 * j + 1) * C0 + c;
  size_t pb = (size_t)(2 * j + 1) * C0 + c;
  float4 xa = load4(x, xb, md), pa = load4(pos, pb, md);
  float4 acc = {xa.x + pa.x, xa.y + pa.y, xa.z + pa.z, xa.w + pa.w};
  float cnt = 1.f;
  if (threadIdx.x == 0) s_cur = head[tj];
  __syncthreads();
  int cur = s_cur;
  while (cur != -1) {
    if (threadIdx.x == 0) {
      int n = 0, cc = cur;
      while (cc != -1 && n < 64) {
        sl[n++] = cc;
        cc = nxt[(size_t)b * p2 + cc];
      }
      s_n = n;
      s_cur = cc;
    }
    __syncthreads();
    int n = s_n;
    cur = s_cur;
    for (int k = 0; k < n; ++k) {
      int i = sl[k];
      size_t exb = ((size_t)b * P0 + 2 * i) * C0 + c;
      size_t epb = (size_t)(2 * i) * C0 + c;
      float4 ea = load4(x, exb, md), ep = load4(pos, epb, md);
      acc.x += ea.x + ep.x;
      acc.y += ea.y + ep.y;
      acc.z += ea.z + ep.z;
      acc.w += ea.w + ep.w;
      cnt += 1.f;
    }
    __syncthreads();
  }
  float inv = 1.f / cnt;
  float4 o = {acc.x * inv, acc.y * inv, acc.z * inv, acc.w * inv};
  *(float4*)(xo + (size_t)tj * C0 + c) = o;
  if (threadIdx.x == 0) so[tj] = cnt;
}

__global__ __launch_bounds__(256) void merge_gather_f(const float* __restrict__ xi,
                                                      const float* __restrict__ si,
                                                      const int* __restrict__ head,
                                                      const int* __restrict__ nxt,
                                                      float* __restrict__ xo,
                                                      float* __restrict__ so, int p, int p2) {
  int tj = blockIdx.x;
  int b = tj / p2, j = tj - b * p2;
  int c = threadIdx.x * 4;
  __shared__ int sl[64];
  __shared__ int s_n, s_cur;
  float sz = si[(size_t)b * p + 2 * j + 1];
  float4 v = *(const float4*)(xi + ((size_t)b * p + 2 * j + 1) * C0 + c);
  float4 acc = {v.x * sz, v.y * sz, v.z * sz, v.w * sz};
  float ssum = sz;
  if (threadIdx.x == 0) s_cur = head[tj];
  __syncthreads();
  int cur = s_cur;
  while (cur != -1) {
    if (threadIdx.x == 0) {
      int n = 0, cc = cur;
      while (cc != -1 && n < 64) {
        sl[n++] = cc;
        cc = nxt[(size_t)b * p2 + cc];
      }
      s_n = n;
      s_cur = cc;
    }
    __syncthreads();
    int n = s_n;
    cur = s_cur;
    for (int k = 0; k < n; ++k) {
      int i = sl[k];
      float szi = si[(size_t)b * p + 2 * i];
      float4 e = *(const float4*)(xi + ((size_t)b * p + 2 * i) * C0 + c);
      acc.x += e.x * szi;
      acc.y += e.y * szi;
      acc.z += e.z * szi;
      acc.w += e.w * szi;
      ssum += szi;
    }
    __syncthreads();
  }
  float inv = 1.f / ssum;
  float4 o = {acc.x * inv, acc.y * inv, acc.z * inv, acc.w * inv};
  *(float4*)(xo + (size_t)tj * C0 + c) = o;
  if (threadIdx.x == 0) so[tj] = ssum;
}

// ---------------- last iteration (p=144, p2=72, r=16): stable descending rank ----------------
__global__ void rank_kernel(const float* __restrict__ nmax, const int* __restrict__ nidx,
                            int* __restrict__ unm_map, int* __restrict__ src_ord,
                            int* __restrict__ src_dst) {
  int b = blockIdx.x;
  int i = threadIdx.x;
  __shared__ float v[72];
  __shared__ int nx[72];
  if (i < 72) { v[i] = nmax[b * 72 + i]; nx[i] = nidx[b * 72 + i]; }
  __syncthreads();
  if (i < 72) {
    float vi = v[i];
    int rank = 0;
    for (int k = 0; k < 72; ++k) {
      float vk = v[k];
      rank += (vk > vi) || (vk == vi && k < i);
    }
    if (rank < 16) {
      int d = nx[i];
      if ((unsigned)d >= 72u) d = 0;
      src_ord[b * 16 + rank] = i;
      src_dst[b * 16 + rank] = d;
    } else {
      unm_map[b * 56 + (rank - 16)] = i;
    }
  }
}

__global__ void final_init(const float* __restrict__ x5, const float* __restrict__ s5,
                           const int* __restrict__ unm_map, float* __restrict__ xf,
                           float* __restrict__ sf) {
  int bt = blockIdx.x;
  int b = bt >> 7, tk = bt & 127;
  int c = threadIdx.x * 4;
  float4 o;
  float szo;
  if (tk < 56) {
    int se = unm_map[b * 56 + tk];
    if ((unsigned)se >= 72u) se = 0;
    o = *(const float4*)(x5 + ((size_t)b * 144 + 2 * se) * C0 + c);
    szo = 1.f;
  } else {
    int j = tk - 56;
    float sz = s5[b * 144 + 2 * j + 1];
    float4 v = *(const float4*)(x5 + ((size_t)b * 144 + 2 * j + 1) * C0 + c);
    o.x = v.x * sz; o.y = v.y * sz; o.z = v.z * sz; o.w = v.w * sz;
    szo = sz;
  }
  *(float4*)(xf + (size_t)bt * C0 + c) = o;
  if (threadIdx.x == 0) sf[bt] = szo;
}

__global__ void final_scatter(const float* __restrict__ x5, const float* __restrict__ s5,
                              const int* __restrict__ src_ord, const int* __restrict__ src_dst,
                              float* __restrict__ xf, float* __restrict__ sf) {
  int bk = blockIdx.x;
  int b = bk >> 4, k = bk & 15;
  int c = threadIdx.x * 4;
  int st = src_ord[b * 16 + k], dst = src_dst[b * 16 + k];
  if ((unsigned)st >= 72u) st = 0;
  if ((unsigned)dst >= 72u) dst = 0;
  float sz = s5[b * 144 + 2 * st];
  float4 v = *(const float4*)(x5 + ((size_t)b * 144 + 2 * st) * C0 + c);
  float* out = xf + ((size_t)(b * 128 + 56 + dst)) * C0 + c;
  atomicAdd(out + 0, v.x * sz);
  atomicAdd(out + 1, v.y * sz);
  atomicAdd(out + 2, v.z * sz);
  atomicAdd(out + 3, v.w * sz);
  if (threadIdx.x == 0) atomicAdd(sf + b * 128 + 56 + dst, sz);
}

__global__ void final_div_cvt(const float* __restrict__ xf, const float* __restrict__ sf,
                              __hip_bfloat16* __restrict__ xb) {
  int bt = blockIdx.x;
  int c = threadIdx.x * 4;
  float sz = sf[bt];
  float4 v = *(const float4*)(xf + (size_t)bt * C0 + c);
  __hip_bfloat16* o = xb + (size_t)bt * C0 + c;
  o[0] = __float2bfloat16(v.x / sz);
  o[1] = __float2bfloat16(v.y / sz);
  o[2] = __float2bfloat16(v.z / sz);
  o[3] = __float2bfloat16(v.w / sz);
}

// ---------------- dual-dtype transpose (KxN -> NxK), output bf16 ----------------
__global__ void transpose_in(const void* __restrict__ in, const int* __restrict__ mode,
                             u16* __restrict__ out, int K, int N) {
  __shared__ u16 tile[64][65];
  int n0 = blockIdx.x * 64, k0 = blockIdx.y * 64;
  int t = threadIdx.x;
  int md = *mode;
  int r = t >> 4, c4 = (t & 15) * 4;
#pragma unroll
  for (int pass = 0; pass < 4; ++pass) {
    int row = r + pass * 16;
#pragma unroll
    for (int e = 0; e < 4; ++e) {
      float v = load_in(in, (size_t)(k0 + row) * N + n0 + c4 + e, md);
      __hip_bfloat16 bv = __float2bfloat16(v);
      tile[row][c4 + e] = *(u16*)&bv;
    }
  }
  __syncthreads();
#pragma unroll
  for (int pass = 0; pass < 4; ++pass) {
    int row = r + pass * 16;
    ushort4 o;
    o.x = tile[c4][row]; o.y = tile[c4 + 1][row]; o.z = tile[c4 + 2][row]; o.w = tile[c4 + 3][row];
    *(ushort4*)(out + (size_t)(n0 + row) * K + k0 + c4) = o;
  }
}

// ---------------- bf16 MFMA GEMM, B pre-transposed (NT) ----------------
__global__ __launch_bounds__(256) void gemm_bt(const u16* __restrict__ A,
                                               const u16* __restrict__ BT,
                                               const void* __restrict__ bias,
                                               const int* __restrict__ mode,
                                               void* __restrict__ C, int M, int N,
                                               int K, int act, int out_sel) {
  __shared__ __align__(16) u16 As[128 * 64];
  __shared__ __align__(16) u16 Bs[128 * 64];
  const int t = threadIdx.x, w = t >> 6, L = t & 63;
  const int m0 = blockIdx.y * 128, n0 = blockIdx.x * 128;
  const int wr = w >> 1, wc = w & 1;
  const int md = *mode;
  floatx4 acc[4][4];
#pragma unroll
  for (int a = 0; a < 4; ++a)
#pragma unroll
    for (int bb = 0; bb < 4; ++bb) acc[a][bb] = (floatx4){0.f, 0.f, 0.f, 0.f};
  const int fr = L & 15, fq = (L >> 4) * 8;
  const int srow = t >> 3, sc8 = (t & 7) * 8;
  for (int k0 = 0; k0 < K; k0 += 64) {
#pragma unroll
    for (int q = 0; q < 4; ++q) {
      int row = srow + q * 32;
      *(short8*)(As + row * 64 + sc8) =
          *(const short8*)(A + (size_t)(m0 + row) * K + k0 + sc8);
      *(short8*)(Bs + row * 64 + sc8) =
          *(const short8*)(BT + (size_t)(n0 + row) * K + k0 + sc8);
    }
    __syncthreads();
#pragma unroll
    for (int kh = 0; kh < 2; ++kh) {
      short8 af[4], bfr[4];
#pragma unroll
      for (int mt = 0; mt < 4; ++mt)
        af[mt] = *(const short8*)(As + (wr * 64 + mt * 16 + fr) * 64 + kh * 32 + fq);
#pragma unroll
      for (int nt = 0; nt < 4; ++nt)
        bfr[nt] = *(const short8*)(Bs + (wc * 64 + nt * 16 + fr) * 64 + kh * 32 + fq);
#pragma unroll
      for (int mt = 0; mt < 4; ++mt)
#pragma unroll
        for (int nt = 0; nt < 4; ++nt)
          acc[mt][nt] =
              __builtin_amdgcn_mfma_f32_16x16x32_bf16(af[mt], bfr[nt], acc[mt][nt], 0, 0, 0);
    }
    __syncthreads();
  }
#pragma unroll
  for (int mt = 0; mt < 4; ++mt)
#pragma unroll
    for (int nt = 0; nt < 4; ++nt) {
      int n = n0 + wc * 64 + nt * 16 + fr;
      float bz = load_in(bias, n, md);
#pragma unroll
      for (int rr = 0; rr < 4; ++rr) {
        int m = m0 + wr * 64 + mt * 16 + (L >> 4) * 4 + rr;
        float v = acc[mt][nt][rr] + bz;
        if (act) v = 0.5f * v * (1.f + erff(v * 0.70710678118654752f));
        size_t idx = (size_t)m * N + n;
        if (out_sel == 0 || md) {
          __hip_bfloat16 bv = __float2bfloat16(v);
          ((u16*)C)[idx] = *(u16*)&bv;
        } else {
          ((float*)C)[idx] = v;
        }
      }
    }
}

// ---------------- host ----------------
extern "C" void kernel_launch(void* const* d_in, const int* in_sizes, int n_in, void* d_out,
                              int out_size, void* d_ws, size_t ws_size, hipStream_t stream) {
  const void* x = d_in[0];
  const void* pe = d_in[1];
  const void* W1 = d_in[2];
  const void* b1 = d_in[3];
  const void* W2 = d_in[4];
  const void* b2 = d_in[5];

  char* base = (char*)d_ws;
  size_t off = 0;
  auto alloc = [&](size_t bytes) -> void* {
    void* p = base + off;
    off += (bytes + 255) & ~(size_t)255;
    return p;
  };
  int* mode = (int*)alloc(256);
  float* mbuf = (float*)alloc((size_t)NB * 4608 * 64 * 4);
  float* pm = (float*)alloc((size_t)NB * 2304 * 18 * 4);
  int* pi = (int*)alloc((size_t)NB * 2304 * 18 * 4);
  float* nmax = (float*)alloc((size_t)NB * 2304 * 4);
  int* nidx = (int*)alloc((size_t)NB * 2304 * 4);
  float* bufA = (float*)alloc((size_t)NB * 2304 * C0 * 4);
  float* bufB = (float*)alloc((size_t)NB * 1152 * C0 * 4);
  float* s1 = (float*)alloc((size_t)NB * 2304 * 4);
  float* s2 = (float*)alloc((size_t)NB * 1152 * 4);
  float* s3 = (float*)alloc((size_t)NB * 576 * 4);
  float* s4 = (float*)alloc((size_t)NB * 288 * 4);
  float* s5 = (float*)alloc((size_t)NB * 144 * 4);
  float* sf = (float*)alloc((size_t)NB * 128 * 4);
  int* unm_map = (int*)alloc((size_t)NB * 56 * 4);
  int* src_ord = (int*)alloc((size_t)NB * 16 * 4);
  int* src_dst = (int*)alloc((size_t)NB * 16 * 4);
  u16* xfb = (u16*)alloc((size_t)NB * 128 * C0 * 2);
  u16* hbuf = (u16*)alloc((size_t)1024 * H0 * 2);
  u16* w1t = (u16*)alloc((size_t)H0 * C0 * 2);
  u16* w2t = (u16*)alloc((size_t)H0 * H0 * 2);
  // linked-list buffers: heads per iteration (2304+1152+576+288+144+72 = 4536), one nxt buffer
  int* heads = (int*)alloc((size_t)NB * 4536 * 4);
  int* nxt = (int*)alloc((size_t)NB * 2304 * 4);
  if (off > ws_size) return;

  int* h_it[6];
  h_it[0] = heads;
  h_it[1] = h_it[0] + NB * 2304;
  h_it[2] = h_it[1] + NB * 1152;
  h_it[3] = h_it[2] + NB * 576;
  h_it[4] = h_it[3] + NB * 288;
  h_it[5] = h_it[4] + NB * 144;

  float* x1 = bufA;
  float* x2 = bufB;
  float* x3 = bufA;
  float* x4 = bufB;
  float* x5 = bufA;
  float* xf = bufB;

  detect_mode_kernel<<<1, 1, 0, stream>>>((const uint32_t*)pe, mode);
  init_heads_kernel<<<(NB * 4536 + 255) / 256, 256, 0, stream>>>(heads, NB * 4536);

  // weight transposes (W is KxN row-major -> NxK bf16)
  transpose_in<<<dim3(4096 / 64, 1024 / 64), 256, 0, stream>>>(W1, mode, w1t, 1024, 4096);
  transpose_in<<<dim3(4096 / 64, 4096 / 64), 256, 0, stream>>>(W2, mode, w2t, 4096, 4096);

  // ---- iter 1: p=4608 -> p2=2304 (all evens merge)
  metric_in_kernel<<<NB * P0 / 4, 256, 0, stream>>>(x, pe, mode, mbuf);
  score_kernel<<<dim3(18, 18, NB), 256, 0, stream>>>(mbuf, 4608, 2304, 18, pm, pi);
  argmax_combine_kernel<<<(NB * 2304 + 255) / 256, 256, 0, stream>>>(pm, pi, 2304, 18, nmax,
                                                                     nidx, h_it[0], nxt);
  merge_gather_in<<<NB * 2304, 256, 0, stream>>>(x, pe, mode, h_it[0], nxt, x1, s1, 2304);

  // ---- iters 2..5 (generic all-evens-merge)
  float* xs_in[4] = {x1, x2, x3, x4};
  float* ss_in[4] = {s1, s2, s3, s4};
  float* xs_out[4] = {x2, x3, x4, x5};
  float* ss_out[4] = {s2, s3, s4, s5};
  int ps[5] = {2304, 1152, 576, 288, 144};
  for (int it = 0; it < 4; ++it) {
    int p = ps[it], p2 = ps[it + 1];
    int iT = (p2 + 127) / 128, jT = (p2 + 127) / 128;
    metric_f32_kernel<<<NB * p / 4, 256, 0, stream>>>(xs_in[it], mbuf, p);
    score_kernel<<<dim3(jT, iT, NB), 256, 0, stream>>>(mbuf, p, p2, jT, pm, pi);
    argmax_combine_kernel<<<(NB * p2 + 255) / 256, 256, 0, stream>>>(pm, pi, p2, jT, nmax, nidx,
                                                                     h_it[it + 1], nxt);
    merge_gather_f<<<NB * p2, 256, 0, stream>>>(xs_in[it], ss_in[it], h_it[it + 1], nxt,
                                                xs_out[it], ss_out[it], p, p2);
  }

  // ---- iter 6: p=144, p2=72, r=16 -> 128 tokens
  metric_f32_kernel<<<NB * 144 / 4, 256, 0, stream>>>(x5, mbuf, 144);
  score_kernel<<<dim3(1, 1, NB), 256, 0, stream>>>(mbuf, 144, 72, 1, pm, pi);
  argmax_combine_kernel<<<(NB * 72 + 255) / 256, 256, 0, stream>>>(pm, pi, 72, 1, nmax, nidx,
                                                                   h_it[5], nxt);
  rank_kernel<<<NB, 128, 0, stream>>>(nmax, nidx, unm_map, src_ord, src_dst);
  final_init<<<NB * 128, 256, 0, stream>>>(x5, s5, unm_map, xf, sf);
  final_scatter<<<NB * 16, 256, 0, stream>>>(x5, s5, src_ord, src_dst, xf, sf);
  final_div_cvt<<<NB * 128, 256, 0, stream>>>(xf, sf, (__hip_bfloat16*)xfb);

  // ---- MLP: h = gelu(x@W1 + b1); out = h@W2 + b2
  gemm_bt<<<dim3(4096 / 128, 1024 / 128), 256, 0, stream>>>(xfb, w1t, b1, mode, hbuf, 1024, 4096,
                                                            1024, 1, 0);
  gemm_bt<<<dim3(4096 / 128, 1024 / 128), 256, 0, stream>>>(hbuf, w2t, b2, mode, d_out, 1024,
                                                            4096, 4096, 0, 1);
}

// Round 2
// 834.685 us; speedup vs baseline: 1.7355x; 1.0888x over previous
//
#include <hip/hip_runtime.h>
#include <hip/hip_bf16.h>
#include <math.h>
#include <stdint.h>

typedef unsigned short u16;
typedef __attribute__((ext_vector_type(8))) short short8;
typedef __attribute__((ext_vector_type(4))) float floatx4;

#define NB 8
#define P0 4608
#define C0 1024
#define H0 4096

// mode: 0 = inputs/outputs are float32, 1 = bf16
__global__ void detect_mode_kernel(const uint32_t* __restrict__ pe_words, int* __restrict__ mode) {
  *mode = (pe_words[64] != 0u) ? 1 : 0;
}

__device__ __forceinline__ float load_in(const void* p, size_t idx, int mode) {
  if (mode) return __bfloat162float(((const __hip_bfloat16*)p)[idx]);
  return ((const float*)p)[idx];
}

__device__ __forceinline__ float4 load4(const void* p, size_t idx, int mode) {
  float4 r;
  if (mode) {
    ushort4 u = *(const ushort4*)((const u16*)p + idx);
    r.x = __bfloat162float(*(__hip_bfloat16*)&u.x);
    r.y = __bfloat162float(*(__hip_bfloat16*)&u.y);
    r.z = __bfloat162float(*(__hip_bfloat16*)&u.z);
    r.w = __bfloat162float(*(__hip_bfloat16*)&u.w);
  } else {
    r = *(const float4*)((const float*)p + idx);
  }
  return r;
}

__device__ __forceinline__ void write_hilo(u16* __restrict__ m2, size_t tok, int lane, float v) {
  __hip_bfloat16 hi = __float2bfloat16(v);
  float hif = __bfloat162float(hi);
  __hip_bfloat16 lo = __float2bfloat16(v - hif);
  m2[tok * 128 + lane] = *(u16*)&hi;
  m2[tok * 128 + 64 + lane] = *(u16*)&lo;
}

// ---------------- metric: mean over 16 heads of 64-dim chunks, L2 normalize, bf16 hi/lo split ----------------
__global__ void metric_in_kernel(const void* __restrict__ x, const void* __restrict__ pos,
                                 const int* __restrict__ mode, u16* __restrict__ m2) {
  int tok = blockIdx.x * 4 + (threadIdx.x >> 6);
  int lane = threadIdx.x & 63;
  if (tok >= NB * P0) return;
  int b = tok / P0, t = tok - b * P0;
  int md = *mode;
  size_t xbase = ((size_t)b * P0 + t) * C0 + lane;
  size_t pbase = (size_t)t * C0 + lane;
  float s = 0.f;
#pragma unroll
  for (int h = 0; h < 16; ++h)
    s += load_in(x, xbase + h * 64, md) + load_in(pos, pbase + h * 64, md);
  s *= (1.f / 16.f);
  float sq = s * s;
#pragma unroll
  for (int off = 1; off < 64; off <<= 1) sq += __shfl_xor(sq, off, 64);
  write_hilo(m2, (size_t)tok, lane, s / sqrtf(sq));
}

__global__ void metric_f32_kernel(const float* __restrict__ x, u16* __restrict__ m2, int p) {
  int tok = blockIdx.x * 4 + (threadIdx.x >> 6);
  int lane = threadIdx.x & 63;
  if (tok >= NB * p) return;
  const float* xr = x + (size_t)tok * C0 + lane;
  float s = 0.f;
#pragma unroll
  for (int h = 0; h < 16; ++h) s += xr[h * 64];
  s *= (1.f / 16.f);
  float sq = s * s;
#pragma unroll
  for (int off = 1; off < 64; off <<= 1) sq += __shfl_xor(sq, off, 64);
  write_hilo(m2, (size_t)tok, lane, s / sqrtf(sq));
}

// ---------------- scores via bf16x4 split-precision MFMA + per-(row, 64-col) argmax partials ----------------
// M2: per token 128 bf16 = [64 hi | 64 lo]. scores[i][j] = dot(m[2i], m[2j+1]).
// Each 128x128 block: 4 waves (2x2), each wave 64x64 via 4x4 16x16 fragments.
// Emits 2 argmax partials per 128-col tile (one per 64-col wave slice): jT2 = 2*jT.
__global__ __launch_bounds__(256) void score_mfma_kernel(const u16* __restrict__ M2,
                                                         int p, int p2, int jT2,
                                                         float* __restrict__ pm,
                                                         int* __restrict__ pi) {
  const int bi = blockIdx.x, ii = blockIdx.y, b = blockIdx.z;
  const int t = threadIdx.x, w = t >> 6, L = t & 63;
  const int wr = w >> 1, wc = w & 1;
  const int fr = L & 15, fo = (L >> 4) * 8;
  const u16* Mb = M2 + (size_t)b * p * 128;

  floatx4 acc[4][4];
#pragma unroll
  for (int mt = 0; mt < 4; ++mt)
#pragma unroll
    for (int nt = 0; nt < 4; ++nt) acc[mt][nt] = (floatx4){0.f, 0.f, 0.f, 0.f};

  const u16* arp[4];
  const u16* brp[4];
#pragma unroll
  for (int mt = 0; mt < 4; ++mt) {
    int i = ii * 128 + wr * 64 + mt * 16 + fr;
    int ta = 2 * i;
    if (ta > p - 2) ta = p - 2;
    arp[mt] = Mb + (size_t)ta * 128 + fo;
    int j = bi * 128 + wc * 64 + mt * 16 + fr;
    int tb = 2 * j + 1;
    if (tb > p - 1) tb = p - 1;
    brp[mt] = Mb + (size_t)tb * 128 + fo;
  }

#pragma unroll
  for (int ks = 0; ks < 2; ++ks) {
    short8 ah[4], al[4], bh[4], bl[4];
#pragma unroll
    for (int mt = 0; mt < 4; ++mt) {
      ah[mt] = *(const short8*)(arp[mt] + ks * 32);
      al[mt] = *(const short8*)(arp[mt] + ks * 32 + 64);
      bh[mt] = *(const short8*)(brp[mt] + ks * 32);
      bl[mt] = *(const short8*)(brp[mt] + ks * 32 + 64);
    }
#pragma unroll
    for (int mt = 0; mt < 4; ++mt)
#pragma unroll
      for (int nt = 0; nt < 4; ++nt) {
        acc[mt][nt] = __builtin_amdgcn_mfma_f32_16x16x32_bf16(ah[mt], bh[nt], acc[mt][nt], 0, 0, 0);
        acc[mt][nt] = __builtin_amdgcn_mfma_f32_16x16x32_bf16(ah[mt], bl[nt], acc[mt][nt], 0, 0, 0);
        acc[mt][nt] = __builtin_amdgcn_mfma_f32_16x16x32_bf16(al[mt], bh[nt], acc[mt][nt], 0, 0, 0);
        acc[mt][nt] = __builtin_amdgcn_mfma_f32_16x16x32_bf16(al[mt], bl[nt], acc[mt][nt], 0, 0, 0);
      }
  }

  // epilogue: per output row, argmax over this wave's 64 cols
  const int gi4 = (L >> 4) * 4;
#pragma unroll
  for (int mt = 0; mt < 4; ++mt) {
#pragma unroll
    for (int reg = 0; reg < 4; ++reg) {
      int i = ii * 128 + wr * 64 + mt * 16 + gi4 + reg;
      float bm = -INFINITY;
      int bj = 0x7fffffff;
#pragma unroll
      for (int nt = 0; nt < 4; ++nt) {
        int j = bi * 128 + wc * 64 + nt * 16 + fr;
        float v = acc[mt][nt][reg];
        if (j < p2 && v > bm) { bm = v; bj = j; }
      }
#pragma unroll
      for (int mk = 1; mk < 16; mk <<= 1) {
        float om = __shfl_xor(bm, mk, 64);
        int oj = __shfl_xor(bj, mk, 64);
        if (om > bm || (om == bm && oj < bj)) { bm = om; bj = oj; }
      }
      if (fr == 0 && i < p2) {
        size_t o = ((size_t)b * 2304 + i) * jT2 + bi * 2 + wc;
        pm[o] = bm;
        pi[o] = bj;
      }
    }
  }
}

// argmax combine + build per-destination linked list (head[dst] -> chain via nxt[src])
__global__ void argmax_combine_kernel(const float* __restrict__ pm, const int* __restrict__ pi,
                                      int p2, int jT, float* __restrict__ nmax,
                                      int* __restrict__ nidx, int* __restrict__ head,
                                      int* __restrict__ nxt) {
  int g = blockIdx.x * 256 + threadIdx.x;
  if (g >= NB * p2) return;
  int b = g / p2, i = g - b * p2;
  const float* r = pm + ((size_t)b * 2304 + i) * jT;
  const int* ri = pi + ((size_t)b * 2304 + i) * jT;
  float best = r[0];
  int bidx = ri[0];
  for (int k = 1; k < jT; ++k) {
    if (r[k] > best || (r[k] == best && ri[k] < bidx)) { best = r[k]; bidx = ri[k]; }
  }
  nmax[g] = best;
  nidx[g] = bidx;
  int d = bidx;
  if ((unsigned)d >= (unsigned)p2) d = 0;
  nxt[g] = atomicExch(&head[(size_t)b * p2 + d], i);
}

__global__ void init_heads_kernel(int* __restrict__ h, int n) {
  int g = blockIdx.x * 256 + threadIdx.x;
  if (g < n) h[g] = -1;
}

// ---------------- fused merge (gather form): out[j] = (odd + sum(evens)) / count ----------------
__global__ __launch_bounds__(256) void merge_gather_in(const void* __restrict__ x,
                                                       const void* __restrict__ pos,
                                                       const int* __restrict__ mode,
                                                       const int* __restrict__ head,
                                                       const int* __restrict__ nxt,
                                                       float* __restrict__ xo,
                                                       float* __restrict__ so, int p2) {
  int tj = blockIdx.x;
  int b = tj / p2, j = tj - b * p2;
  int c = threadIdx.x * 4;
  int md = *mode;
  __shared__ int sl[64];
  __shared__ int s_n, s_cur;
  size_t xb = ((size_t)b * P0 + 2 * j + 1) * C0 + c;
  size_t pb = (size_t)(2 * j + 1) * C0 + c;
  float4 xa = load4(x, xb, md), pa = load4(pos, pb, md);
  float4 acc = {xa.x + pa.x, xa.y + pa.y, xa.z + pa.z, xa.w + pa.w};
  float cnt = 1.f;
  if (threadIdx.x == 0) s_cur = head[tj];
  __syncthreads();
  int cur = s_cur;
  while (cur != -1) {
    if (threadIdx.x == 0) {
      int n = 0, cc = cur;
      while (cc != -1 && n < 64) {
        sl[n++] = cc;
        cc = nxt[(size_t)b * p2 + cc];
      }
      s_n = n;
      s_cur = cc;
    }
    __syncthreads();
    int n = s_n;
    cur = s_cur;
    for (int k = 0; k < n; ++k) {
      int i = sl[k];
      size_t exb = ((size_t)b * P0 + 2 * i) * C0 + c;
      size_t epb = (size_t)(2 * i) * C0 + c;
      float4 ea = load4(x, exb, md), ep = load4(pos, epb, md);
      acc.x += ea.x + ep.x;
      acc.y += ea.y + ep.y;
      acc.z += ea.z + ep.z;
      acc.w += ea.w + ep.w;
      cnt += 1.f;
    }
    __syncthreads();
  }
  float inv = 1.f / cnt;
  float4 o = {acc.x * inv, acc.y * inv, acc.z * inv, acc.w * inv};
  *(float4*)(xo + (size_t)tj * C0 + c) = o;
  if (threadIdx.x == 0) so[tj] = cnt;
}

__global__ __launch_bounds__(256) void merge_gather_f(const float* __restrict__ xi,
                                                      const float* __restrict__ si,
                                                      const int* __restrict__ head,
                                                      const int* __restrict__ nxt,
                                                      float* __restrict__ xo,
                                                      float* __restrict__ so, int p, int p2) {
  int tj = blockIdx.x;
  int b = tj / p2, j = tj - b * p2;
  int c = threadIdx.x * 4;
  __shared__ int sl[64];
  __shared__ int s_n, s_cur;
  float sz = si[(size_t)b * p + 2 * j + 1];
  float4 v = *(const float4*)(xi + ((size_t)b * p + 2 * j + 1) * C0 + c);
  float4 acc = {v.x * sz, v.y * sz, v.z * sz, v.w * sz};
  float ssum = sz;
  if (threadIdx.x == 0) s_cur = head[tj];
  __syncthreads();
  int cur = s_cur;
  while (cur != -1) {
    if (threadIdx.x == 0) {
      int n = 0, cc = cur;
      while (cc != -1 && n < 64) {
        sl[n++] = cc;
        cc = nxt[(size_t)b * p2 + cc];
      }
      s_n = n;
      s_cur = cc;
    }
    __syncthreads();
    int n = s_n;
    cur = s_cur;
    for (int k = 0; k < n; ++k) {
      int i = sl[k];
      float szi = si[(size_t)b * p + 2 * i];
      float4 e = *(const float4*)(xi + ((size_t)b * p + 2 * i) * C0 + c);
      acc.x += e.x * szi;
      acc.y += e.y * szi;
      acc.z += e.z * szi;
      acc.w += e.w * szi;
      ssum += szi;
    }
    __syncthreads();
  }
  float inv = 1.f / ssum;
  float4 o = {acc.x * inv, acc.y * inv, acc.z * inv, acc.w * inv};
  *(float4*)(xo + (size_t)tj * C0 + c) = o;
  if (threadIdx.x == 0) so[tj] = ssum;
}

// ---------------- last iteration (p=144, p2=72, r=16): stable descending rank ----------------
__global__ void rank_kernel(const float* __restrict__ nmax, const int* __restrict__ nidx,
                            int* __restrict__ unm_map, int* __restrict__ src_ord,
                            int* __restrict__ src_dst) {
  int b = blockIdx.x;
  int i = threadIdx.x;
  __shared__ float v[72];
  __shared__ int nx[72];
  if (i < 72) { v[i] = nmax[b * 72 + i]; nx[i] = nidx[b * 72 + i]; }
  __syncthreads();
  if (i < 72) {
    float vi = v[i];
    int rank = 0;
    for (int k = 0; k < 72; ++k) {
      float vk = v[k];
      rank += (vk > vi) || (vk == vi && k < i);
    }
    if (rank < 16) {
      int d = nx[i];
      if ((unsigned)d >= 72u) d = 0;
      src_ord[b * 16 + rank] = i;
      src_dst[b * 16 + rank] = d;
    } else {
      unm_map[b * 56 + (rank - 16)] = i;
    }
  }
}

__global__ void final_init(const float* __restrict__ x5, const float* __restrict__ s5,
                           const int* __restrict__ unm_map, float* __restrict__ xf,
                           float* __restrict__ sf) {
  int bt = blockIdx.x;
  int b = bt >> 7, tk = bt & 127;
  int c = threadIdx.x * 4;
  float4 o;
  float szo;
  if (tk < 56) {
    int se = unm_map[b * 56 + tk];
    if ((unsigned)se >= 72u) se = 0;
    o = *(const float4*)(x5 + ((size_t)b * 144 + 2 * se) * C0 + c);
    szo = 1.f;
  } else {
    int j = tk - 56;
    float sz = s5[b * 144 + 2 * j + 1];
    float4 v = *(const float4*)(x5 + ((size_t)b * 144 + 2 * j + 1) * C0 + c);
    o.x = v.x * sz; o.y = v.y * sz; o.z = v.z * sz; o.w = v.w * sz;
    szo = sz;
  }
  *(float4*)(xf + (size_t)bt * C0 + c) = o;
  if (threadIdx.x == 0) sf[bt] = szo;
}

__global__ void final_scatter(const float* __restrict__ x5, const float* __restrict__ s5,
                              const int* __restrict__ src_ord, const int* __restrict__ src_dst,
                              float* __restrict__ xf, float* __restrict__ sf) {
  int bk = blockIdx.x;
  int b = bk >> 4, k = bk & 15;
  int c = threadIdx.x * 4;
  int st = src_ord[b * 16 + k], dst = src_dst[b * 16 + k];
  if ((unsigned)st >= 72u) st = 0;
  if ((unsigned)dst >= 72u) dst = 0;
  float sz = s5[b * 144 + 2 * st];
  float4 v = *(const float4*)(x5 + ((size_t)b * 144 + 2 * st) * C0 + c);
  float* out = xf + ((size_t)(b * 128 + 56 + dst)) * C0 + c;
  atomicAdd(out + 0, v.x * sz);
  atomicAdd(out + 1, v.y * sz);
  atomicAdd(out + 2, v.z * sz);
  atomicAdd(out + 3, v.w * sz);
  if (threadIdx.x == 0) atomicAdd(sf + b * 128 + 56 + dst, sz);
}

__global__ void final_div_cvt(const float* __restrict__ xf, const float* __restrict__ sf,
                              __hip_bfloat16* __restrict__ xb) {
  int bt = blockIdx.x;
  int c = threadIdx.x * 4;
  float sz = sf[bt];
  float4 v = *(const float4*)(xf + (size_t)bt * C0 + c);
  __hip_bfloat16* o = xb + (size_t)bt * C0 + c;
  o[0] = __float2bfloat16(v.x / sz);
  o[1] = __float2bfloat16(v.y / sz);
  o[2] = __float2bfloat16(v.z / sz);
  o[3] = __float2bfloat16(v.w / sz);
}

// ---------------- dual-dtype transpose (KxN -> NxK), output bf16 ----------------
__global__ void transpose_in(const void* __restrict__ in, const int* __restrict__ mode,
                             u16* __restrict__ out, int K, int N) {
  __shared__ u16 tile[64][65];
  int n0 = blockIdx.x * 64, k0 = blockIdx.y * 64;
  int t = threadIdx.x;
  int md = *mode;
  int r = t >> 4, c4 = (t & 15) * 4;
#pragma unroll
  for (int pass = 0; pass < 4; ++pass) {
    int row = r + pass * 16;
#pragma unroll
    for (int e = 0; e < 4; ++e) {
      float v = load_in(in, (size_t)(k0 + row) * N + n0 + c4 + e, md);
      __hip_bfloat16 bv = __float2bfloat16(v);
      tile[row][c4 + e] = *(u16*)&bv;
    }
  }
  __syncthreads();
#pragma unroll
  for (int pass = 0; pass < 4; ++pass) {
    int row = r + pass * 16;
    ushort4 o;
    o.x = tile[c4][row]; o.y = tile[c4 + 1][row]; o.z = tile[c4 + 2][row]; o.w = tile[c4 + 3][row];
    *(ushort4*)(out + (size_t)(n0 + row) * K + k0 + c4) = o;
  }
}

// ---------------- bf16 MFMA GEMM, B pre-transposed (NT) ----------------
__global__ __launch_bounds__(256) void gemm_bt(const u16* __restrict__ A,
                                               const u16* __restrict__ BT,
                                               const void* __restrict__ bias,
                                               const int* __restrict__ mode,
                                               void* __restrict__ C, int M, int N,
                                               int K, int act, int out_sel) {
  __shared__ __align__(16) u16 As[128 * 64];
  __shared__ __align__(16) u16 Bs[128 * 64];
  const int t = threadIdx.x, w = t >> 6, L = t & 63;
  const int m0 = blockIdx.y * 128, n0 = blockIdx.x * 128;
  const int wr = w >> 1, wc = w & 1;
  const int md = *mode;
  floatx4 acc[4][4];
#pragma unroll
  for (int a = 0; a < 4; ++a)
#pragma unroll
    for (int bb = 0; bb < 4; ++bb) acc[a][bb] = (floatx4){0.f, 0.f, 0.f, 0.f};
  const int fr = L & 15, fq = (L >> 4) * 8;
  const int srow = t >> 3, sc8 = (t & 7) * 8;
  for (int k0 = 0; k0 < K; k0 += 64) {
#pragma unroll
    for (int q = 0; q < 4; ++q) {
      int row = srow + q * 32;
      *(short8*)(As + row * 64 + sc8) =
          *(const short8*)(A + (size_t)(m0 + row) * K + k0 + sc8);
      *(short8*)(Bs + row * 64 + sc8) =
          *(const short8*)(BT + (size_t)(n0 + row) * K + k0 + sc8);
    }
    __syncthreads();
#pragma unroll
    for (int kh = 0; kh < 2; ++kh) {
      short8 af[4], bfr[4];
#pragma unroll
      for (int mt = 0; mt < 4; ++mt)
        af[mt] = *(const short8*)(As + (wr * 64 + mt * 16 + fr) * 64 + kh * 32 + fq);
#pragma unroll
      for (int nt = 0; nt < 4; ++nt)
        bfr[nt] = *(const short8*)(Bs + (wc * 64 + nt * 16 + fr) * 64 + kh * 32 + fq);
#pragma unroll
      for (int mt = 0; mt < 4; ++mt)
#pragma unroll
        for (int nt = 0; nt < 4; ++nt)
          acc[mt][nt] =
              __builtin_amdgcn_mfma_f32_16x16x32_bf16(af[mt], bfr[nt], acc[mt][nt], 0, 0, 0);
    }
    __syncthreads();
  }
#pragma unroll
  for (int mt = 0; mt < 4; ++mt)
#pragma unroll
    for (int nt = 0; nt < 4; ++nt) {
      int n = n0 + wc * 64 + nt * 16 + fr;
      float bz = load_in(bias, n, md);
#pragma unroll
      for (int rr = 0; rr < 4; ++rr) {
        int m = m0 + wr * 64 + mt * 16 + (L >> 4) * 4 + rr;
        float v = acc[mt][nt][rr] + bz;
        if (act) v = 0.5f * v * (1.f + erff(v * 0.70710678118654752f));
        size_t idx = (size_t)m * N + n;
        if (out_sel == 0 || md) {
          __hip_bfloat16 bv = __float2bfloat16(v);
          ((u16*)C)[idx] = *(u16*)&bv;
        } else {
          ((float*)C)[idx] = v;
        }
      }
    }
}

// ---------------- host ----------------
extern "C" void kernel_launch(void* const* d_in, const int* in_sizes, int n_in, void* d_out,
                              int out_size, void* d_ws, size_t ws_size, hipStream_t stream) {
  const void* x = d_in[0];
  const void* pe = d_in[1];
  const void* W1 = d_in[2];
  const void* b1 = d_in[3];
  const void* W2 = d_in[4];
  const void* b2 = d_in[5];

  char* base = (char*)d_ws;
  size_t off = 0;
  auto alloc = [&](size_t bytes) -> void* {
    void* p = base + off;
    off += (bytes + 255) & ~(size_t)255;
    return p;
  };
  int* mode = (int*)alloc(256);
  u16* m2 = (u16*)alloc((size_t)NB * 4608 * 128 * 2);  // bf16 hi/lo split metric
  float* pm = (float*)alloc((size_t)NB * 2304 * 36 * 4);
  int* pi = (int*)alloc((size_t)NB * 2304 * 36 * 4);
  float* nmax = (float*)alloc((size_t)NB * 2304 * 4);
  int* nidx = (int*)alloc((size_t)NB * 2304 * 4);
  float* bufA = (float*)alloc((size_t)NB * 2304 * C0 * 4);
  float* bufB = (float*)alloc((size_t)NB * 1152 * C0 * 4);
  float* s1 = (float*)alloc((size_t)NB * 2304 * 4);
  float* s2 = (float*)alloc((size_t)NB * 1152 * 4);
  float* s3 = (float*)alloc((size_t)NB * 576 * 4);
  float* s4 = (float*)alloc((size_t)NB * 288 * 4);
  float* s5 = (float*)alloc((size_t)NB * 144 * 4);
  float* sf = (float*)alloc((size_t)NB * 128 * 4);
  int* unm_map = (int*)alloc((size_t)NB * 56 * 4);
  int* src_ord = (int*)alloc((size_t)NB * 16 * 4);
  int* src_dst = (int*)alloc((size_t)NB * 16 * 4);
  u16* xfb = (u16*)alloc((size_t)NB * 128 * C0 * 2);
  u16* hbuf = (u16*)alloc((size_t)1024 * H0 * 2);
  u16* w1t = (u16*)alloc((size_t)H0 * C0 * 2);
  u16* w2t = (u16*)alloc((size_t)H0 * H0 * 2);
  // linked-list buffers: heads per iteration (2304+1152+576+288+144+72 = 4536), one nxt buffer
  int* heads = (int*)alloc((size_t)NB * 4536 * 4);
  int* nxt = (int*)alloc((size_t)NB * 2304 * 4);
  if (off > ws_size) return;

  int* h_it[6];
  h_it[0] = heads;
  h_it[1] = h_it[0] + NB * 2304;
  h_it[2] = h_it[1] + NB * 1152;
  h_it[3] = h_it[2] + NB * 576;
  h_it[4] = h_it[3] + NB * 288;
  h_it[5] = h_it[4] + NB * 144;

  float* x1 = bufA;
  float* x2 = bufB;
  float* x3 = bufA;
  float* x4 = bufB;
  float* x5 = bufA;
  float* xf = bufB;

  detect_mode_kernel<<<1, 1, 0, stream>>>((const uint32_t*)pe, mode);
  init_heads_kernel<<<(NB * 4536 + 255) / 256, 256, 0, stream>>>(heads, NB * 4536);

  // weight transposes (W is KxN row-major -> NxK bf16)
  transpose_in<<<dim3(4096 / 64, 1024 / 64), 256, 0, stream>>>(W1, mode, w1t, 1024, 4096);
  transpose_in<<<dim3(4096 / 64, 4096 / 64), 256, 0, stream>>>(W2, mode, w2t, 4096, 4096);

  // ---- iter 1: p=4608 -> p2=2304 (all evens merge)
  metric_in_kernel<<<NB * P0 / 4, 256, 0, stream>>>(x, pe, mode, m2);
  score_mfma_kernel<<<dim3(18, 18, NB), 256, 0, stream>>>(m2, 4608, 2304, 36, pm, pi);
  argmax_combine_kernel<<<(NB * 2304 + 255) / 256, 256, 0, stream>>>(pm, pi, 2304, 36, nmax,
                                                                     nidx, h_it[0], nxt);
  merge_gather_in<<<NB * 2304, 256, 0, stream>>>(x, pe, mode, h_it[0], nxt, x1, s1, 2304);

  // ---- iters 2..5 (generic all-evens-merge)
  float* xs_in[4] = {x1, x2, x3, x4};
  float* ss_in[4] = {s1, s2, s3, s4};
  float* xs_out[4] = {x2, x3, x4, x5};
  float* ss_out[4] = {s2, s3, s4, s5};
  int ps[5] = {2304, 1152, 576, 288, 144};
  for (int it = 0; it < 4; ++it) {
    int p = ps[it], p2 = ps[it + 1];
    int iT = (p2 + 127) / 128, jT = (p2 + 127) / 128;
    metric_f32_kernel<<<NB * p / 4, 256, 0, stream>>>(xs_in[it], m2, p);
    score_mfma_kernel<<<dim3(jT, iT, NB), 256, 0, stream>>>(m2, p, p2, 2 * jT, pm, pi);
    argmax_combine_kernel<<<(NB * p2 + 255) / 256, 256, 0, stream>>>(pm, pi, p2, 2 * jT, nmax,
                                                                     nidx, h_it[it + 1], nxt);
    merge_gather_f<<<NB * p2, 256, 0, stream>>>(xs_in[it], ss_in[it], h_it[it + 1], nxt,
                                                xs_out[it], ss_out[it], p, p2);
  }

  // ---- iter 6: p=144, p2=72, r=16 -> 128 tokens
  metric_f32_kernel<<<NB * 144 / 4, 256, 0, stream>>>(x5, m2, 144);
  score_mfma_kernel<<<dim3(1, 1, NB), 256, 0, stream>>>(m2, 144, 72, 2, pm, pi);
  argmax_combine_kernel<<<(NB * 72 + 255) / 256, 256, 0, stream>>>(pm, pi, 72, 2, nmax, nidx,
                                                                   h_it[5], nxt);
  rank_kernel<<<NB, 128, 0, stream>>>(nmax, nidx, unm_map, src_ord, src_dst);
  final_init<<<NB * 128, 256, 0, stream>>>(x5, s5, unm_map, xf, sf);
  final_scatter<<<NB * 16, 256, 0, stream>>>(x5, s5, src_ord, src_dst, xf, sf);
  final_div_cvt<<<NB * 128, 256, 0, stream>>>(xf, sf, (__hip_bfloat16*)xfb);

  // ---- MLP: h = gelu(x@W1 + b1); out = h@W2 + b2
  gemm_bt<<<dim3(4096 / 128, 1024 / 128), 256, 0, stream>>>(xfb, w1t, b1, mode, hbuf, 1024, 4096,
                                                            1024, 1, 0);
  gemm_bt<<<dim3(4096 / 128, 1024 / 128), 256, 0, stream>>>(hbuf, w2t, b2, mode, d_out, 1024,
                                                            4096, 4096, 0, 1);
}

// Round 3
// 794.816 us; speedup vs baseline: 1.8226x; 1.0502x over previous
//
#include <hip/hip_runtime.h>
#include <hip/hip_bf16.h>
#include <math.h>
#include <stdint.h>

typedef unsigned short u16;
typedef __attribute__((ext_vector_type(8))) short short8;
typedef __attribute__((ext_vector_type(4))) float floatx4;

#define NB 8
#define P0 4608
#define C0 1024
#define H0 4096

// mode: 0 = inputs/outputs are float32, 1 = bf16
__global__ void detect_mode_kernel(const uint32_t* __restrict__ pe_words, int* __restrict__ mode) {
  *mode = (pe_words[64] != 0u) ? 1 : 0;
}

__device__ __forceinline__ float load_in(const void* p, size_t idx, int mode) {
  if (mode) return __bfloat162float(((const __hip_bfloat16*)p)[idx]);
  return ((const float*)p)[idx];
}

__device__ __forceinline__ float4 load4(const void* p, size_t idx, int mode) {
  float4 r;
  if (mode) {
    ushort4 u = *(const ushort4*)((const u16*)p + idx);
    r.x = __bfloat162float(*(__hip_bfloat16*)&u.x);
    r.y = __bfloat162float(*(__hip_bfloat16*)&u.y);
    r.z = __bfloat162float(*(__hip_bfloat16*)&u.z);
    r.w = __bfloat162float(*(__hip_bfloat16*)&u.w);
  } else {
    r = *(const float4*)((const float*)p + idx);
  }
  return r;
}

__device__ __forceinline__ void write_hilo(u16* __restrict__ m2, size_t tok, int lane, float v) {
  __hip_bfloat16 hi = __float2bfloat16(v);
  float hif = __bfloat162float(hi);
  __hip_bfloat16 lo = __float2bfloat16(v - hif);
  m2[tok * 128 + lane] = *(u16*)&hi;
  m2[tok * 128 + 64 + lane] = *(u16*)&lo;
}

// ---------------- metric: mean over 16 heads of 64-dim chunks, L2 normalize, bf16 hi/lo split ----------------
__global__ void metric_in_kernel(const void* __restrict__ x, const void* __restrict__ pos,
                                 const int* __restrict__ mode, u16* __restrict__ m2) {
  int tok = blockIdx.x * 4 + (threadIdx.x >> 6);
  int lane = threadIdx.x & 63;
  if (tok >= NB * P0) return;
  int b = tok / P0, t = tok - b * P0;
  int md = *mode;
  size_t xbase = ((size_t)b * P0 + t) * C0 + lane;
  size_t pbase = (size_t)t * C0 + lane;
  float s = 0.f;
#pragma unroll
  for (int h = 0; h < 16; ++h)
    s += load_in(x, xbase + h * 64, md) + load_in(pos, pbase + h * 64, md);
  s *= (1.f / 16.f);
  float sq = s * s;
#pragma unroll
  for (int off = 1; off < 64; off <<= 1) sq += __shfl_xor(sq, off, 64);
  write_hilo(m2, (size_t)tok, lane, s / sqrtf(sq));
}

__global__ void metric_f32_kernel(const float* __restrict__ x, u16* __restrict__ m2, int p) {
  int tok = blockIdx.x * 4 + (threadIdx.x >> 6);
  int lane = threadIdx.x & 63;
  if (tok >= NB * p) return;
  const float* xr = x + (size_t)tok * C0 + lane;
  float s = 0.f;
#pragma unroll
  for (int h = 0; h < 16; ++h) s += xr[h * 64];
  s *= (1.f / 16.f);
  float sq = s * s;
#pragma unroll
  for (int off = 1; off < 64; off <<= 1) sq += __shfl_xor(sq, off, 64);
  write_hilo(m2, (size_t)tok, lane, s / sqrtf(sq));
}

// ---------------- scores via bf16x4 split-precision MFMA + per-(row, 64-col) argmax partials ----------------
__global__ __launch_bounds__(256) void score_mfma_kernel(const u16* __restrict__ M2,
                                                         int p, int p2, int jT2,
                                                         float* __restrict__ pm,
                                                         int* __restrict__ pi) {
  const int bi = blockIdx.x, ii = blockIdx.y, b = blockIdx.z;
  const int t = threadIdx.x, w = t >> 6, L = t & 63;
  const int wr = w >> 1, wc = w & 1;
  const int fr = L & 15, fo = (L >> 4) * 8;
  const u16* Mb = M2 + (size_t)b * p * 128;

  floatx4 acc[4][4];
#pragma unroll
  for (int mt = 0; mt < 4; ++mt)
#pragma unroll
    for (int nt = 0; nt < 4; ++nt) acc[mt][nt] = (floatx4){0.f, 0.f, 0.f, 0.f};

  const u16* arp[4];
  const u16* brp[4];
#pragma unroll
  for (int mt = 0; mt < 4; ++mt) {
    int i = ii * 128 + wr * 64 + mt * 16 + fr;
    int ta = 2 * i;
    if (ta > p - 2) ta = p - 2;
    arp[mt] = Mb + (size_t)ta * 128 + fo;
    int j = bi * 128 + wc * 64 + mt * 16 + fr;
    int tb = 2 * j + 1;
    if (tb > p - 1) tb = p - 1;
    brp[mt] = Mb + (size_t)tb * 128 + fo;
  }

#pragma unroll
  for (int ks = 0; ks < 2; ++ks) {
    short8 ah[4], al[4], bh[4], bl[4];
#pragma unroll
    for (int mt = 0; mt < 4; ++mt) {
      ah[mt] = *(const short8*)(arp[mt] + ks * 32);
      al[mt] = *(const short8*)(arp[mt] + ks * 32 + 64);
      bh[mt] = *(const short8*)(brp[mt] + ks * 32);
      bl[mt] = *(const short8*)(brp[mt] + ks * 32 + 64);
    }
#pragma unroll
    for (int mt = 0; mt < 4; ++mt)
#pragma unroll
      for (int nt = 0; nt < 4; ++nt) {
        acc[mt][nt] = __builtin_amdgcn_mfma_f32_16x16x32_bf16(ah[mt], bh[nt], acc[mt][nt], 0, 0, 0);
        acc[mt][nt] = __builtin_amdgcn_mfma_f32_16x16x32_bf16(ah[mt], bl[nt], acc[mt][nt], 0, 0, 0);
        acc[mt][nt] = __builtin_amdgcn_mfma_f32_16x16x32_bf16(al[mt], bh[nt], acc[mt][nt], 0, 0, 0);
        acc[mt][nt] = __builtin_amdgcn_mfma_f32_16x16x32_bf16(al[mt], bl[nt], acc[mt][nt], 0, 0, 0);
      }
  }

  // epilogue: per output row, argmax over this wave's 64 cols
  const int gi4 = (L >> 4) * 4;
#pragma unroll
  for (int mt = 0; mt < 4; ++mt) {
#pragma unroll
    for (int reg = 0; reg < 4; ++reg) {
      int i = ii * 128 + wr * 64 + mt * 16 + gi4 + reg;
      float bm = -INFINITY;
      int bj = 0x7fffffff;
#pragma unroll
      for (int nt = 0; nt < 4; ++nt) {
        int j = bi * 128 + wc * 64 + nt * 16 + fr;
        float v = acc[mt][nt][reg];
        if (j < p2 && v > bm) { bm = v; bj = j; }
      }
#pragma unroll
      for (int mk = 1; mk < 16; mk <<= 1) {
        float om = __shfl_xor(bm, mk, 64);
        int oj = __shfl_xor(bj, mk, 64);
        if (om > bm || (om == bm && oj < bj)) { bm = om; bj = oj; }
      }
      if (fr == 0 && i < p2) {
        size_t o = ((size_t)b * 2304 + i) * jT2 + bi * 2 + wc;
        pm[o] = bm;
        pi[o] = bj;
      }
    }
  }
}

// argmax combine + build per-destination linked list (head[dst] -> chain via nxt[src])
__global__ void argmax_combine_kernel(const float* __restrict__ pm, const int* __restrict__ pi,
                                      int p2, int jT, float* __restrict__ nmax,
                                      int* __restrict__ nidx, int* __restrict__ head,
                                      int* __restrict__ nxt) {
  int g = blockIdx.x * 256 + threadIdx.x;
  if (g >= NB * p2) return;
  int b = g / p2, i = g - b * p2;
  const float* r = pm + ((size_t)b * 2304 + i) * jT;
  const int* ri = pi + ((size_t)b * 2304 + i) * jT;
  float best = r[0];
  int bidx = ri[0];
  for (int k = 1; k < jT; ++k) {
    if (r[k] > best || (r[k] == best && ri[k] < bidx)) { best = r[k]; bidx = ri[k]; }
  }
  nmax[g] = best;
  nidx[g] = bidx;
  int d = bidx;
  if ((unsigned)d >= (unsigned)p2) d = 0;
  nxt[g] = atomicExch(&head[(size_t)b * p2 + d], i);
}

__global__ void init_heads_kernel(int* __restrict__ h, int n) {
  int g = blockIdx.x * 256 + threadIdx.x;
  if (g < n) h[g] = -1;
}

// ---------------- fused merge (gather form): out[j] = (odd + sum(evens)) / count ----------------
__global__ __launch_bounds__(256) void merge_gather_in(const void* __restrict__ x,
                                                       const void* __restrict__ pos,
                                                       const int* __restrict__ mode,
                                                       const int* __restrict__ head,
                                                       const int* __restrict__ nxt,
                                                       float* __restrict__ xo,
                                                       float* __restrict__ so, int p2) {
  int tj = blockIdx.x;
  int b = tj / p2, j = tj - b * p2;
  int c = threadIdx.x * 4;
  int md = *mode;
  __shared__ int sl[64];
  __shared__ int s_n, s_cur;
  size_t xb = ((size_t)b * P0 + 2 * j + 1) * C0 + c;
  size_t pb = (size_t)(2 * j + 1) * C0 + c;
  float4 xa = load4(x, xb, md), pa = load4(pos, pb, md);
  float4 acc = {xa.x + pa.x, xa.y + pa.y, xa.z + pa.z, xa.w + pa.w};
  float cnt = 1.f;
  if (threadIdx.x == 0) s_cur = head[tj];
  __syncthreads();
  int cur = s_cur;
  while (cur != -1) {
    if (threadIdx.x == 0) {
      int n = 0, cc = cur;
      while (cc != -1 && n < 64) {
        sl[n++] = cc;
        cc = nxt[(size_t)b * p2 + cc];
      }
      s_n = n;
      s_cur = cc;
    }
    __syncthreads();
    int n = s_n;
    cur = s_cur;
    for (int k = 0; k < n; ++k) {
      int i = sl[k];
      size_t exb = ((size_t)b * P0 + 2 * i) * C0 + c;
      size_t epb = (size_t)(2 * i) * C0 + c;
      float4 ea = load4(x, exb, md), ep = load4(pos, epb, md);
      acc.x += ea.x + ep.x;
      acc.y += ea.y + ep.y;
      acc.z += ea.z + ep.z;
      acc.w += ea.w + ep.w;
      cnt += 1.f;
    }
    __syncthreads();
  }
  float inv = 1.f / cnt;
  float4 o = {acc.x * inv, acc.y * inv, acc.z * inv, acc.w * inv};
  *(float4*)(xo + (size_t)tj * C0 + c) = o;
  if (threadIdx.x == 0) so[tj] = cnt;
}

__global__ __launch_bounds__(256) void merge_gather_f(const float* __restrict__ xi,
                                                      const float* __restrict__ si,
                                                      const int* __restrict__ head,
                                                      const int* __restrict__ nxt,
                                                      float* __restrict__ xo,
                                                      float* __restrict__ so, int p, int p2) {
  int tj = blockIdx.x;
  int b = tj / p2, j = tj - b * p2;
  int c = threadIdx.x * 4;
  __shared__ int sl[64];
  __shared__ int s_n, s_cur;
  float sz = si[(size_t)b * p + 2 * j + 1];
  float4 v = *(const float4*)(xi + ((size_t)b * p + 2 * j + 1) * C0 + c);
  float4 acc = {v.x * sz, v.y * sz, v.z * sz, v.w * sz};
  float ssum = sz;
  if (threadIdx.x == 0) s_cur = head[tj];
  __syncthreads();
  int cur = s_cur;
  while (cur != -1) {
    if (threadIdx.x == 0) {
      int n = 0, cc = cur;
      while (cc != -1 && n < 64) {
        sl[n++] = cc;
        cc = nxt[(size_t)b * p2 + cc];
      }
      s_n = n;
      s_cur = cc;
    }
    __syncthreads();
    int n = s_n;
    cur = s_cur;
    for (int k = 0; k < n; ++k) {
      int i = sl[k];
      float szi = si[(size_t)b * p + 2 * i];
      float4 e = *(const float4*)(xi + ((size_t)b * p + 2 * i) * C0 + c);
      acc.x += e.x * szi;
      acc.y += e.y * szi;
      acc.z += e.z * szi;
      acc.w += e.w * szi;
      ssum += szi;
    }
    __syncthreads();
  }
  float inv = 1.f / ssum;
  float4 o = {acc.x * inv, acc.y * inv, acc.z * inv, acc.w * inv};
  *(float4*)(xo + (size_t)tj * C0 + c) = o;
  if (threadIdx.x == 0) so[tj] = ssum;
}

// ---------------- last iteration (p=144, p2=72, r=16): stable descending rank ----------------
__global__ void rank_kernel(const float* __restrict__ nmax, const int* __restrict__ nidx,
                            int* __restrict__ unm_map, int* __restrict__ src_ord,
                            int* __restrict__ src_dst) {
  int b = blockIdx.x;
  int i = threadIdx.x;
  __shared__ float v[72];
  __shared__ int nx[72];
  if (i < 72) { v[i] = nmax[b * 72 + i]; nx[i] = nidx[b * 72 + i]; }
  __syncthreads();
  if (i < 72) {
    float vi = v[i];
    int rank = 0;
    for (int k = 0; k < 72; ++k) {
      float vk = v[k];
      rank += (vk > vi) || (vk == vi && k < i);
    }
    if (rank < 16) {
      int d = nx[i];
      if ((unsigned)d >= 72u) d = 0;
      src_ord[b * 16 + rank] = i;
      src_dst[b * 16 + rank] = d;
    } else {
      unm_map[b * 56 + (rank - 16)] = i;
    }
  }
}

__global__ void final_init(const float* __restrict__ x5, const float* __restrict__ s5,
                           const int* __restrict__ unm_map, float* __restrict__ xf,
                           float* __restrict__ sf) {
  int bt = blockIdx.x;
  int b = bt >> 7, tk = bt & 127;
  int c = threadIdx.x * 4;
  float4 o;
  float szo;
  if (tk < 56) {
    int se = unm_map[b * 56 + tk];
    if ((unsigned)se >= 72u) se = 0;
    o = *(const float4*)(x5 + ((size_t)b * 144 + 2 * se) * C0 + c);
    szo = 1.f;
  } else {
    int j = tk - 56;
    float sz = s5[b * 144 + 2 * j + 1];
    float4 v = *(const float4*)(x5 + ((size_t)b * 144 + 2 * j + 1) * C0 + c);
    o.x = v.x * sz; o.y = v.y * sz; o.z = v.z * sz; o.w = v.w * sz;
    szo = sz;
  }
  *(float4*)(xf + (size_t)bt * C0 + c) = o;
  if (threadIdx.x == 0) sf[bt] = szo;
}

__global__ void final_scatter(const float* __restrict__ x5, const float* __restrict__ s5,
                              const int* __restrict__ src_ord, const int* __restrict__ src_dst,
                              float* __restrict__ xf, float* __restrict__ sf) {
  int bk = blockIdx.x;
  int b = bk >> 4, k = bk & 15;
  int c = threadIdx.x * 4;
  int st = src_ord[b * 16 + k], dst = src_dst[b * 16 + k];
  if ((unsigned)st >= 72u) st = 0;
  if ((unsigned)dst >= 72u) dst = 0;
  float sz = s5[b * 144 + 2 * st];
  float4 v = *(const float4*)(x5 + ((size_t)b * 144 + 2 * st) * C0 + c);
  float* out = xf + ((size_t)(b * 128 + 56 + dst)) * C0 + c;
  atomicAdd(out + 0, v.x * sz);
  atomicAdd(out + 1, v.y * sz);
  atomicAdd(out + 2, v.z * sz);
  atomicAdd(out + 3, v.w * sz);
  if (threadIdx.x == 0) atomicAdd(sf + b * 128 + 56 + dst, sz);
}

__global__ void final_div_cvt(const float* __restrict__ xf, const float* __restrict__ sf,
                              __hip_bfloat16* __restrict__ xb) {
  int bt = blockIdx.x;
  int c = threadIdx.x * 4;
  float sz = sf[bt];
  float4 v = *(const float4*)(xf + (size_t)bt * C0 + c);
  __hip_bfloat16* o = xb + (size_t)bt * C0 + c;
  o[0] = __float2bfloat16(v.x / sz);
  o[1] = __float2bfloat16(v.y / sz);
  o[2] = __float2bfloat16(v.z / sz);
  o[3] = __float2bfloat16(v.w / sz);
}

// ---------------- dual-dtype transpose (KxN -> NxK), output bf16 ----------------
__global__ void transpose_in(const void* __restrict__ in, const int* __restrict__ mode,
                             u16* __restrict__ out, int K, int N) {
  __shared__ u16 tile[64][65];
  int n0 = blockIdx.x * 64, k0 = blockIdx.y * 64;
  int t = threadIdx.x;
  int md = *mode;
  int r = t >> 4, c4 = (t & 15) * 4;
#pragma unroll
  for (int pass = 0; pass < 4; ++pass) {
    int row = r + pass * 16;
#pragma unroll
    for (int e = 0; e < 4; ++e) {
      float v = load_in(in, (size_t)(k0 + row) * N + n0 + c4 + e, md);
      __hip_bfloat16 bv = __float2bfloat16(v);
      tile[row][c4 + e] = *(u16*)&bv;
    }
  }
  __syncthreads();
#pragma unroll
  for (int pass = 0; pass < 4; ++pass) {
    int row = r + pass * 16;
    ushort4 o;
    o.x = tile[c4][row]; o.y = tile[c4 + 1][row]; o.z = tile[c4 + 2][row]; o.w = tile[c4 + 3][row];
    *(ushort4*)(out + (size_t)(n0 + row) * K + k0 + c4) = o;
  }
}

// ---------------- bf16 MFMA GEMM, B pre-transposed (NT), 64x128 tile, 2-phase gload_lds dbuf ----------------
#define GL2LDS(gp, lp)                                                                   \
  __builtin_amdgcn_global_load_lds((const __attribute__((address_space(1))) uint32_t*)(gp), \
                                   (__attribute__((address_space(3))) uint32_t*)(lp), 16, 0, 0)

__global__ __launch_bounds__(256) void gemm_bt(const u16* __restrict__ A,
                                               const u16* __restrict__ BT,
                                               const void* __restrict__ bias,
                                               const int* __restrict__ mode,
                                               void* __restrict__ C, int M, int N,
                                               int K, int act, int out_sel) {
  __shared__ __align__(16) u16 As[2 * 64 * 64];
  __shared__ __align__(16) u16 Bs[2 * 128 * 64];
  const int t = threadIdx.x, w = t >> 6, L = t & 63;
  const int m0 = blockIdx.y * 64, n0 = blockIdx.x * 128;
  const int wr = w >> 1, wc = w & 1;
  const int md = *mode;
  const int fr = L & 15, fq = (L >> 4) * 8;
  const int trow = t >> 3, tc8 = (t & 7) * 8;
  floatx4 acc[2][4];
#pragma unroll
  for (int a = 0; a < 2; ++a)
#pragma unroll
    for (int bb = 0; bb < 4; ++bb) acc[a][bb] = (floatx4){0.f, 0.f, 0.f, 0.f};

  auto stage = [&](int buf, int kk) {
#pragma unroll
    for (int q = 0; q < 2; ++q)
      GL2LDS(A + (size_t)(m0 + q * 32 + trow) * K + kk + tc8,
             As + buf * 4096 + q * 2048 + t * 8);
#pragma unroll
    for (int q = 0; q < 4; ++q)
      GL2LDS(BT + (size_t)(n0 + q * 32 + trow) * K + kk + tc8,
             Bs + buf * 8192 + q * 2048 + t * 8);
  };

  stage(0, 0);
  asm volatile("s_waitcnt vmcnt(0)" ::: "memory");
  __builtin_amdgcn_s_barrier();
  int cur = 0;
  for (int k0 = 0; k0 < K; k0 += 64) {
    int kn = k0 + 64;
    if (kn < K) stage(cur ^ 1, kn);  // next-tile loads fly under current compute
    const u16* Ab = As + cur * 4096;
    const u16* Bb = Bs + cur * 8192;
#pragma unroll
    for (int kh = 0; kh < 2; ++kh) {
      short8 af[2], bfr[4];
#pragma unroll
      for (int mt = 0; mt < 2; ++mt)
        af[mt] = *(const short8*)(Ab + (wr * 32 + mt * 16 + fr) * 64 + kh * 32 + fq);
#pragma unroll
      for (int nt = 0; nt < 4; ++nt)
        bfr[nt] = *(const short8*)(Bb + (wc * 64 + nt * 16 + fr) * 64 + kh * 32 + fq);
#pragma unroll
      for (int mt = 0; mt < 2; ++mt)
#pragma unroll
        for (int nt = 0; nt < 4; ++nt)
          acc[mt][nt] =
              __builtin_amdgcn_mfma_f32_16x16x32_bf16(af[mt], bfr[nt], acc[mt][nt], 0, 0, 0);
    }
    asm volatile("s_waitcnt vmcnt(0)" ::: "memory");
    __builtin_amdgcn_s_barrier();
    cur ^= 1;
  }
  const int gi4 = (L >> 4) * 4;
#pragma unroll
  for (int mt = 0; mt < 2; ++mt)
#pragma unroll
    for (int nt = 0; nt < 4; ++nt) {
      int n = n0 + wc * 64 + nt * 16 + fr;
      float bz = load_in(bias, n, md);
#pragma unroll
      for (int rr = 0; rr < 4; ++rr) {
        int m = m0 + wr * 32 + mt * 16 + gi4 + rr;
        float v = acc[mt][nt][rr] + bz;
        if (act) v = 0.5f * v * (1.f + erff(v * 0.70710678118654752f));
        size_t idx = (size_t)m * N + n;
        if (out_sel == 0 || md) {
          __hip_bfloat16 bv = __float2bfloat16(v);
          ((u16*)C)[idx] = *(u16*)&bv;
        } else {
          ((float*)C)[idx] = v;
        }
      }
    }
}

// ---------------- host ----------------
extern "C" void kernel_launch(void* const* d_in, const int* in_sizes, int n_in, void* d_out,
                              int out_size, void* d_ws, size_t ws_size, hipStream_t stream) {
  const void* x = d_in[0];
  const void* pe = d_in[1];
  const void* W1 = d_in[2];
  const void* b1 = d_in[3];
  const void* W2 = d_in[4];
  const void* b2 = d_in[5];

  char* base = (char*)d_ws;
  size_t off = 0;
  auto alloc = [&](size_t bytes) -> void* {
    void* p = base + off;
    off += (bytes + 255) & ~(size_t)255;
    return p;
  };
  int* mode = (int*)alloc(256);
  u16* m2 = (u16*)alloc((size_t)NB * 4608 * 128 * 2);  // bf16 hi/lo split metric
  float* pm = (float*)alloc((size_t)NB * 2304 * 36 * 4);
  int* pi = (int*)alloc((size_t)NB * 2304 * 36 * 4);
  float* nmax = (float*)alloc((size_t)NB * 2304 * 4);
  int* nidx = (int*)alloc((size_t)NB * 2304 * 4);
  float* bufA = (float*)alloc((size_t)NB * 2304 * C0 * 4);
  float* bufB = (float*)alloc((size_t)NB * 1152 * C0 * 4);
  float* s1 = (float*)alloc((size_t)NB * 2304 * 4);
  float* s2 = (float*)alloc((size_t)NB * 1152 * 4);
  float* s3 = (float*)alloc((size_t)NB * 576 * 4);
  float* s4 = (float*)alloc((size_t)NB * 288 * 4);
  float* s5 = (float*)alloc((size_t)NB * 144 * 4);
  float* sf = (float*)alloc((size_t)NB * 128 * 4);
  int* unm_map = (int*)alloc((size_t)NB * 56 * 4);
  int* src_ord = (int*)alloc((size_t)NB * 16 * 4);
  int* src_dst = (int*)alloc((size_t)NB * 16 * 4);
  u16* xfb = (u16*)alloc((size_t)NB * 128 * C0 * 2);
  u16* hbuf = (u16*)alloc((size_t)1024 * H0 * 2);
  u16* w1t = (u16*)alloc((size_t)H0 * C0 * 2);
  u16* w2t = (u16*)alloc((size_t)H0 * H0 * 2);
  // linked-list buffers: heads per iteration (2304+1152+576+288+144+72 = 4536), one nxt buffer
  int* heads = (int*)alloc((size_t)NB * 4536 * 4);
  int* nxt = (int*)alloc((size_t)NB * 2304 * 4);
  if (off > ws_size) return;

  int* h_it[6];
  h_it[0] = heads;
  h_it[1] = h_it[0] + NB * 2304;
  h_it[2] = h_it[1] + NB * 1152;
  h_it[3] = h_it[2] + NB * 576;
  h_it[4] = h_it[3] + NB * 288;
  h_it[5] = h_it[4] + NB * 144;

  float* x1 = bufA;
  float* x2 = bufB;
  float* x3 = bufA;
  float* x4 = bufB;
  float* x5 = bufA;
  float* xf = bufB;

  detect_mode_kernel<<<1, 1, 0, stream>>>((const uint32_t*)pe, mode);
  init_heads_kernel<<<(NB * 4536 + 255) / 256, 256, 0, stream>>>(heads, NB * 4536);

  // weight transposes (W is KxN row-major -> NxK bf16)
  transpose_in<<<dim3(4096 / 64, 1024 / 64), 256, 0, stream>>>(W1, mode, w1t, 1024, 4096);
  transpose_in<<<dim3(4096 / 64, 4096 / 64), 256, 0, stream>>>(W2, mode, w2t, 4096, 4096);

  // ---- iter 1: p=4608 -> p2=2304 (all evens merge)
  metric_in_kernel<<<NB * P0 / 4, 256, 0, stream>>>(x, pe, mode, m2);
  score_mfma_kernel<<<dim3(18, 18, NB), 256, 0, stream>>>(m2, 4608, 2304, 36, pm, pi);
  argmax_combine_kernel<<<(NB * 2304 + 255) / 256, 256, 0, stream>>>(pm, pi, 2304, 36, nmax,
                                                                     nidx, h_it[0], nxt);
  merge_gather_in<<<NB * 2304, 256, 0, stream>>>(x, pe, mode, h_it[0], nxt, x1, s1, 2304);

  // ---- iters 2..5 (generic all-evens-merge)
  float* xs_in[4] = {x1, x2, x3, x4};
  float* ss_in[4] = {s1, s2, s3, s4};
  float* xs_out[4] = {x2, x3, x4, x5};
  float* ss_out[4] = {s2, s3, s4, s5};
  int ps[5] = {2304, 1152, 576, 288, 144};
  for (int it = 0; it < 4; ++it) {
    int p = ps[it], p2 = ps[it + 1];
    int iT = (p2 + 127) / 128, jT = (p2 + 127) / 128;
    metric_f32_kernel<<<NB * p / 4, 256, 0, stream>>>(xs_in[it], m2, p);
    score_mfma_kernel<<<dim3(jT, iT, NB), 256, 0, stream>>>(m2, p, p2, 2 * jT, pm, pi);
    argmax_combine_kernel<<<(NB * p2 + 255) / 256, 256, 0, stream>>>(pm, pi, p2, 2 * jT, nmax,
                                                                     nidx, h_it[it + 1], nxt);
    merge_gather_f<<<NB * p2, 256, 0, stream>>>(xs_in[it], ss_in[it], h_it[it + 1], nxt,
                                                xs_out[it], ss_out[it], p, p2);
  }

  // ---- iter 6: p=144, p2=72, r=16 -> 128 tokens
  metric_f32_kernel<<<NB * 144 / 4, 256, 0, stream>>>(x5, m2, 144);
  score_mfma_kernel<<<dim3(1, 1, NB), 256, 0, stream>>>(m2, 144, 72, 2, pm, pi);
  argmax_combine_kernel<<<(NB * 72 + 255) / 256, 256, 0, stream>>>(pm, pi, 72, 2, nmax, nidx,
                                                                   h_it[5], nxt);
  rank_kernel<<<NB, 128, 0, stream>>>(nmax, nidx, unm_map, src_ord, src_dst);
  final_init<<<NB * 128, 256, 0, stream>>>(x5, s5, unm_map, xf, sf);
  final_scatter<<<NB * 16, 256, 0, stream>>>(x5, s5, src_ord, src_dst, xf, sf);
  final_div_cvt<<<NB * 128, 256, 0, stream>>>(xf, sf, (__hip_bfloat16*)xfb);

  // ---- MLP: h = gelu(x@W1 + b1); out = h@W2 + b2
  gemm_bt<<<dim3(4096 / 128, 1024 / 64), 256, 0, stream>>>(xfb, w1t, b1, mode, hbuf, 1024, 4096,
                                                           1024, 1, 0);
  gemm_bt<<<dim3(4096 / 128, 1024 / 64), 256, 0, stream>>>(hbuf, w2t, b2, mode, d_out, 1024,
                                                           4096, 4096, 0, 1);
}

// Round 4
// 782.113 us; speedup vs baseline: 1.8522x; 1.0162x over previous
//
#include <hip/hip_runtime.h>
#include <hip/hip_bf16.h>
#include <math.h>
#include <stdint.h>

typedef unsigned short u16;
typedef __attribute__((ext_vector_type(8))) short short8;
typedef __attribute__((ext_vector_type(4))) float floatx4;

#define NB 8
#define P0 4608
#define C0 1024
#define H0 4096

// mode: 0 = inputs/outputs are float32, 1 = bf16
__global__ void detect_mode_kernel(const uint32_t* __restrict__ pe_words, int* __restrict__ mode) {
  *mode = (pe_words[64] != 0u) ? 1 : 0;
}

__device__ __forceinline__ float load_in(const void* p, size_t idx, int mode) {
  if (mode) return __bfloat162float(((const __hip_bfloat16*)p)[idx]);
  return ((const float*)p)[idx];
}

__device__ __forceinline__ float4 load4(const void* p, size_t idx, int mode) {
  float4 r;
  if (mode) {
    ushort4 u = *(const ushort4*)((const u16*)p + idx);
    r.x = __bfloat162float(*(__hip_bfloat16*)&u.x);
    r.y = __bfloat162float(*(__hip_bfloat16*)&u.y);
    r.z = __bfloat162float(*(__hip_bfloat16*)&u.z);
    r.w = __bfloat162float(*(__hip_bfloat16*)&u.w);
  } else {
    r = *(const float4*)((const float*)p + idx);
  }
  return r;
}

__device__ __forceinline__ void write_hilo(u16* __restrict__ m2, size_t tok, int lane, float v) {
  __hip_bfloat16 hi = __float2bfloat16(v);
  float hif = __bfloat162float(hi);
  __hip_bfloat16 lo = __float2bfloat16(v - hif);
  m2[tok * 128 + lane] = *(u16*)&hi;
  m2[tok * 128 + 64 + lane] = *(u16*)&lo;
}

// ---------------- metric: mean over 16 heads of 64-dim chunks, L2 normalize, bf16 hi/lo split ----------------
__global__ void metric_in_kernel(const void* __restrict__ x, const void* __restrict__ pos,
                                 const int* __restrict__ mode, u16* __restrict__ m2) {
  int tok = blockIdx.x * 4 + (threadIdx.x >> 6);
  int lane = threadIdx.x & 63;
  if (tok >= NB * P0) return;
  int b = tok / P0, t = tok - b * P0;
  int md = *mode;
  size_t xbase = ((size_t)b * P0 + t) * C0 + lane;
  size_t pbase = (size_t)t * C0 + lane;
  float s = 0.f;
#pragma unroll
  for (int h = 0; h < 16; ++h)
    s += load_in(x, xbase + h * 64, md) + load_in(pos, pbase + h * 64, md);
  s *= (1.f / 16.f);
  float sq = s * s;
#pragma unroll
  for (int off = 1; off < 64; off <<= 1) sq += __shfl_xor(sq, off, 64);
  write_hilo(m2, (size_t)tok, lane, s / sqrtf(sq));
}

__global__ void metric_f32_kernel(const float* __restrict__ x, u16* __restrict__ m2, int p) {
  int tok = blockIdx.x * 4 + (threadIdx.x >> 6);
  int lane = threadIdx.x & 63;
  if (tok >= NB * p) return;
  const float* xr = x + (size_t)tok * C0 + lane;
  float s = 0.f;
#pragma unroll
  for (int h = 0; h < 16; ++h) s += xr[h * 64];
  s *= (1.f / 16.f);
  float sq = s * s;
#pragma unroll
  for (int off = 1; off < 64; off <<= 1) sq += __shfl_xor(sq, off, 64);
  write_hilo(m2, (size_t)tok, lane, s / sqrtf(sq));
}

// ---------------- scores via bf16x4 split-precision MFMA + per-(row, 64-col) argmax partials ----------------
__global__ __launch_bounds__(256) void score_mfma_kernel(const u16* __restrict__ M2,
                                                         int p, int p2, int jT2,
                                                         float* __restrict__ pm,
                                                         int* __restrict__ pi) {
  const int bi = blockIdx.x, ii = blockIdx.y, b = blockIdx.z;
  const int t = threadIdx.x, w = t >> 6, L = t & 63;
  const int wr = w >> 1, wc = w & 1;
  const int fr = L & 15, fo = (L >> 4) * 8;
  const u16* Mb = M2 + (size_t)b * p * 128;

  floatx4 acc[4][4];
#pragma unroll
  for (int mt = 0; mt < 4; ++mt)
#pragma unroll
    for (int nt = 0; nt < 4; ++nt) acc[mt][nt] = (floatx4){0.f, 0.f, 0.f, 0.f};

  const u16* arp[4];
  const u16* brp[4];
#pragma unroll
  for (int mt = 0; mt < 4; ++mt) {
    int i = ii * 128 + wr * 64 + mt * 16 + fr;
    int ta = 2 * i;
    if (ta > p - 2) ta = p - 2;
    arp[mt] = Mb + (size_t)ta * 128 + fo;
    int j = bi * 128 + wc * 64 + mt * 16 + fr;
    int tb = 2 * j + 1;
    if (tb > p - 1) tb = p - 1;
    brp[mt] = Mb + (size_t)tb * 128 + fo;
  }

#pragma unroll
  for (int ks = 0; ks < 2; ++ks) {
    short8 ah[4], al[4], bh[4], bl[4];
#pragma unroll
    for (int mt = 0; mt < 4; ++mt) {
      ah[mt] = *(const short8*)(arp[mt] + ks * 32);
      al[mt] = *(const short8*)(arp[mt] + ks * 32 + 64);
      bh[mt] = *(const short8*)(brp[mt] + ks * 32);
      bl[mt] = *(const short8*)(brp[mt] + ks * 32 + 64);
    }
#pragma unroll
    for (int mt = 0; mt < 4; ++mt)
#pragma unroll
      for (int nt = 0; nt < 4; ++nt) {
        acc[mt][nt] = __builtin_amdgcn_mfma_f32_16x16x32_bf16(ah[mt], bh[nt], acc[mt][nt], 0, 0, 0);
        acc[mt][nt] = __builtin_amdgcn_mfma_f32_16x16x32_bf16(ah[mt], bl[nt], acc[mt][nt], 0, 0, 0);
        acc[mt][nt] = __builtin_amdgcn_mfma_f32_16x16x32_bf16(al[mt], bh[nt], acc[mt][nt], 0, 0, 0);
        acc[mt][nt] = __builtin_amdgcn_mfma_f32_16x16x32_bf16(al[mt], bl[nt], acc[mt][nt], 0, 0, 0);
      }
  }

  // epilogue: per output row, argmax over this wave's 64 cols
  const int gi4 = (L >> 4) * 4;
#pragma unroll
  for (int mt = 0; mt < 4; ++mt) {
#pragma unroll
    for (int reg = 0; reg < 4; ++reg) {
      int i = ii * 128 + wr * 64 + mt * 16 + gi4 + reg;
      float bm = -INFINITY;
      int bj = 0x7fffffff;
#pragma unroll
      for (int nt = 0; nt < 4; ++nt) {
        int j = bi * 128 + wc * 64 + nt * 16 + fr;
        float v = acc[mt][nt][reg];
        if (j < p2 && v > bm) { bm = v; bj = j; }
      }
#pragma unroll
      for (int mk = 1; mk < 16; mk <<= 1) {
        float om = __shfl_xor(bm, mk, 64);
        int oj = __shfl_xor(bj, mk, 64);
        if (om > bm || (om == bm && oj < bj)) { bm = om; bj = oj; }
      }
      if (fr == 0 && i < p2) {
        size_t o = ((size_t)b * 2304 + i) * jT2 + bi * 2 + wc;
        pm[o] = bm;
        pi[o] = bj;
      }
    }
  }
}

// argmax combine + build per-destination linked list (head[dst] -> chain via nxt[src])
__global__ void argmax_combine_kernel(const float* __restrict__ pm, const int* __restrict__ pi,
                                      int p2, int jT, float* __restrict__ nmax,
                                      int* __restrict__ nidx, int* __restrict__ head,
                                      int* __restrict__ nxt) {
  int g = blockIdx.x * 256 + threadIdx.x;
  if (g >= NB * p2) return;
  int b = g / p2, i = g - b * p2;
  const float* r = pm + ((size_t)b * 2304 + i) * jT;
  const int* ri = pi + ((size_t)b * 2304 + i) * jT;
  float best = r[0];
  int bidx = ri[0];
  for (int k = 1; k < jT; ++k) {
    if (r[k] > best || (r[k] == best && ri[k] < bidx)) { best = r[k]; bidx = ri[k]; }
  }
  nmax[g] = best;
  nidx[g] = bidx;
  int d = bidx;
  if ((unsigned)d >= (unsigned)p2) d = 0;
  nxt[g] = atomicExch(&head[(size_t)b * p2 + d], i);
}

__global__ void init_heads_kernel(int* __restrict__ h, int n) {
  int g = blockIdx.x * 256 + threadIdx.x;
  if (g < n) h[g] = -1;
}

// ---------------- fused merge (gather form): out[j] = (odd + sum(evens)) / count ----------------
__global__ __launch_bounds__(256) void merge_gather_in(const void* __restrict__ x,
                                                       const void* __restrict__ pos,
                                                       const int* __restrict__ mode,
                                                       const int* __restrict__ head,
                                                       const int* __restrict__ nxt,
                                                       float* __restrict__ xo,
                                                       float* __restrict__ so, int p2) {
  int tj = blockIdx.x;
  int b = tj / p2, j = tj - b * p2;
  int c = threadIdx.x * 4;
  int md = *mode;
  __shared__ int sl[64];
  __shared__ int s_n, s_cur;
  size_t xb = ((size_t)b * P0 + 2 * j + 1) * C0 + c;
  size_t pb = (size_t)(2 * j + 1) * C0 + c;
  float4 xa = load4(x, xb, md), pa = load4(pos, pb, md);
  float4 acc = {xa.x + pa.x, xa.y + pa.y, xa.z + pa.z, xa.w + pa.w};
  float cnt = 1.f;
  if (threadIdx.x == 0) s_cur = head[tj];
  __syncthreads();
  int cur = s_cur;
  while (cur != -1) {
    if (threadIdx.x == 0) {
      int n = 0, cc = cur;
      while (cc != -1 && n < 64) {
        sl[n++] = cc;
        cc = nxt[(size_t)b * p2 + cc];
      }
      s_n = n;
      s_cur = cc;
    }
    __syncthreads();
    int n = s_n;
    cur = s_cur;
    for (int k = 0; k < n; ++k) {
      int i = sl[k];
      size_t exb = ((size_t)b * P0 + 2 * i) * C0 + c;
      size_t epb = (size_t)(2 * i) * C0 + c;
      float4 ea = load4(x, exb, md), ep = load4(pos, epb, md);
      acc.x += ea.x + ep.x;
      acc.y += ea.y + ep.y;
      acc.z += ea.z + ep.z;
      acc.w += ea.w + ep.w;
      cnt += 1.f;
    }
    __syncthreads();
  }
  float inv = 1.f / cnt;
  float4 o = {acc.x * inv, acc.y * inv, acc.z * inv, acc.w * inv};
  *(float4*)(xo + (size_t)tj * C0 + c) = o;
  if (threadIdx.x == 0) so[tj] = cnt;
}

__global__ __launch_bounds__(256) void merge_gather_f(const float* __restrict__ xi,
                                                      const float* __restrict__ si,
                                                      const int* __restrict__ head,
                                                      const int* __restrict__ nxt,
                                                      float* __restrict__ xo,
                                                      float* __restrict__ so, int p, int p2) {
  int tj = blockIdx.x;
  int b = tj / p2, j = tj - b * p2;
  int c = threadIdx.x * 4;
  __shared__ int sl[64];
  __shared__ int s_n, s_cur;
  float sz = si[(size_t)b * p + 2 * j + 1];
  float4 v = *(const float4*)(xi + ((size_t)b * p + 2 * j + 1) * C0 + c);
  float4 acc = {v.x * sz, v.y * sz, v.z * sz, v.w * sz};
  float ssum = sz;
  if (threadIdx.x == 0) s_cur = head[tj];
  __syncthreads();
  int cur = s_cur;
  while (cur != -1) {
    if (threadIdx.x == 0) {
      int n = 0, cc = cur;
      while (cc != -1 && n < 64) {
        sl[n++] = cc;
        cc = nxt[(size_t)b * p2 + cc];
      }
      s_n = n;
      s_cur = cc;
    }
    __syncthreads();
    int n = s_n;
    cur = s_cur;
    for (int k = 0; k < n; ++k) {
      int i = sl[k];
      float szi = si[(size_t)b * p + 2 * i];
      float4 e = *(const float4*)(xi + ((size_t)b * p + 2 * i) * C0 + c);
      acc.x += e.x * szi;
      acc.y += e.y * szi;
      acc.z += e.z * szi;
      acc.w += e.w * szi;
      ssum += szi;
    }
    __syncthreads();
  }
  float inv = 1.f / ssum;
  float4 o = {acc.x * inv, acc.y * inv, acc.z * inv, acc.w * inv};
  *(float4*)(xo + (size_t)tj * C0 + c) = o;
  if (threadIdx.x == 0) so[tj] = ssum;
}

// ---------------- last iteration (p=144, p2=72, r=16): stable descending rank ----------------
__global__ void rank_kernel(const float* __restrict__ nmax, const int* __restrict__ nidx,
                            int* __restrict__ unm_map, int* __restrict__ src_ord,
                            int* __restrict__ src_dst) {
  int b = blockIdx.x;
  int i = threadIdx.x;
  __shared__ float v[72];
  __shared__ int nx[72];
  if (i < 72) { v[i] = nmax[b * 72 + i]; nx[i] = nidx[b * 72 + i]; }
  __syncthreads();
  if (i < 72) {
    float vi = v[i];
    int rank = 0;
    for (int k = 0; k < 72; ++k) {
      float vk = v[k];
      rank += (vk > vi) || (vk == vi && k < i);
    }
    if (rank < 16) {
      int d = nx[i];
      if ((unsigned)d >= 72u) d = 0;
      src_ord[b * 16 + rank] = i;
      src_dst[b * 16 + rank] = d;
    } else {
      unm_map[b * 56 + (rank - 16)] = i;
    }
  }
}

__global__ void final_init(const float* __restrict__ x5, const float* __restrict__ s5,
                           const int* __restrict__ unm_map, float* __restrict__ xf,
                           float* __restrict__ sf) {
  int bt = blockIdx.x;
  int b = bt >> 7, tk = bt & 127;
  int c = threadIdx.x * 4;
  float4 o;
  float szo;
  if (tk < 56) {
    int se = unm_map[b * 56 + tk];
    if ((unsigned)se >= 72u) se = 0;
    o = *(const float4*)(x5 + ((size_t)b * 144 + 2 * se) * C0 + c);
    szo = 1.f;
  } else {
    int j = tk - 56;
    float sz = s5[b * 144 + 2 * j + 1];
    float4 v = *(const float4*)(x5 + ((size_t)b * 144 + 2 * j + 1) * C0 + c);
    o.x = v.x * sz; o.y = v.y * sz; o.z = v.z * sz; o.w = v.w * sz;
    szo = sz;
  }
  *(float4*)(xf + (size_t)bt * C0 + c) = o;
  if (threadIdx.x == 0) sf[bt] = szo;
}

__global__ void final_scatter(const float* __restrict__ x5, const float* __restrict__ s5,
                              const int* __restrict__ src_ord, const int* __restrict__ src_dst,
                              float* __restrict__ xf, float* __restrict__ sf) {
  int bk = blockIdx.x;
  int b = bk >> 4, k = bk & 15;
  int c = threadIdx.x * 4;
  int st = src_ord[b * 16 + k], dst = src_dst[b * 16 + k];
  if ((unsigned)st >= 72u) st = 0;
  if ((unsigned)dst >= 72u) dst = 0;
  float sz = s5[b * 144 + 2 * st];
  float4 v = *(const float4*)(x5 + ((size_t)b * 144 + 2 * st) * C0 + c);
  float* out = xf + ((size_t)(b * 128 + 56 + dst)) * C0 + c;
  atomicAdd(out + 0, v.x * sz);
  atomicAdd(out + 1, v.y * sz);
  atomicAdd(out + 2, v.z * sz);
  atomicAdd(out + 3, v.w * sz);
  if (threadIdx.x == 0) atomicAdd(sf + b * 128 + 56 + dst, sz);
}

__global__ void final_div_cvt(const float* __restrict__ xf, const float* __restrict__ sf,
                              __hip_bfloat16* __restrict__ xb) {
  int bt = blockIdx.x;
  int c = threadIdx.x * 4;
  float sz = sf[bt];
  float4 v = *(const float4*)(xf + (size_t)bt * C0 + c);
  __hip_bfloat16* o = xb + (size_t)bt * C0 + c;
  o[0] = __float2bfloat16(v.x / sz);
  o[1] = __float2bfloat16(v.y / sz);
  o[2] = __float2bfloat16(v.z / sz);
  o[3] = __float2bfloat16(v.w / sz);
}

// ---------------- dual-dtype transpose (KxN -> NxK), output bf16 ----------------
__global__ void transpose_in(const void* __restrict__ in, const int* __restrict__ mode,
                             u16* __restrict__ out, int K, int N) {
  __shared__ u16 tile[64][65];
  int n0 = blockIdx.x * 64, k0 = blockIdx.y * 64;
  int t = threadIdx.x;
  int md = *mode;
  int r = t >> 4, c4 = (t & 15) * 4;
#pragma unroll
  for (int pass = 0; pass < 4; ++pass) {
    int row = r + pass * 16;
#pragma unroll
    for (int e = 0; e < 4; ++e) {
      float v = load_in(in, (size_t)(k0 + row) * N + n0 + c4 + e, md);
      __hip_bfloat16 bv = __float2bfloat16(v);
      tile[row][c4 + e] = *(u16*)&bv;
    }
  }
  __syncthreads();
#pragma unroll
  for (int pass = 0; pass < 4; ++pass) {
    int row = r + pass * 16;
    ushort4 o;
    o.x = tile[c4][row]; o.y = tile[c4 + 1][row]; o.z = tile[c4 + 2][row]; o.w = tile[c4 + 3][row];
    *(ushort4*)(out + (size_t)(n0 + row) * K + k0 + c4) = o;
  }
}

// ---------------- bf16 MFMA GEMM, B pre-transposed (NT), 64x128 tile ----------------
// 2-phase dbuf with counted vmcnt (T4) + XOR LDS swizzle via pre-swizzled global source (T2,
// rule-21: linear gload_lds dest + inverse-swizzled source + swizzled read) + setprio (T5).
#define GL2LDS(gp, lp)                                                                   \
  __builtin_amdgcn_global_load_lds((const __attribute__((address_space(1))) uint32_t*)(gp), \
                                   (__attribute__((address_space(3))) uint32_t*)(lp), 16, 0, 0)

__global__ __launch_bounds__(256, 2) void gemm_bt(const u16* __restrict__ A,
                                                  const u16* __restrict__ BT,
                                                  const void* __restrict__ bias,
                                                  const int* __restrict__ mode,
                                                  void* __restrict__ C, int M, int N,
                                                  int K, int act, int out_sel) {
  __shared__ __align__(16) u16 As[2 * 64 * 64];
  __shared__ __align__(16) u16 Bs[2 * 128 * 64];
  const int t = threadIdx.x, w = t >> 6, L = t & 63;
  const int m0 = blockIdx.y * 64, n0 = blockIdx.x * 128;
  const int wr = w >> 1, wc = w & 1;
  const int md = *mode;
  const int fr = L & 15, fq = (L >> 4) * 8;
  floatx4 acc[2][4];
#pragma unroll
  for (int a = 0; a < 2; ++a)
#pragma unroll
    for (int bb = 0; bb < 4; ++bb) acc[a][bb] = (floatx4){0.f, 0.f, 0.f, 0.f};

  // stage: LDS dest linear (granule g = q*256+t, 16B each); global source column
  // pre-swizzled colg' = colg ^ (row&7) so that swizzled reads see logical data.
  auto stage = [&](int buf, int kk) {
#pragma unroll
    for (int q = 0; q < 2; ++q) {
      int g = q * 256 + t;
      int row = g >> 3, colg = (g & 7) ^ (row & 7);
      GL2LDS(A + (size_t)(m0 + row) * K + kk + colg * 8, As + buf * 4096 + g * 8);
    }
#pragma unroll
    for (int q = 0; q < 4; ++q) {
      int g = q * 256 + t;
      int row = g >> 3, colg = (g & 7) ^ (row & 7);
      GL2LDS(BT + (size_t)(n0 + row) * K + kk + colg * 8, Bs + buf * 8192 + g * 8);
    }
  };

  stage(0, 0);  // 6 loads in flight
  const int NT = K >> 6;
  int cur = 0;
  for (int it = 0; it < NT; ++it) {
    if (it + 1 < NT) {
      stage(cur ^ 1, (it + 1) << 6);  // +6 loads; current tile's 6 are the oldest
      asm volatile("s_waitcnt vmcnt(6)" ::: "memory");  // oldest 6 retired, next 6 fly on
    } else {
      asm volatile("s_waitcnt vmcnt(0)" ::: "memory");
    }
    __builtin_amdgcn_s_barrier();  // all waves: current tile LDS complete
    const u16* Ab = As + cur * 4096;
    const u16* Bb = Bs + cur * 8192;
    __builtin_amdgcn_s_setprio(1);
#pragma unroll
    for (int kh = 0; kh < 2; ++kh) {
      short8 af[2], bfr[4];
#pragma unroll
      for (int mt = 0; mt < 2; ++mt) {
        int ra = wr * 32 + mt * 16 + fr;
        int cg = (kh * 4 + (L >> 4)) ^ (ra & 7);  // swizzled read granule
        af[mt] = *(const short8*)(Ab + ra * 64 + cg * 8);
      }
#pragma unroll
      for (int nt = 0; nt < 4; ++nt) {
        int rb = wc * 64 + nt * 16 + fr;
        int cg = (kh * 4 + (L >> 4)) ^ (rb & 7);
        bfr[nt] = *(const short8*)(Bb + rb * 64 + cg * 8);
      }
#pragma unroll
      for (int mt = 0; mt < 2; ++mt)
#pragma unroll
        for (int nt = 0; nt < 4; ++nt)
          acc[mt][nt] =
              __builtin_amdgcn_mfma_f32_16x16x32_bf16(af[mt], bfr[nt], acc[mt][nt], 0, 0, 0);
    }
    __builtin_amdgcn_s_setprio(0);
    __builtin_amdgcn_s_barrier();  // all waves done reading cur -> next iter may overwrite
    cur ^= 1;
  }
  const int gi4 = (L >> 4) * 4;
#pragma unroll
  for (int mt = 0; mt < 2; ++mt)
#pragma unroll
    for (int nt = 0; nt < 4; ++nt) {
      int n = n0 + wc * 64 + nt * 16 + fr;
      float bz = load_in(bias, n, md);
#pragma unroll
      for (int rr = 0; rr < 4; ++rr) {
        int m = m0 + wr * 32 + mt * 16 + gi4 + rr;
        float v = acc[mt][nt][rr] + bz;
        if (act) v = 0.5f * v * (1.f + erff(v * 0.70710678118654752f));
        size_t idx = (size_t)m * N + n;
        if (out_sel == 0 || md) {
          __hip_bfloat16 bv = __float2bfloat16(v);
          ((u16*)C)[idx] = *(u16*)&bv;
        } else {
          ((float*)C)[idx] = v;
        }
      }
    }
}

// ---------------- host ----------------
extern "C" void kernel_launch(void* const* d_in, const int* in_sizes, int n_in, void* d_out,
                              int out_size, void* d_ws, size_t ws_size, hipStream_t stream) {
  const void* x = d_in[0];
  const void* pe = d_in[1];
  const void* W1 = d_in[2];
  const void* b1 = d_in[3];
  const void* W2 = d_in[4];
  const void* b2 = d_in[5];

  char* base = (char*)d_ws;
  size_t off = 0;
  auto alloc = [&](size_t bytes) -> void* {
    void* p = base + off;
    off += (bytes + 255) & ~(size_t)255;
    return p;
  };
  int* mode = (int*)alloc(256);
  u16* m2 = (u16*)alloc((size_t)NB * 4608 * 128 * 2);  // bf16 hi/lo split metric
  float* pm = (float*)alloc((size_t)NB * 2304 * 36 * 4);
  int* pi = (int*)alloc((size_t)NB * 2304 * 36 * 4);
  float* nmax = (float*)alloc((size_t)NB * 2304 * 4);
  int* nidx = (int*)alloc((size_t)NB * 2304 * 4);
  float* bufA = (float*)alloc((size_t)NB * 2304 * C0 * 4);
  float* bufB = (float*)alloc((size_t)NB * 1152 * C0 * 4);
  float* s1 = (float*)alloc((size_t)NB * 2304 * 4);
  float* s2 = (float*)alloc((size_t)NB * 1152 * 4);
  float* s3 = (float*)alloc((size_t)NB * 576 * 4);
  float* s4 = (float*)alloc((size_t)NB * 288 * 4);
  float* s5 = (float*)alloc((size_t)NB * 144 * 4);
  float* sf = (float*)alloc((size_t)NB * 128 * 4);
  int* unm_map = (int*)alloc((size_t)NB * 56 * 4);
  int* src_ord = (int*)alloc((size_t)NB * 16 * 4);
  int* src_dst = (int*)alloc((size_t)NB * 16 * 4);
  u16* xfb = (u16*)alloc((size_t)NB * 128 * C0 * 2);
  u16* hbuf = (u16*)alloc((size_t)1024 * H0 * 2);
  u16* w1t = (u16*)alloc((size_t)H0 * C0 * 2);
  u16* w2t = (u16*)alloc((size_t)H0 * H0 * 2);
  // linked-list buffers: heads per iteration (2304+1152+576+288+144+72 = 4536), one nxt buffer
  int* heads = (int*)alloc((size_t)NB * 4536 * 4);
  int* nxt = (int*)alloc((size_t)NB * 2304 * 4);
  if (off > ws_size) return;

  int* h_it[6];
  h_it[0] = heads;
  h_it[1] = h_it[0] + NB * 2304;
  h_it[2] = h_it[1] + NB * 1152;
  h_it[3] = h_it[2] + NB * 576;
  h_it[4] = h_it[3] + NB * 288;
  h_it[5] = h_it[4] + NB * 144;

  float* x1 = bufA;
  float* x2 = bufB;
  float* x3 = bufA;
  float* x4 = bufB;
  float* x5 = bufA;
  float* xf = bufB;

  detect_mode_kernel<<<1, 1, 0, stream>>>((const uint32_t*)pe, mode);
  init_heads_kernel<<<(NB * 4536 + 255) / 256, 256, 0, stream>>>(heads, NB * 4536);

  // weight transposes (W is KxN row-major -> NxK bf16)
  transpose_in<<<dim3(4096 / 64, 1024 / 64), 256, 0, stream>>>(W1, mode, w1t, 1024, 4096);
  transpose_in<<<dim3(4096 / 64, 4096 / 64), 256, 0, stream>>>(W2, mode, w2t, 4096, 4096);

  // ---- iter 1: p=4608 -> p2=2304 (all evens merge)
  metric_in_kernel<<<NB * P0 / 4, 256, 0, stream>>>(x, pe, mode, m2);
  score_mfma_kernel<<<dim3(18, 18, NB), 256, 0, stream>>>(m2, 4608, 2304, 36, pm, pi);
  argmax_combine_kernel<<<(NB * 2304 + 255) / 256, 256, 0, stream>>>(pm, pi, 2304, 36, nmax,
                                                                     nidx, h_it[0], nxt);
  merge_gather_in<<<NB * 2304, 256, 0, stream>>>(x, pe, mode, h_it[0], nxt, x1, s1, 2304);

  // ---- iters 2..5 (generic all-evens-merge)
  float* xs_in[4] = {x1, x2, x3, x4};
  float* ss_in[4] = {s1, s2, s3, s4};
  float* xs_out[4] = {x2, x3, x4, x5};
  float* ss_out[4] = {s2, s3, s4, s5};
  int ps[5] = {2304, 1152, 576, 288, 144};
  for (int it = 0; it < 4; ++it) {
    int p = ps[it], p2 = ps[it + 1];
    int iT = (p2 + 127) / 128, jT = (p2 + 127) / 128;
    metric_f32_kernel<<<NB * p / 4, 256, 0, stream>>>(xs_in[it], m2, p);
    score_mfma_kernel<<<dim3(jT, iT, NB), 256, 0, stream>>>(m2, p, p2, 2 * jT, pm, pi);
    argmax_combine_kernel<<<(NB * p2 + 255) / 256, 256, 0, stream>>>(pm, pi, p2, 2 * jT, nmax,
                                                                     nidx, h_it[it + 1], nxt);
    merge_gather_f<<<NB * p2, 256, 0, stream>>>(xs_in[it], ss_in[it], h_it[it + 1], nxt,
                                                xs_out[it], ss_out[it], p, p2);
  }

  // ---- iter 6: p=144, p2=72, r=16 -> 128 tokens
  metric_f32_kernel<<<NB * 144 / 4, 256, 0, stream>>>(x5, m2, 144);
  score_mfma_kernel<<<dim3(1, 1, NB), 256, 0, stream>>>(m2, 144, 72, 2, pm, pi);
  argmax_combine_kernel<<<(NB * 72 + 255) / 256, 256, 0, stream>>>(pm, pi, 72, 2, nmax, nidx,
                                                                   h_it[5], nxt);
  rank_kernel<<<NB, 128, 0, stream>>>(nmax, nidx, unm_map, src_ord, src_dst);
  final_init<<<NB * 128, 256, 0, stream>>>(x5, s5, unm_map, xf, sf);
  final_scatter<<<NB * 16, 256, 0, stream>>>(x5, s5, src_ord, src_dst, xf, sf);
  final_div_cvt<<<NB * 128, 256, 0, stream>>>(xf, sf, (__hip_bfloat16*)xfb);

  // ---- MLP: h = gelu(x@W1 + b1); out = h@W2 + b2
  gemm_bt<<<dim3(4096 / 128, 1024 / 64), 256, 0, stream>>>(xfb, w1t, b1, mode, hbuf, 1024, 4096,
                                                           1024, 1, 0);
  gemm_bt<<<dim3(4096 / 128, 1024 / 64), 256, 0, stream>>>(hbuf, w2t, b2, mode, d_out, 1024,
                                                           4096, 4096, 0, 1);
}

// Round 5
// 754.569 us; speedup vs baseline: 1.9198x; 1.0365x over previous
//
#include <hip/hip_runtime.h>
#include <hip/hip_bf16.h>
#include <math.h>
#include <stdint.h>

typedef unsigned short u16;
typedef __attribute__((ext_vector_type(8))) short short8;
typedef __attribute__((ext_vector_type(4))) float floatx4;

#define NB 8
#define P0 4608
#define C0 1024
#define H0 4096

// mode: 0 = inputs/outputs are float32, 1 = bf16
__global__ void detect_mode_kernel(const uint32_t* __restrict__ pe_words, int* __restrict__ mode) {
  *mode = (pe_words[64] != 0u) ? 1 : 0;
}

__device__ __forceinline__ float load_in(const void* p, size_t idx, int mode) {
  if (mode) return __bfloat162float(((const __hip_bfloat16*)p)[idx]);
  return ((const float*)p)[idx];
}

__device__ __forceinline__ float4 load4(const void* p, size_t idx, int mode) {
  float4 r;
  if (mode) {
    ushort4 u = *(const ushort4*)((const u16*)p + idx);
    r.x = __bfloat162float(*(__hip_bfloat16*)&u.x);
    r.y = __bfloat162float(*(__hip_bfloat16*)&u.y);
    r.z = __bfloat162float(*(__hip_bfloat16*)&u.z);
    r.w = __bfloat162float(*(__hip_bfloat16*)&u.w);
  } else {
    r = *(const float4*)((const float*)p + idx);
  }
  return r;
}

__device__ __forceinline__ void write_hilo(u16* __restrict__ m2, size_t tok, int lane, float v) {
  __hip_bfloat16 hi = __float2bfloat16(v);
  float hif = __bfloat162float(hi);
  __hip_bfloat16 lo = __float2bfloat16(v - hif);
  m2[tok * 128 + lane] = *(u16*)&hi;
  m2[tok * 128 + 64 + lane] = *(u16*)&lo;
}

// ---------------- metric: mean over 16 heads of 64-dim chunks, L2 normalize, bf16 hi/lo split ----------------
__global__ void metric_in_kernel(const void* __restrict__ x, const void* __restrict__ pos,
                                 const int* __restrict__ mode, u16* __restrict__ m2) {
  int tok = blockIdx.x * 4 + (threadIdx.x >> 6);
  int lane = threadIdx.x & 63;
  if (tok >= NB * P0) return;
  int b = tok / P0, t = tok - b * P0;
  int md = *mode;
  size_t xbase = ((size_t)b * P0 + t) * C0 + lane;
  size_t pbase = (size_t)t * C0 + lane;
  float s = 0.f;
  if (md) {
    const __hip_bfloat16* xp = (const __hip_bfloat16*)x + xbase;
    const __hip_bfloat16* pp = (const __hip_bfloat16*)pos + pbase;
#pragma unroll
    for (int h = 0; h < 16; ++h)
      s += __bfloat162float(xp[h * 64]) + __bfloat162float(pp[h * 64]);
  } else {
    const float* xp = (const float*)x + xbase;
    const float* pp = (const float*)pos + pbase;
#pragma unroll
    for (int h = 0; h < 16; ++h) s += xp[h * 64] + pp[h * 64];
  }
  s *= (1.f / 16.f);
  float sq = s * s;
#pragma unroll
  for (int off = 1; off < 64; off <<= 1) sq += __shfl_xor(sq, off, 64);
  write_hilo(m2, (size_t)tok, lane, s / sqrtf(sq));
}

// ---------------- scores via bf16x4 split-precision MFMA + per-(row, 64-col) argmax partials ----------------
__global__ __launch_bounds__(256) void score_mfma_kernel(const u16* __restrict__ M2,
                                                         int p, int p2, int jT2,
                                                         float* __restrict__ pm,
                                                         int* __restrict__ pi) {
  const int bi = blockIdx.x, ii = blockIdx.y, b = blockIdx.z;
  const int t = threadIdx.x, w = t >> 6, L = t & 63;
  const int wr = w >> 1, wc = w & 1;
  const int fr = L & 15, fo = (L >> 4) * 8;
  const u16* Mb = M2 + (size_t)b * p * 128;

  floatx4 acc[4][4];
#pragma unroll
  for (int mt = 0; mt < 4; ++mt)
#pragma unroll
    for (int nt = 0; nt < 4; ++nt) acc[mt][nt] = (floatx4){0.f, 0.f, 0.f, 0.f};

  const u16* arp[4];
  const u16* brp[4];
#pragma unroll
  for (int mt = 0; mt < 4; ++mt) {
    int i = ii * 128 + wr * 64 + mt * 16 + fr;
    int ta = 2 * i;
    if (ta > p - 2) ta = p - 2;
    arp[mt] = Mb + (size_t)ta * 128 + fo;
    int j = bi * 128 + wc * 64 + mt * 16 + fr;
    int tb = 2 * j + 1;
    if (tb > p - 1) tb = p - 1;
    brp[mt] = Mb + (size_t)tb * 128 + fo;
  }

#pragma unroll
  for (int ks = 0; ks < 2; ++ks) {
    short8 ah[4], al[4], bh[4], bl[4];
#pragma unroll
    for (int mt = 0; mt < 4; ++mt) {
      ah[mt] = *(const short8*)(arp[mt] + ks * 32);
      al[mt] = *(const short8*)(arp[mt] + ks * 32 + 64);
      bh[mt] = *(const short8*)(brp[mt] + ks * 32);
      bl[mt] = *(const short8*)(brp[mt] + ks * 32 + 64);
    }
#pragma unroll
    for (int mt = 0; mt < 4; ++mt)
#pragma unroll
      for (int nt = 0; nt < 4; ++nt) {
        acc[mt][nt] = __builtin_amdgcn_mfma_f32_16x16x32_bf16(ah[mt], bh[nt], acc[mt][nt], 0, 0, 0);
        acc[mt][nt] = __builtin_amdgcn_mfma_f32_16x16x32_bf16(ah[mt], bl[nt], acc[mt][nt], 0, 0, 0);
        acc[mt][nt] = __builtin_amdgcn_mfma_f32_16x16x32_bf16(al[mt], bh[nt], acc[mt][nt], 0, 0, 0);
        acc[mt][nt] = __builtin_amdgcn_mfma_f32_16x16x32_bf16(al[mt], bl[nt], acc[mt][nt], 0, 0, 0);
      }
  }

  // epilogue: per output row, argmax over this wave's 64 cols
  const int gi4 = (L >> 4) * 4;
#pragma unroll
  for (int mt = 0; mt < 4; ++mt) {
#pragma unroll
    for (int reg = 0; reg < 4; ++reg) {
      int i = ii * 128 + wr * 64 + mt * 16 + gi4 + reg;
      float bm = -INFINITY;
      int bj = 0x7fffffff;
#pragma unroll
      for (int nt = 0; nt < 4; ++nt) {
        int j = bi * 128 + wc * 64 + nt * 16 + fr;
        float v = acc[mt][nt][reg];
        if (j < p2 && v > bm) { bm = v; bj = j; }
      }
#pragma unroll
      for (int mk = 1; mk < 16; mk <<= 1) {
        float om = __shfl_xor(bm, mk, 64);
        int oj = __shfl_xor(bj, mk, 64);
        if (om > bm || (om == bm && oj < bj)) { bm = om; bj = oj; }
      }
      if (fr == 0 && i < p2) {
        size_t o = ((size_t)b * 2304 + i) * jT2 + bi * 2 + wc;
        pm[o] = bm;
        pi[o] = bj;
      }
    }
  }
}

// argmax combine + build per-destination linked list (head[dst] -> chain via nxt[src])
__global__ void argmax_combine_kernel(const float* __restrict__ pm, const int* __restrict__ pi,
                                      int p2, int jT, float* __restrict__ nmax,
                                      int* __restrict__ nidx, int* __restrict__ head,
                                      int* __restrict__ nxt) {
  int g = blockIdx.x * 256 + threadIdx.x;
  if (g >= NB * p2) return;
  int b = g / p2, i = g - b * p2;
  const float* r = pm + ((size_t)b * 2304 + i) * jT;
  const int* ri = pi + ((size_t)b * 2304 + i) * jT;
  float best = r[0];
  int bidx = ri[0];
  for (int k = 1; k < jT; ++k) {
    if (r[k] > best || (r[k] == best && ri[k] < bidx)) { best = r[k]; bidx = ri[k]; }
  }
  nmax[g] = best;
  nidx[g] = bidx;
  int d = bidx;
  if ((unsigned)d >= (unsigned)p2) d = 0;
  nxt[g] = atomicExch(&head[(size_t)b * p2 + d], i);
}

__global__ void init_heads_kernel(int* __restrict__ h, int n) {
  int g = blockIdx.x * 256 + threadIdx.x;
  if (g < n) h[g] = -1;
}

// ---------------- fused merge (gather form) + fused next-iter metric ----------------
// out[j] = (odd + sum(evens)) / count; metric[j] = L2norm(mean_heads(out[j])) as bf16 hi/lo.
__global__ __launch_bounds__(256) void merge_gather_in(const void* __restrict__ x,
                                                       const void* __restrict__ pos,
                                                       const int* __restrict__ mode,
                                                       const int* __restrict__ head,
                                                       const int* __restrict__ nxt,
                                                       float* __restrict__ xo,
                                                       float* __restrict__ so, int p2,
                                                       u16* __restrict__ m2out) {
  int tj = blockIdx.x;
  int b = tj / p2, j = tj - b * p2;
  int c = threadIdx.x * 4;
  int md = *mode;
  __shared__ int sl[64];
  __shared__ int s_n, s_cur;
  __shared__ float mred[16][64];
  size_t xb = ((size_t)b * P0 + 2 * j + 1) * C0 + c;
  size_t pb = (size_t)(2 * j + 1) * C0 + c;
  float4 xa = load4(x, xb, md), pa = load4(pos, pb, md);
  float4 acc = {xa.x + pa.x, xa.y + pa.y, xa.z + pa.z, xa.w + pa.w};
  float cnt = 1.f;
  if (threadIdx.x == 0) s_cur = head[tj];
  __syncthreads();
  int cur = s_cur;
  while (cur != -1) {
    if (threadIdx.x == 0) {
      int n = 0, cc = cur;
      while (cc != -1 && n < 64) {
        sl[n++] = cc;
        cc = nxt[(size_t)b * p2 + cc];
      }
      s_n = n;
      s_cur = cc;
    }
    __syncthreads();
    int n = s_n;
    cur = s_cur;
    for (int k = 0; k < n; ++k) {
      int i = sl[k];
      size_t exb = ((size_t)b * P0 + 2 * i) * C0 + c;
      size_t epb = (size_t)(2 * i) * C0 + c;
      float4 ea = load4(x, exb, md), ep = load4(pos, epb, md);
      acc.x += ea.x + ep.x;
      acc.y += ea.y + ep.y;
      acc.z += ea.z + ep.z;
      acc.w += ea.w + ep.w;
      cnt += 1.f;
    }
    __syncthreads();
  }
  float inv = 1.f / cnt;
  float4 o = {acc.x * inv, acc.y * inv, acc.z * inv, acc.w * inv};
  *(float4*)(xo + (size_t)tj * C0 + c) = o;
  if (threadIdx.x == 0) so[tj] = cnt;
  // fused metric: channel c maps to head c/64, dim c%64
  {
    int hq = threadIdx.x >> 4, dq = (threadIdx.x & 15) * 4;
    mred[hq][dq + 0] = o.x;
    mred[hq][dq + 1] = o.y;
    mred[hq][dq + 2] = o.z;
    mred[hq][dq + 3] = o.w;
  }
  __syncthreads();
  if (threadIdx.x < 64) {
    float s = 0.f;
#pragma unroll
    for (int h = 0; h < 16; ++h) s += mred[h][threadIdx.x];
    s *= (1.f / 16.f);
    float sq = s * s;
#pragma unroll
    for (int off = 1; off < 64; off <<= 1) sq += __shfl_xor(sq, off, 64);
    write_hilo(m2out, (size_t)tj, threadIdx.x, s / sqrtf(sq));
  }
}

__global__ __launch_bounds__(256) void merge_gather_f(const float* __restrict__ xi,
                                                      const float* __restrict__ si,
                                                      const int* __restrict__ head,
                                                      const int* __restrict__ nxt,
                                                      float* __restrict__ xo,
                                                      float* __restrict__ so, int p, int p2,
                                                      u16* __restrict__ m2out) {
  int tj = blockIdx.x;
  int b = tj / p2, j = tj - b * p2;
  int c = threadIdx.x * 4;
  __shared__ int sl[64];
  __shared__ int s_n, s_cur;
  __shared__ float mred[16][64];
  float sz = si[(size_t)b * p + 2 * j + 1];
  float4 v = *(const float4*)(xi + ((size_t)b * p + 2 * j + 1) * C0 + c);
  float4 acc = {v.x * sz, v.y * sz, v.z * sz, v.w * sz};
  float ssum = sz;
  if (threadIdx.x == 0) s_cur = head[tj];
  __syncthreads();
  int cur = s_cur;
  while (cur != -1) {
    if (threadIdx.x == 0) {
      int n = 0, cc = cur;
      while (cc != -1 && n < 64) {
        sl[n++] = cc;
        cc = nxt[(size_t)b * p2 + cc];
      }
      s_n = n;
      s_cur = cc;
    }
    __syncthreads();
    int n = s_n;
    cur = s_cur;
    for (int k = 0; k < n; ++k) {
      int i = sl[k];
      float szi = si[(size_t)b * p + 2 * i];
      float4 e = *(const float4*)(xi + ((size_t)b * p + 2 * i) * C0 + c);
      acc.x += e.x * szi;
      acc.y += e.y * szi;
      acc.z += e.z * szi;
      acc.w += e.w * szi;
      ssum += szi;
    }
    __syncthreads();
  }
  float inv = 1.f / ssum;
  float4 o = {acc.x * inv, acc.y * inv, acc.z * inv, acc.w * inv};
  *(float4*)(xo + (size_t)tj * C0 + c) = o;
  if (threadIdx.x == 0) so[tj] = ssum;
  // fused metric
  {
    int hq = threadIdx.x >> 4, dq = (threadIdx.x & 15) * 4;
    mred[hq][dq + 0] = o.x;
    mred[hq][dq + 1] = o.y;
    mred[hq][dq + 2] = o.z;
    mred[hq][dq + 3] = o.w;
  }
  __syncthreads();
  if (threadIdx.x < 64) {
    float s = 0.f;
#pragma unroll
    for (int h = 0; h < 16; ++h) s += mred[h][threadIdx.x];
    s *= (1.f / 16.f);
    float sq = s * s;
#pragma unroll
    for (int off = 1; off < 64; off <<= 1) sq += __shfl_xor(sq, off, 64);
    write_hilo(m2out, (size_t)tj, threadIdx.x, s / sqrtf(sq));
  }
}

// ---------------- last iteration (p=144, p2=72, r=16): stable descending rank ----------------
__global__ void rank_kernel(const float* __restrict__ nmax, const int* __restrict__ nidx,
                            int* __restrict__ unm_map, int* __restrict__ src_ord,
                            int* __restrict__ src_dst) {
  int b = blockIdx.x;
  int i = threadIdx.x;
  __shared__ float v[72];
  __shared__ int nx[72];
  if (i < 72) { v[i] = nmax[b * 72 + i]; nx[i] = nidx[b * 72 + i]; }
  __syncthreads();
  if (i < 72) {
    float vi = v[i];
    int rank = 0;
    for (int k = 0; k < 72; ++k) {
      float vk = v[k];
      rank += (vk > vi) || (vk == vi && k < i);
    }
    if (rank < 16) {
      int d = nx[i];
      if ((unsigned)d >= 72u) d = 0;
      src_ord[b * 16 + rank] = i;
      src_dst[b * 16 + rank] = d;
    } else {
      unm_map[b * 56 + (rank - 16)] = i;
    }
  }
}

__global__ void final_init(const float* __restrict__ x5, const float* __restrict__ s5,
                           const int* __restrict__ unm_map, float* __restrict__ xf,
                           float* __restrict__ sf) {
  int bt = blockIdx.x;
  int b = bt >> 7, tk = bt & 127;
  int c = threadIdx.x * 4;
  float4 o;
  float szo;
  if (tk < 56) {
    int se = unm_map[b * 56 + tk];
    if ((unsigned)se >= 72u) se = 0;
    o = *(const float4*)(x5 + ((size_t)b * 144 + 2 * se) * C0 + c);
    szo = 1.f;
  } else {
    int j = tk - 56;
    float sz = s5[b * 144 + 2 * j + 1];
    float4 v = *(const float4*)(x5 + ((size_t)b * 144 + 2 * j + 1) * C0 + c);
    o.x = v.x * sz; o.y = v.y * sz; o.z = v.z * sz; o.w = v.w * sz;
    szo = sz;
  }
  *(float4*)(xf + (size_t)bt * C0 + c) = o;
  if (threadIdx.x == 0) sf[bt] = szo;
}

__global__ void final_scatter(const float* __restrict__ x5, const float* __restrict__ s5,
                              const int* __restrict__ src_ord, const int* __restrict__ src_dst,
                              float* __restrict__ xf, float* __restrict__ sf) {
  int bk = blockIdx.x;
  int b = bk >> 4, k = bk & 15;
  int c = threadIdx.x * 4;
  int st = src_ord[b * 16 + k], dst = src_dst[b * 16 + k];
  if ((unsigned)st >= 72u) st = 0;
  if ((unsigned)dst >= 72u) dst = 0;
  float sz = s5[b * 144 + 2 * st];
  float4 v = *(const float4*)(x5 + ((size_t)b * 144 + 2 * st) * C0 + c);
  float* out = xf + ((size_t)(b * 128 + 56 + dst)) * C0 + c;
  atomicAdd(out + 0, v.x * sz);
  atomicAdd(out + 1, v.y * sz);
  atomicAdd(out + 2, v.z * sz);
  atomicAdd(out + 3, v.w * sz);
  if (threadIdx.x == 0) atomicAdd(sf + b * 128 + 56 + dst, sz);
}

__global__ void final_div_cvt(const float* __restrict__ xf, const float* __restrict__ sf,
                              __hip_bfloat16* __restrict__ xb) {
  int bt = blockIdx.x;
  int c = threadIdx.x * 4;
  float sz = sf[bt];
  float4 v = *(const float4*)(xf + (size_t)bt * C0 + c);
  __hip_bfloat16* o = xb + (size_t)bt * C0 + c;
  o[0] = __float2bfloat16(v.x / sz);
  o[1] = __float2bfloat16(v.y / sz);
  o[2] = __float2bfloat16(v.z / sz);
  o[3] = __float2bfloat16(v.w / sz);
}

// ---------------- dual-dtype transpose (KxN -> NxK), output bf16, vectorized loads ----------------
__global__ void transpose_in(const void* __restrict__ in, const int* __restrict__ mode,
                             u16* __restrict__ out, int K, int N) {
  __shared__ u16 tile[64][65];
  int n0 = blockIdx.x * 64, k0 = blockIdx.y * 64;
  int t = threadIdx.x;
  int md = *mode;
  int r = t >> 4, c4 = (t & 15) * 4;
  if (md) {
#pragma unroll
    for (int pass = 0; pass < 4; ++pass) {
      int row = r + pass * 16;
      ushort4 u = *(const ushort4*)((const u16*)in + (size_t)(k0 + row) * N + n0 + c4);
      tile[row][c4 + 0] = u.x;
      tile[row][c4 + 1] = u.y;
      tile[row][c4 + 2] = u.z;
      tile[row][c4 + 3] = u.w;
    }
  } else {
#pragma unroll
    for (int pass = 0; pass < 4; ++pass) {
      int row = r + pass * 16;
      float4 v = *(const float4*)((const float*)in + (size_t)(k0 + row) * N + n0 + c4);
      __hip_bfloat16 b0 = __float2bfloat16(v.x), b1 = __float2bfloat16(v.y);
      __hip_bfloat16 b2 = __float2bfloat16(v.z), b3 = __float2bfloat16(v.w);
      tile[row][c4 + 0] = *(u16*)&b0;
      tile[row][c4 + 1] = *(u16*)&b1;
      tile[row][c4 + 2] = *(u16*)&b2;
      tile[row][c4 + 3] = *(u16*)&b3;
    }
  }
  __syncthreads();
#pragma unroll
  for (int pass = 0; pass < 4; ++pass) {
    int row = r + pass * 16;
    ushort4 o;
    o.x = tile[c4][row]; o.y = tile[c4 + 1][row]; o.z = tile[c4 + 2][row]; o.w = tile[c4 + 3][row];
    *(ushort4*)(out + (size_t)(n0 + row) * K + k0 + c4) = o;
  }
}

// ---------------- bf16 MFMA GEMM, B pre-transposed (NT), 64x128 tile ----------------
// 2-phase dbuf with counted vmcnt (T4) + XOR LDS swizzle via pre-swizzled global source (T2,
// rule-21: linear gload_lds dest + inverse-swizzled source + swizzled read) + setprio (T5).
#define GL2LDS(gp, lp)                                                                   \
  __builtin_amdgcn_global_load_lds((const __attribute__((address_space(1))) uint32_t*)(gp), \
                                   (__attribute__((address_space(3))) uint32_t*)(lp), 16, 0, 0)

__global__ __launch_bounds__(256, 2) void gemm_bt(const u16* __restrict__ A,
                                                  const u16* __restrict__ BT,
                                                  const void* __restrict__ bias,
                                                  const int* __restrict__ mode,
                                                  void* __restrict__ C, int M, int N,
                                                  int K, int act, int out_sel) {
  __shared__ __align__(16) u16 As[2 * 64 * 64];
  __shared__ __align__(16) u16 Bs[2 * 128 * 64];
  const int t = threadIdx.x, w = t >> 6, L = t & 63;
  const int m0 = blockIdx.y * 64, n0 = blockIdx.x * 128;
  const int wr = w >> 1, wc = w & 1;
  const int md = *mode;
  const int fr = L & 15;
  floatx4 acc[2][4];
#pragma unroll
  for (int a = 0; a < 2; ++a)
#pragma unroll
    for (int bb = 0; bb < 4; ++bb) acc[a][bb] = (floatx4){0.f, 0.f, 0.f, 0.f};

  // stage: LDS dest linear (granule g = q*256+t, 16B each); global source column
  // pre-swizzled colg' = colg ^ (row&7) so that swizzled reads see logical data.
  auto stage = [&](int buf, int kk) {
#pragma unroll
    for (int q = 0; q < 2; ++q) {
      int g = q * 256 + t;
      int row = g >> 3, colg = (g & 7) ^ (row & 7);
      GL2LDS(A + (size_t)(m0 + row) * K + kk + colg * 8, As + buf * 4096 + g * 8);
    }
#pragma unroll
    for (int q = 0; q < 4; ++q) {
      int g = q * 256 + t;
      int row = g >> 3, colg = (g & 7) ^ (row & 7);
      GL2LDS(BT + (size_t)(n0 + row) * K + kk + colg * 8, Bs + buf * 8192 + g * 8);
    }
  };

  stage(0, 0);  // 6 loads in flight
  const int NT = K >> 6;
  int cur = 0;
  for (int it = 0; it < NT; ++it) {
    if (it + 1 < NT) {
      stage(cur ^ 1, (it + 1) << 6);  // +6 loads; current tile's 6 are the oldest
      asm volatile("s_waitcnt vmcnt(6)" ::: "memory");  // oldest 6 retired, next 6 fly on
    } else {
      asm volatile("s_waitcnt vmcnt(0)" ::: "memory");
    }
    __builtin_amdgcn_s_barrier();  // all waves: current tile LDS complete
    const u16* Ab = As + cur * 4096;
    const u16* Bb = Bs + cur * 8192;
    __builtin_amdgcn_s_setprio(1);
#pragma unroll
    for (int kh = 0; kh < 2; ++kh) {
      short8 af[2], bfr[4];
#pragma unroll
      for (int mt = 0; mt < 2; ++mt) {
        int ra = wr * 32 + mt * 16 + fr;
        int cg = (kh * 4 + (L >> 4)) ^ (ra & 7);  // swizzled read granule
        af[mt] = *(const short8*)(Ab + ra * 64 + cg * 8);
      }
#pragma unroll
      for (int nt = 0; nt < 4; ++nt) {
        int rb = wc * 64 + nt * 16 + fr;
        int cg = (kh * 4 + (L >> 4)) ^ (rb & 7);
        bfr[nt] = *(const short8*)(Bb + rb * 64 + cg * 8);
      }
#pragma unroll
      for (int mt = 0; mt < 2; ++mt)
#pragma unroll
        for (int nt = 0; nt < 4; ++nt)
          acc[mt][nt] =
              __builtin_amdgcn_mfma_f32_16x16x32_bf16(af[mt], bfr[nt], acc[mt][nt], 0, 0, 0);
    }
    __builtin_amdgcn_s_setprio(0);
    __builtin_amdgcn_s_barrier();  // all waves done reading cur -> next iter may overwrite
    cur ^= 1;
  }
  const int gi4 = (L >> 4) * 4;
#pragma unroll
  for (int mt = 0; mt < 2; ++mt)
#pragma unroll
    for (int nt = 0; nt < 4; ++nt) {
      int n = n0 + wc * 64 + nt * 16 + fr;
      float bz = load_in(bias, n, md);
#pragma unroll
      for (int rr = 0; rr < 4; ++rr) {
        int m = m0 + wr * 32 + mt * 16 + gi4 + rr;
        float v = acc[mt][nt][rr] + bz;
        if (act) v = 0.5f * v * (1.f + erff(v * 0.70710678118654752f));
        size_t idx = (size_t)m * N + n;
        if (out_sel == 0 || md) {
          __hip_bfloat16 bv = __float2bfloat16(v);
          ((u16*)C)[idx] = *(u16*)&bv;
        } else {
          ((float*)C)[idx] = v;
        }
      }
    }
}

// ---------------- host ----------------
extern "C" void kernel_launch(void* const* d_in, const int* in_sizes, int n_in, void* d_out,
                              int out_size, void* d_ws, size_t ws_size, hipStream_t stream) {
  const void* x = d_in[0];
  const void* pe = d_in[1];
  const void* W1 = d_in[2];
  const void* b1 = d_in[3];
  const void* W2 = d_in[4];
  const void* b2 = d_in[5];

  char* base = (char*)d_ws;
  size_t off = 0;
  auto alloc = [&](size_t bytes) -> void* {
    void* p = base + off;
    off += (bytes + 255) & ~(size_t)255;
    return p;
  };
  int* mode = (int*)alloc(256);
  u16* m2 = (u16*)alloc((size_t)NB * 4608 * 128 * 2);  // bf16 hi/lo split metric
  float* pm = (float*)alloc((size_t)NB * 2304 * 36 * 4);
  int* pi = (int*)alloc((size_t)NB * 2304 * 36 * 4);
  float* nmax = (float*)alloc((size_t)NB * 2304 * 4);
  int* nidx = (int*)alloc((size_t)NB * 2304 * 4);
  float* bufA = (float*)alloc((size_t)NB * 2304 * C0 * 4);
  float* bufB = (float*)alloc((size_t)NB * 1152 * C0 * 4);
  float* s1 = (float*)alloc((size_t)NB * 2304 * 4);
  float* s2 = (float*)alloc((size_t)NB * 1152 * 4);
  float* s3 = (float*)alloc((size_t)NB * 576 * 4);
  float* s4 = (float*)alloc((size_t)NB * 288 * 4);
  float* s5 = (float*)alloc((size_t)NB * 144 * 4);
  float* sf = (float*)alloc((size_t)NB * 128 * 4);
  int* unm_map = (int*)alloc((size_t)NB * 56 * 4);
  int* src_ord = (int*)alloc((size_t)NB * 16 * 4);
  int* src_dst = (int*)alloc((size_t)NB * 16 * 4);
  u16* xfb = (u16*)alloc((size_t)NB * 128 * C0 * 2);
  u16* hbuf = (u16*)alloc((size_t)1024 * H0 * 2);
  u16* w1t = (u16*)alloc((size_t)H0 * C0 * 2);
  u16* w2t = (u16*)alloc((size_t)H0 * H0 * 2);
  // linked-list buffers: heads per iteration (2304+1152+576+288+144+72 = 4536), one nxt buffer
  int* heads = (int*)alloc((size_t)NB * 4536 * 4);
  int* nxt = (int*)alloc((size_t)NB * 2304 * 4);
  if (off > ws_size) return;

  int* h_it[6];
  h_it[0] = heads;
  h_it[1] = h_it[0] + NB * 2304;
  h_it[2] = h_it[1] + NB * 1152;
  h_it[3] = h_it[2] + NB * 576;
  h_it[4] = h_it[3] + NB * 288;
  h_it[5] = h_it[4] + NB * 144;

  float* x1 = bufA;
  float* x2 = bufB;
  float* x3 = bufA;
  float* x4 = bufB;
  float* x5 = bufA;
  float* xf = bufB;

  detect_mode_kernel<<<1, 1, 0, stream>>>((const uint32_t*)pe, mode);
  init_heads_kernel<<<(NB * 4536 + 255) / 256, 256, 0, stream>>>(heads, NB * 4536);

  // weight transposes (W is KxN row-major -> NxK bf16)
  transpose_in<<<dim3(4096 / 64, 1024 / 64), 256, 0, stream>>>(W1, mode, w1t, 1024, 4096);
  transpose_in<<<dim3(4096 / 64, 4096 / 64), 256, 0, stream>>>(W2, mode, w2t, 4096, 4096);

  // ---- iter 1: p=4608 -> p2=2304 (all evens merge)
  metric_in_kernel<<<NB * P0 / 4, 256, 0, stream>>>(x, pe, mode, m2);
  score_mfma_kernel<<<dim3(18, 18, NB), 256, 0, stream>>>(m2, 4608, 2304, 36, pm, pi);
  argmax_combine_kernel<<<(NB * 2304 + 255) / 256, 256, 0, stream>>>(pm, pi, 2304, 36, nmax,
                                                                     nidx, h_it[0], nxt);
  merge_gather_in<<<NB * 2304, 256, 0, stream>>>(x, pe, mode, h_it[0], nxt, x1, s1, 2304, m2);

  // ---- iters 2..5 (generic all-evens-merge); metric is fused into the previous gather
  float* xs_in[4] = {x1, x2, x3, x4};
  float* ss_in[4] = {s1, s2, s3, s4};
  float* xs_out[4] = {x2, x3, x4, x5};
  float* ss_out[4] = {s2, s3, s4, s5};
  int ps[5] = {2304, 1152, 576, 288, 144};
  for (int it = 0; it < 4; ++it) {
    int p = ps[it], p2 = ps[it + 1];
    int iT = (p2 + 127) / 128, jT = (p2 + 127) / 128;
    score_mfma_kernel<<<dim3(jT, iT, NB), 256, 0, stream>>>(m2, p, p2, 2 * jT, pm, pi);
    argmax_combine_kernel<<<(NB * p2 + 255) / 256, 256, 0, stream>>>(pm, pi, p2, 2 * jT, nmax,
                                                                     nidx, h_it[it + 1], nxt);
    merge_gather_f<<<NB * p2, 256, 0, stream>>>(xs_in[it], ss_in[it], h_it[it + 1], nxt,
                                                xs_out[it], ss_out[it], p, p2, m2);
  }

  // ---- iter 6: p=144, p2=72, r=16 -> 128 tokens (metric fused into iter-5 gather)
  score_mfma_kernel<<<dim3(1, 1, NB), 256, 0, stream>>>(m2, 144, 72, 2, pm, pi);
  argmax_combine_kernel<<<(NB * 72 + 255) / 256, 256, 0, stream>>>(pm, pi, 72, 2, nmax, nidx,
                                                                   h_it[5], nxt);
  rank_kernel<<<NB, 128, 0, stream>>>(nmax, nidx, unm_map, src_ord, src_dst);
  final_init<<<NB * 128, 256, 0, stream>>>(x5, s5, unm_map, xf, sf);
  final_scatter<<<NB * 16, 256, 0, stream>>>(x5, s5, src_ord, src_dst, xf, sf);
  final_div_cvt<<<NB * 128, 256, 0, stream>>>(xf, sf, (__hip_bfloat16*)xfb);

  // ---- MLP: h = gelu(x@W1 + b1); out = h@W2 + b2
  gemm_bt<<<dim3(4096 / 128, 1024 / 64), 256, 0, stream>>>(xfb, w1t, b1, mode, hbuf, 1024, 4096,
                                                           1024, 1, 0);
  gemm_bt<<<dim3(4096 / 128, 1024 / 64), 256, 0, stream>>>(hbuf, w2t, b2, mode, d_out, 1024,
                                                           4096, 4096, 0, 1);
}

// Round 6
// 742.324 us; speedup vs baseline: 1.9515x; 1.0165x over previous
//
#include <hip/hip_runtime.h>
#include <hip/hip_bf16.h>
#include <math.h>
#include <stdint.h>

typedef unsigned short u16;
typedef __attribute__((ext_vector_type(8))) short short8;
typedef __attribute__((ext_vector_type(4))) float floatx4;

#define NB 8
#define P0 4608
#define C0 1024
#define H0 4096

__device__ __forceinline__ float load_in(const void* p, size_t idx, int mode) {
  if (mode) return __bfloat162float(((const __hip_bfloat16*)p)[idx]);
  return ((const float*)p)[idx];
}

__device__ __forceinline__ float4 load4(const void* p, size_t idx, int mode) {
  float4 r;
  if (mode) {
    ushort4 u = *(const ushort4*)((const u16*)p + idx);
    r.x = __bfloat162float(*(__hip_bfloat16*)&u.x);
    r.y = __bfloat162float(*(__hip_bfloat16*)&u.y);
    r.z = __bfloat162float(*(__hip_bfloat16*)&u.z);
    r.w = __bfloat162float(*(__hip_bfloat16*)&u.w);
  } else {
    r = *(const float4*)((const float*)p + idx);
  }
  return r;
}

__device__ __forceinline__ void write_hilo(u16* __restrict__ m2, size_t tok, int lane, float v) {
  __hip_bfloat16 hi = __float2bfloat16(v);
  float hif = __bfloat162float(hi);
  __hip_bfloat16 lo = __float2bfloat16(v - hif);
  m2[tok * 128 + lane] = *(u16*)&hi;
  m2[tok * 128 + 64 + lane] = *(u16*)&lo;
}

// init linked-list heads + detect mode (thread 0)
__global__ void init_heads_kernel(int* __restrict__ h, int n,
                                  const uint32_t* __restrict__ pe_words,
                                  int* __restrict__ mode) {
  int g = blockIdx.x * 256 + threadIdx.x;
  if (g < n) h[g] = -1;
  if (g == 0) *mode = (pe_words[64] != 0u) ? 1 : 0;
}

// ---------------- metric: mean over 16 heads of 64-dim chunks, L2 normalize, bf16 hi/lo split
// Vectorized: channel c = 4*l + 256*hp covers the wave contiguously; head-sum via butterfly.
__global__ void metric_in_kernel(const void* __restrict__ x, const void* __restrict__ pos,
                                 const int* __restrict__ mode, u16* __restrict__ m2) {
  int tok = blockIdx.x * 4 + (threadIdx.x >> 6);
  int l = threadIdx.x & 63;
  if (tok >= NB * P0) return;
  int b = tok / P0, t = tok - b * P0;
  int md = *mode;
  size_t xrow = ((size_t)b * P0 + t) * C0;
  size_t prow = (size_t)t * C0;
  float4 acc = {0.f, 0.f, 0.f, 0.f};
  if (md) {
#pragma unroll
    for (int hp = 0; hp < 4; ++hp) {
      float4 v = load4(x, xrow + hp * 256 + 4 * l, 1);
      float4 w = load4(pos, prow + hp * 256 + 4 * l, 1);
      acc.x += v.x + w.x; acc.y += v.y + w.y; acc.z += v.z + w.z; acc.w += v.w + w.w;
    }
  } else {
#pragma unroll
    for (int hp = 0; hp < 4; ++hp) {
      float4 v = *(const float4*)((const float*)x + xrow + hp * 256 + 4 * l);
      float4 w = *(const float4*)((const float*)pos + prow + hp * 256 + 4 * l);
      acc.x += v.x + w.x; acc.y += v.y + w.y; acc.z += v.z + w.z; acc.w += v.w + w.w;
    }
  }
  // sum across the 4 head-quads (lanes differing in bits 4,5)
#pragma unroll
  for (int mk = 16; mk <= 32; mk <<= 1) {
    acc.x += __shfl_xor(acc.x, mk, 64);
    acc.y += __shfl_xor(acc.y, mk, 64);
    acc.z += __shfl_xor(acc.z, mk, 64);
    acc.w += __shfl_xor(acc.w, mk, 64);
  }
  acc.x *= (1.f / 16.f); acc.y *= (1.f / 16.f); acc.z *= (1.f / 16.f); acc.w *= (1.f / 16.f);
  float sq = acc.x * acc.x + acc.y * acc.y + acc.z * acc.z + acc.w * acc.w;
#pragma unroll
  for (int mk = 1; mk <= 8; mk <<= 1) sq += __shfl_xor(sq, mk, 64);
  if ((l >> 4) == 0) {
    float inv = 1.f / sqrtf(sq);
    int s4 = (l & 15) * 4;
    ushort4 hi4, lo4;
    float vv[4] = {acc.x * inv, acc.y * inv, acc.z * inv, acc.w * inv};
    u16 hw[4], lw[4];
#pragma unroll
    for (int e = 0; e < 4; ++e) {
      __hip_bfloat16 hi = __float2bfloat16(vv[e]);
      float hif = __bfloat162float(hi);
      __hip_bfloat16 lo = __float2bfloat16(vv[e] - hif);
      hw[e] = *(u16*)&hi; lw[e] = *(u16*)&lo;
    }
    hi4.x = hw[0]; hi4.y = hw[1]; hi4.z = hw[2]; hi4.w = hw[3];
    lo4.x = lw[0]; lo4.y = lw[1]; lo4.z = lw[2]; lo4.w = lw[3];
    *(ushort4*)(m2 + (size_t)tok * 128 + s4) = hi4;
    *(ushort4*)(m2 + (size_t)tok * 128 + 64 + s4) = lo4;
  }
}

// ---------------- scores via bf16x4 split-precision MFMA + per-(row, 64-col) argmax partials ----------------
__global__ __launch_bounds__(256) void score_mfma_kernel(const u16* __restrict__ M2,
                                                         int p, int p2, int jT2,
                                                         float* __restrict__ pm,
                                                         int* __restrict__ pi) {
  const int bi = blockIdx.x, ii = blockIdx.y, b = blockIdx.z;
  const int t = threadIdx.x, w = t >> 6, L = t & 63;
  const int wr = w >> 1, wc = w & 1;
  const int fr = L & 15, fo = (L >> 4) * 8;
  const u16* Mb = M2 + (size_t)b * p * 128;

  floatx4 acc[4][4];
#pragma unroll
  for (int mt = 0; mt < 4; ++mt)
#pragma unroll
    for (int nt = 0; nt < 4; ++nt) acc[mt][nt] = (floatx4){0.f, 0.f, 0.f, 0.f};

  const u16* arp[4];
  const u16* brp[4];
#pragma unroll
  for (int mt = 0; mt < 4; ++mt) {
    int i = ii * 128 + wr * 64 + mt * 16 + fr;
    int ta = 2 * i;
    if (ta > p - 2) ta = p - 2;
    arp[mt] = Mb + (size_t)ta * 128 + fo;
    int j = bi * 128 + wc * 64 + mt * 16 + fr;
    int tb = 2 * j + 1;
    if (tb > p - 1) tb = p - 1;
    brp[mt] = Mb + (size_t)tb * 128 + fo;
  }

#pragma unroll
  for (int ks = 0; ks < 2; ++ks) {
    short8 ah[4], al[4], bh[4], bl[4];
#pragma unroll
    for (int mt = 0; mt < 4; ++mt) {
      ah[mt] = *(const short8*)(arp[mt] + ks * 32);
      al[mt] = *(const short8*)(arp[mt] + ks * 32 + 64);
      bh[mt] = *(const short8*)(brp[mt] + ks * 32);
      bl[mt] = *(const short8*)(brp[mt] + ks * 32 + 64);
    }
#pragma unroll
    for (int mt = 0; mt < 4; ++mt)
#pragma unroll
      for (int nt = 0; nt < 4; ++nt) {
        acc[mt][nt] = __builtin_amdgcn_mfma_f32_16x16x32_bf16(ah[mt], bh[nt], acc[mt][nt], 0, 0, 0);
        acc[mt][nt] = __builtin_amdgcn_mfma_f32_16x16x32_bf16(ah[mt], bl[nt], acc[mt][nt], 0, 0, 0);
        acc[mt][nt] = __builtin_amdgcn_mfma_f32_16x16x32_bf16(al[mt], bh[nt], acc[mt][nt], 0, 0, 0);
        acc[mt][nt] = __builtin_amdgcn_mfma_f32_16x16x32_bf16(al[mt], bl[nt], acc[mt][nt], 0, 0, 0);
      }
  }

  const int gi4 = (L >> 4) * 4;
#pragma unroll
  for (int mt = 0; mt < 4; ++mt) {
#pragma unroll
    for (int reg = 0; reg < 4; ++reg) {
      int i = ii * 128 + wr * 64 + mt * 16 + gi4 + reg;
      float bm = -INFINITY;
      int bj = 0x7fffffff;
#pragma unroll
      for (int nt = 0; nt < 4; ++nt) {
        int j = bi * 128 + wc * 64 + nt * 16 + fr;
        float v = acc[mt][nt][reg];
        if (j < p2 && v > bm) { bm = v; bj = j; }
      }
#pragma unroll
      for (int mk = 1; mk < 16; mk <<= 1) {
        float om = __shfl_xor(bm, mk, 64);
        int oj = __shfl_xor(bj, mk, 64);
        if (om > bm || (om == bm && oj < bj)) { bm = om; bj = oj; }
      }
      if (fr == 0 && i < p2) {
        size_t o = ((size_t)b * 2304 + i) * jT2 + bi * 2 + wc;
        pm[o] = bm;
        pi[o] = bj;
      }
    }
  }
}

// argmax combine + build per-destination linked list (head[dst] -> chain via nxt[src])
__global__ void argmax_combine_kernel(const float* __restrict__ pm, const int* __restrict__ pi,
                                      int p2, int jT, float* __restrict__ nmax,
                                      int* __restrict__ nidx, int* __restrict__ head,
                                      int* __restrict__ nxt) {
  int g = blockIdx.x * 256 + threadIdx.x;
  if (g >= NB * p2) return;
  int b = g / p2, i = g - b * p2;
  const float* r = pm + ((size_t)b * 2304 + i) * jT;
  const int* ri = pi + ((size_t)b * 2304 + i) * jT;
  float best = r[0];
  int bidx = ri[0];
  for (int k = 1; k < jT; ++k) {
    if (r[k] > best || (r[k] == best && ri[k] < bidx)) { best = r[k]; bidx = ri[k]; }
  }
  nmax[g] = best;
  nidx[g] = bidx;
  int d = bidx;
  if ((unsigned)d >= (unsigned)p2) d = 0;
  nxt[g] = atomicExch(&head[(size_t)b * p2 + d], i);
}

// ---------------- fused merge (gather form) + fused next-iter metric ----------------
__global__ __launch_bounds__(256) void merge_gather_in(const void* __restrict__ x,
                                                       const void* __restrict__ pos,
                                                       const int* __restrict__ mode,
                                                       const int* __restrict__ head,
                                                       const int* __restrict__ nxt,
                                                       float* __restrict__ xo,
                                                       float* __restrict__ so, int p2,
                                                       u16* __restrict__ m2out) {
  int tj = blockIdx.x;
  int b = tj / p2, j = tj - b * p2;
  int c = threadIdx.x * 4;
  int md = *mode;
  __shared__ int sl[64];
  __shared__ int s_n, s_cur;
  __shared__ float mred[16][64];
  size_t xb = ((size_t)b * P0 + 2 * j + 1) * C0 + c;
  size_t pb = (size_t)(2 * j + 1) * C0 + c;
  float4 xa = load4(x, xb, md), pa = load4(pos, pb, md);
  float4 acc = {xa.x + pa.x, xa.y + pa.y, xa.z + pa.z, xa.w + pa.w};
  float cnt = 1.f;
  if (threadIdx.x == 0) s_cur = head[tj];
  __syncthreads();
  int cur = s_cur;
  while (cur != -1) {
    if (threadIdx.x == 0) {
      int n = 0, cc = cur;
      while (cc != -1 && n < 64) {
        sl[n++] = cc;
        cc = nxt[(size_t)b * p2 + cc];
      }
      s_n = n;
      s_cur = cc;
    }
    __syncthreads();
    int n = s_n;
    cur = s_cur;
    for (int k = 0; k < n; ++k) {
      int i = sl[k];
      size_t exb = ((size_t)b * P0 + 2 * i) * C0 + c;
      size_t epb = (size_t)(2 * i) * C0 + c;
      float4 ea = load4(x, exb, md), ep = load4(pos, epb, md);
      acc.x += ea.x + ep.x;
      acc.y += ea.y + ep.y;
      acc.z += ea.z + ep.z;
      acc.w += ea.w + ep.w;
      cnt += 1.f;
    }
    __syncthreads();
  }
  float inv = 1.f / cnt;
  float4 o = {acc.x * inv, acc.y * inv, acc.z * inv, acc.w * inv};
  *(float4*)(xo + (size_t)tj * C0 + c) = o;
  if (threadIdx.x == 0) so[tj] = cnt;
  {
    int hq = threadIdx.x >> 4, dq = (threadIdx.x & 15) * 4;
    mred[hq][dq + 0] = o.x;
    mred[hq][dq + 1] = o.y;
    mred[hq][dq + 2] = o.z;
    mred[hq][dq + 3] = o.w;
  }
  __syncthreads();
  if (threadIdx.x < 64) {
    float s = 0.f;
#pragma unroll
    for (int h = 0; h < 16; ++h) s += mred[h][threadIdx.x];
    s *= (1.f / 16.f);
    float sq = s * s;
#pragma unroll
    for (int off = 1; off < 64; off <<= 1) sq += __shfl_xor(sq, off, 64);
    write_hilo(m2out, (size_t)tj, threadIdx.x, s / sqrtf(sq));
  }
}

__global__ __launch_bounds__(256) void merge_gather_f(const float* __restrict__ xi,
                                                      const float* __restrict__ si,
                                                      const int* __restrict__ head,
                                                      const int* __restrict__ nxt,
                                                      float* __restrict__ xo,
                                                      float* __restrict__ so, int p, int p2,
                                                      u16* __restrict__ m2out) {
  int tj = blockIdx.x;
  int b = tj / p2, j = tj - b * p2;
  int c = threadIdx.x * 4;
  __shared__ int sl[64];
  __shared__ int s_n, s_cur;
  __shared__ float mred[16][64];
  float sz = si[(size_t)b * p + 2 * j + 1];
  float4 v = *(const float4*)(xi + ((size_t)b * p + 2 * j + 1) * C0 + c);
  float4 acc = {v.x * sz, v.y * sz, v.z * sz, v.w * sz};
  float ssum = sz;
  if (threadIdx.x == 0) s_cur = head[tj];
  __syncthreads();
  int cur = s_cur;
  while (cur != -1) {
    if (threadIdx.x == 0) {
      int n = 0, cc = cur;
      while (cc != -1 && n < 64) {
        sl[n++] = cc;
        cc = nxt[(size_t)b * p2 + cc];
      }
      s_n = n;
      s_cur = cc;
    }
    __syncthreads();
    int n = s_n;
    cur = s_cur;
    for (int k = 0; k < n; ++k) {
      int i = sl[k];
      float szi = si[(size_t)b * p + 2 * i];
      float4 e = *(const float4*)(xi + ((size_t)b * p + 2 * i) * C0 + c);
      acc.x += e.x * szi;
      acc.y += e.y * szi;
      acc.z += e.z * szi;
      acc.w += e.w * szi;
      ssum += szi;
    }
    __syncthreads();
  }
  float inv = 1.f / ssum;
  float4 o = {acc.x * inv, acc.y * inv, acc.z * inv, acc.w * inv};
  *(float4*)(xo + (size_t)tj * C0 + c) = o;
  if (threadIdx.x == 0) so[tj] = ssum;
  {
    int hq = threadIdx.x >> 4, dq = (threadIdx.x & 15) * 4;
    mred[hq][dq + 0] = o.x;
    mred[hq][dq + 1] = o.y;
    mred[hq][dq + 2] = o.z;
    mred[hq][dq + 3] = o.w;
  }
  __syncthreads();
  if (threadIdx.x < 64) {
    float s = 0.f;
#pragma unroll
    for (int h = 0; h < 16; ++h) s += mred[h][threadIdx.x];
    s *= (1.f / 16.f);
    float sq = s * s;
#pragma unroll
    for (int off = 1; off < 64; off <<= 1) sq += __shfl_xor(sq, off, 64);
    write_hilo(m2out, (size_t)tj, threadIdx.x, s / sqrtf(sq));
  }
}

// ---------------- last iteration: fused argmax-combine (jT=2) + stable descending rank ----------------
__global__ void rank_combine_kernel(const float* __restrict__ pm, const int* __restrict__ pi,
                                    int* __restrict__ unm_map, int* __restrict__ src_ord,
                                    int* __restrict__ src_dst) {
  int b = blockIdx.x;
  int i = threadIdx.x;
  __shared__ float v[72];
  __shared__ int nx[72];
  if (i < 72) {
    const float* r = pm + ((size_t)b * 2304 + i) * 2;
    const int* ri = pi + ((size_t)b * 2304 + i) * 2;
    float best = r[0];
    int bidx = ri[0];
    if (r[1] > best || (r[1] == best && ri[1] < bidx)) { best = r[1]; bidx = ri[1]; }
    v[i] = best;
    nx[i] = bidx;
  }
  __syncthreads();
  if (i < 72) {
    float vi = v[i];
    int rank = 0;
    for (int k = 0; k < 72; ++k) {
      float vk = v[k];
      rank += (vk > vi) || (vk == vi && k < i);
    }
    if (rank < 16) {
      int d = nx[i];
      if ((unsigned)d >= 72u) d = 0;
      src_ord[b * 16 + rank] = i;
      src_dst[b * 16 + rank] = d;
    } else {
      unm_map[b * 56 + (rank - 16)] = i;
    }
  }
}

// ---------------- fused final gather: init + merge (scan 16-entry src table) + div + bf16 cvt ----------------
__global__ __launch_bounds__(256) void final_gather(const float* __restrict__ x5,
                                                    const float* __restrict__ s5,
                                                    const int* __restrict__ unm_map,
                                                    const int* __restrict__ src_ord,
                                                    const int* __restrict__ src_dst,
                                                    __hip_bfloat16* __restrict__ xb) {
  int bt = blockIdx.x;
  int b = bt >> 7, tk = bt & 127;
  int c = threadIdx.x * 4;
  __shared__ int sord[16], sdst[16];
  if (threadIdx.x < 16) {
    sord[threadIdx.x] = src_ord[b * 16 + threadIdx.x];
    sdst[threadIdx.x] = src_dst[b * 16 + threadIdx.x];
  }
  __syncthreads();
  float4 o;
  if (tk < 56) {
    int se = unm_map[b * 56 + tk];
    if ((unsigned)se >= 72u) se = 0;
    o = *(const float4*)(x5 + ((size_t)b * 144 + 2 * se) * C0 + c);
  } else {
    int j = tk - 56;
    float sz = s5[b * 144 + 2 * j + 1];
    float4 v = *(const float4*)(x5 + ((size_t)b * 144 + 2 * j + 1) * C0 + c);
    float4 acc = {v.x * sz, v.y * sz, v.z * sz, v.w * sz};
    float ssum = sz;
#pragma unroll
    for (int k = 0; k < 16; ++k) {
      if (sdst[k] == j) {
        int st = sord[k];
        if ((unsigned)st >= 72u) st = 0;
        float szi = s5[b * 144 + 2 * st];
        float4 e = *(const float4*)(x5 + ((size_t)b * 144 + 2 * st) * C0 + c);
        acc.x += e.x * szi;
        acc.y += e.y * szi;
        acc.z += e.z * szi;
        acc.w += e.w * szi;
        ssum += szi;
      }
    }
    float inv = 1.f / ssum;
    o.x = acc.x * inv; o.y = acc.y * inv; o.z = acc.z * inv; o.w = acc.w * inv;
  }
  __hip_bfloat16* op = xb + (size_t)bt * C0 + c;
  op[0] = __float2bfloat16(o.x);
  op[1] = __float2bfloat16(o.y);
  op[2] = __float2bfloat16(o.z);
  op[3] = __float2bfloat16(o.w);
}

// ---------------- dual-dtype transpose (KxN -> NxK), output bf16, vectorized loads ----------------
__global__ void transpose_in(const void* __restrict__ in, const int* __restrict__ mode,
                             u16* __restrict__ out, int K, int N) {
  __shared__ u16 tile[64][65];
  int n0 = blockIdx.x * 64, k0 = blockIdx.y * 64;
  int t = threadIdx.x;
  int md = *mode;
  int r = t >> 4, c4 = (t & 15) * 4;
  if (md) {
#pragma unroll
    for (int pass = 0; pass < 4; ++pass) {
      int row = r + pass * 16;
      ushort4 u = *(const ushort4*)((const u16*)in + (size_t)(k0 + row) * N + n0 + c4);
      tile[row][c4 + 0] = u.x;
      tile[row][c4 + 1] = u.y;
      tile[row][c4 + 2] = u.z;
      tile[row][c4 + 3] = u.w;
    }
  } else {
#pragma unroll
    for (int pass = 0; pass < 4; ++pass) {
      int row = r + pass * 16;
      float4 v = *(const float4*)((const float*)in + (size_t)(k0 + row) * N + n0 + c4);
      __hip_bfloat16 b0 = __float2bfloat16(v.x), b1 = __float2bfloat16(v.y);
      __hip_bfloat16 b2 = __float2bfloat16(v.z), b3 = __float2bfloat16(v.w);
      tile[row][c4 + 0] = *(u16*)&b0;
      tile[row][c4 + 1] = *(u16*)&b1;
      tile[row][c4 + 2] = *(u16*)&b2;
      tile[row][c4 + 3] = *(u16*)&b3;
    }
  }
  __syncthreads();
#pragma unroll
  for (int pass = 0; pass < 4; ++pass) {
    int row = r + pass * 16;
    ushort4 o;
    o.x = tile[c4][row]; o.y = tile[c4 + 1][row]; o.z = tile[c4 + 2][row]; o.w = tile[c4 + 3][row];
    *(ushort4*)(out + (size_t)(n0 + row) * K + k0 + c4) = o;
  }
}

// ---------------- bf16 MFMA GEMM, B pre-transposed (NT), 64x128 tile ----------------
// 3-stage dbuf, 2 tiles prefetched ahead, counted vmcnt(12/6/0) + XOR LDS swizzle via
// pre-swizzled global source (rule-21) + setprio.
#define GL2LDS(gp, lp)                                                                   \
  __builtin_amdgcn_global_load_lds((const __attribute__((address_space(1))) uint32_t*)(gp), \
                                   (__attribute__((address_space(3))) uint32_t*)(lp), 16, 0, 0)

__global__ __launch_bounds__(256, 2) void gemm_bt(const u16* __restrict__ A,
                                                  const u16* __restrict__ BT,
                                                  const void* __restrict__ bias,
                                                  const int* __restrict__ mode,
                                                  void* __restrict__ C, int M, int N,
                                                  int K, int act, int out_sel) {
  __shared__ __align__(16) u16 As[3 * 64 * 64];
  __shared__ __align__(16) u16 Bs[3 * 128 * 64];
  const int t = threadIdx.x, w = t >> 6, L = t & 63;
  const int m0 = blockIdx.y * 64, n0 = blockIdx.x * 128;
  const int wr = w >> 1, wc = w & 1;
  const int md = *mode;
  const int fr = L & 15;
  floatx4 acc[2][4];
#pragma unroll
  for (int a = 0; a < 2; ++a)
#pragma unroll
    for (int bb = 0; bb < 4; ++bb) acc[a][bb] = (floatx4){0.f, 0.f, 0.f, 0.f};

  auto stage = [&](int buf, int kk) {
#pragma unroll
    for (int q = 0; q < 2; ++q) {
      int g = q * 256 + t;
      int row = g >> 3, colg = (g & 7) ^ (row & 7);
      GL2LDS(A + (size_t)(m0 + row) * K + kk + colg * 8, As + buf * 4096 + g * 8);
    }
#pragma unroll
    for (int q = 0; q < 4; ++q) {
      int g = q * 256 + t;
      int row = g >> 3, colg = (g & 7) ^ (row & 7);
      GL2LDS(BT + (size_t)(n0 + row) * K + kk + colg * 8, Bs + buf * 8192 + g * 8);
    }
  };

  const int NT = K >> 6;
  stage(0, 0);
  stage(1, 64);  // 12 loads in flight
  int cur = 0;
  for (int it = 0; it < NT; ++it) {
    if (it + 2 < NT) {
      int b2 = cur + 2;
      if (b2 >= 3) b2 -= 3;
      stage(b2, (it + 2) << 6);                          // +6 loads
      asm volatile("s_waitcnt vmcnt(12)" ::: "memory");  // tile it landed; it+1/it+2 fly on
    } else if (it + 1 < NT) {
      asm volatile("s_waitcnt vmcnt(6)" ::: "memory");
    } else {
      asm volatile("s_waitcnt vmcnt(0)" ::: "memory");
    }
    __builtin_amdgcn_s_barrier();  // all waves: current tile LDS complete
    const u16* Ab = As + cur * 4096;
    const u16* Bb = Bs + cur * 8192;
    __builtin_amdgcn_s_setprio(1);
#pragma unroll
    for (int kh = 0; kh < 2; ++kh) {
      short8 af[2], bfr[4];
#pragma unroll
      for (int mt = 0; mt < 2; ++mt) {
        int ra = wr * 32 + mt * 16 + fr;
        int cg = (kh * 4 + (L >> 4)) ^ (ra & 7);
        af[mt] = *(const short8*)(Ab + ra * 64 + cg * 8);
      }
#pragma unroll
      for (int nt = 0; nt < 4; ++nt) {
        int rb = wc * 64 + nt * 16 + fr;
        int cg = (kh * 4 + (L >> 4)) ^ (rb & 7);
        bfr[nt] = *(const short8*)(Bb + rb * 64 + cg * 8);
      }
#pragma unroll
      for (int mt = 0; mt < 2; ++mt)
#pragma unroll
        for (int nt = 0; nt < 4; ++nt)
          acc[mt][nt] =
              __builtin_amdgcn_mfma_f32_16x16x32_bf16(af[mt], bfr[nt], acc[mt][nt], 0, 0, 0);
    }
    __builtin_amdgcn_s_setprio(0);
    __builtin_amdgcn_s_barrier();  // done reading cur -> it+2 staging may overwrite it-1's buf
    cur = (cur + 1 == 3) ? 0 : cur + 1;
  }
  const int gi4 = (L >> 4) * 4;
#pragma unroll
  for (int mt = 0; mt < 2; ++mt)
#pragma unroll
    for (int nt = 0; nt < 4; ++nt) {
      int n = n0 + wc * 64 + nt * 16 + fr;
      float bz = load_in(bias, n, md);
#pragma unroll
      for (int rr = 0; rr < 4; ++rr) {
        int m = m0 + wr * 32 + mt * 16 + gi4 + rr;
        float v = acc[mt][nt][rr] + bz;
        if (act) v = 0.5f * v * (1.f + erff(v * 0.70710678118654752f));
        size_t idx = (size_t)m * N + n;
        if (out_sel == 0 || md) {
          __hip_bfloat16 bv = __float2bfloat16(v);
          ((u16*)C)[idx] = *(u16*)&bv;
        } else {
          ((float*)C)[idx] = v;
        }
      }
    }
}

// ---------------- host ----------------
extern "C" void kernel_launch(void* const* d_in, const int* in_sizes, int n_in, void* d_out,
                              int out_size, void* d_ws, size_t ws_size, hipStream_t stream) {
  const void* x = d_in[0];
  const void* pe = d_in[1];
  const void* W1 = d_in[2];
  const void* b1 = d_in[3];
  const void* W2 = d_in[4];
  const void* b2 = d_in[5];

  char* base = (char*)d_ws;
  size_t off = 0;
  auto alloc = [&](size_t bytes) -> void* {
    void* p = base + off;
    off += (bytes + 255) & ~(size_t)255;
    return p;
  };
  int* mode = (int*)alloc(256);
  u16* m2 = (u16*)alloc((size_t)NB * 4608 * 128 * 2);  // bf16 hi/lo split metric
  float* pm = (float*)alloc((size_t)NB * 2304 * 36 * 4);
  int* pi = (int*)alloc((size_t)NB * 2304 * 36 * 4);
  float* nmax = (float*)alloc((size_t)NB * 2304 * 4);
  int* nidx = (int*)alloc((size_t)NB * 2304 * 4);
  float* bufA = (float*)alloc((size_t)NB * 2304 * C0 * 4);
  float* bufB = (float*)alloc((size_t)NB * 1152 * C0 * 4);
  float* s1 = (float*)alloc((size_t)NB * 2304 * 4);
  float* s2 = (float*)alloc((size_t)NB * 1152 * 4);
  float* s3 = (float*)alloc((size_t)NB * 576 * 4);
  float* s4 = (float*)alloc((size_t)NB * 288 * 4);
  float* s5 = (float*)alloc((size_t)NB * 144 * 4);
  int* unm_map = (int*)alloc((size_t)NB * 56 * 4);
  int* src_ord = (int*)alloc((size_t)NB * 16 * 4);
  int* src_dst = (int*)alloc((size_t)NB * 16 * 4);
  u16* xfb = (u16*)alloc((size_t)NB * 128 * C0 * 2);
  u16* hbuf = (u16*)alloc((size_t)1024 * H0 * 2);
  u16* w1t = (u16*)alloc((size_t)H0 * C0 * 2);
  u16* w2t = (u16*)alloc((size_t)H0 * H0 * 2);
  // linked-list buffers: heads per iteration (2304+1152+576+288+144 = 4464), one nxt buffer
  int* heads = (int*)alloc((size_t)NB * 4464 * 4);
  int* nxt = (int*)alloc((size_t)NB * 2304 * 4);
  if (off > ws_size) return;

  int* h_it[5];
  h_it[0] = heads;
  h_it[1] = h_it[0] + NB * 2304;
  h_it[2] = h_it[1] + NB * 1152;
  h_it[3] = h_it[2] + NB * 576;
  h_it[4] = h_it[3] + NB * 288;

  float* x1 = bufA;
  float* x2 = bufB;
  float* x3 = bufA;
  float* x4 = bufB;
  float* x5 = bufA;

  init_heads_kernel<<<(NB * 4464 + 255) / 256, 256, 0, stream>>>(heads, NB * 4464,
                                                                 (const uint32_t*)pe, mode);

  // weight transposes (W is KxN row-major -> NxK bf16)
  transpose_in<<<dim3(4096 / 64, 1024 / 64), 256, 0, stream>>>(W1, mode, w1t, 1024, 4096);
  transpose_in<<<dim3(4096 / 64, 4096 / 64), 256, 0, stream>>>(W2, mode, w2t, 4096, 4096);

  // ---- iter 1: p=4608 -> p2=2304 (all evens merge)
  metric_in_kernel<<<NB * P0 / 4, 256, 0, stream>>>(x, pe, mode, m2);
  score_mfma_kernel<<<dim3(18, 18, NB), 256, 0, stream>>>(m2, 4608, 2304, 36, pm, pi);
  argmax_combine_kernel<<<(NB * 2304 + 255) / 256, 256, 0, stream>>>(pm, pi, 2304, 36, nmax,
                                                                     nidx, h_it[0], nxt);
  merge_gather_in<<<NB * 2304, 256, 0, stream>>>(x, pe, mode, h_it[0], nxt, x1, s1, 2304, m2);

  // ---- iters 2..5 (generic all-evens-merge); metric is fused into the previous gather
  float* xs_in[4] = {x1, x2, x3, x4};
  float* ss_in[4] = {s1, s2, s3, s4};
  float* xs_out[4] = {x2, x3, x4, x5};
  float* ss_out[4] = {s2, s3, s4, s5};
  int ps[5] = {2304, 1152, 576, 288, 144};
  for (int it = 0; it < 4; ++it) {
    int p = ps[it], p2 = ps[it + 1];
    int iT = (p2 + 127) / 128, jT = (p2 + 127) / 128;
    score_mfma_kernel<<<dim3(jT, iT, NB), 256, 0, stream>>>(m2, p, p2, 2 * jT, pm, pi);
    argmax_combine_kernel<<<(NB * p2 + 255) / 256, 256, 0, stream>>>(pm, pi, p2, 2 * jT, nmax,
                                                                     nidx, h_it[it + 1], nxt);
    merge_gather_f<<<NB * p2, 256, 0, stream>>>(xs_in[it], ss_in[it], h_it[it + 1], nxt,
                                                xs_out[it], ss_out[it], p, p2, m2);
  }

  // ---- iter 6: p=144, p2=72, r=16 -> 128 tokens (fused combine+rank, fused final gather)
  score_mfma_kernel<<<dim3(1, 1, NB), 256, 0, stream>>>(m2, 144, 72, 2, pm, pi);
  rank_combine_kernel<<<NB, 128, 0, stream>>>(pm, pi, unm_map, src_ord, src_dst);
  final_gather<<<NB * 128, 256, 0, stream>>>(x5, s5, unm_map, src_ord, src_dst,
                                             (__hip_bfloat16*)xfb);

  // ---- MLP: h = gelu(x@W1 + b1); out = h@W2 + b2
  gemm_bt<<<dim3(4096 / 128, 1024 / 64), 256, 0, stream>>>(xfb, w1t, b1, mode, hbuf, 1024, 4096,
                                                           1024, 1, 0);
  gemm_bt<<<dim3(4096 / 128, 1024 / 64), 256, 0, stream>>>(hbuf, w2t, b2, mode, d_out, 1024,
                                                           4096, 4096, 0, 1);
}

// Round 7
// 709.186 us; speedup vs baseline: 2.0427x; 1.0467x over previous
//
#include <hip/hip_runtime.h>
#include <hip/hip_bf16.h>
#include <math.h>
#include <stdint.h>

typedef unsigned short u16;
typedef __attribute__((ext_vector_type(8))) short short8;
typedef __attribute__((ext_vector_type(4))) float floatx4;

#define NB 8
#define P0 4608
#define C0 1024
#define H0 4096

__device__ __forceinline__ float load_in(const void* p, size_t idx, int mode) {
  if (mode) return __bfloat162float(((const __hip_bfloat16*)p)[idx]);
  return ((const float*)p)[idx];
}

__device__ __forceinline__ float4 load4(const void* p, size_t idx, int mode) {
  float4 r;
  if (mode) {
    ushort4 u = *(const ushort4*)((const u16*)p + idx);
    r.x = __bfloat162float(*(__hip_bfloat16*)&u.x);
    r.y = __bfloat162float(*(__hip_bfloat16*)&u.y);
    r.z = __bfloat162float(*(__hip_bfloat16*)&u.z);
    r.w = __bfloat162float(*(__hip_bfloat16*)&u.w);
  } else {
    r = *(const float4*)((const float*)p + idx);
  }
  return r;
}

__device__ __forceinline__ void write_hilo(u16* __restrict__ m2, size_t tok, int lane, float v) {
  __hip_bfloat16 hi = __float2bfloat16(v);
  float hif = __bfloat162float(hi);
  __hip_bfloat16 lo = __float2bfloat16(v - hif);
  m2[tok * 128 + lane] = *(u16*)&hi;
  m2[tok * 128 + 64 + lane] = *(u16*)&lo;
}

// ---------------- metric (iter 1) + fused linked-list-heads init; mode derived from pe ----------------
__global__ void metric_in_kernel(const void* __restrict__ x, const void* __restrict__ pos,
                                 u16* __restrict__ m2, int* __restrict__ heads, int nheads) {
  int g = blockIdx.x * 256 + threadIdx.x;
  if (g < nheads) heads[g] = -1;
  int tok = blockIdx.x * 4 + (threadIdx.x >> 6);
  int l = threadIdx.x & 63;
  if (tok >= NB * P0) return;
  int b = tok / P0, t = tok - b * P0;
  int md = ((const uint32_t*)pos)[64] != 0u;
  size_t xrow = ((size_t)b * P0 + t) * C0;
  size_t prow = (size_t)t * C0;
  float4 acc = {0.f, 0.f, 0.f, 0.f};
  if (md) {
#pragma unroll
    for (int hp = 0; hp < 4; ++hp) {
      float4 v = load4(x, xrow + hp * 256 + 4 * l, 1);
      float4 w = load4(pos, prow + hp * 256 + 4 * l, 1);
      acc.x += v.x + w.x; acc.y += v.y + w.y; acc.z += v.z + w.z; acc.w += v.w + w.w;
    }
  } else {
#pragma unroll
    for (int hp = 0; hp < 4; ++hp) {
      float4 v = *(const float4*)((const float*)x + xrow + hp * 256 + 4 * l);
      float4 w = *(const float4*)((const float*)pos + prow + hp * 256 + 4 * l);
      acc.x += v.x + w.x; acc.y += v.y + w.y; acc.z += v.z + w.z; acc.w += v.w + w.w;
    }
  }
#pragma unroll
  for (int mk = 16; mk <= 32; mk <<= 1) {
    acc.x += __shfl_xor(acc.x, mk, 64);
    acc.y += __shfl_xor(acc.y, mk, 64);
    acc.z += __shfl_xor(acc.z, mk, 64);
    acc.w += __shfl_xor(acc.w, mk, 64);
  }
  acc.x *= (1.f / 16.f); acc.y *= (1.f / 16.f); acc.z *= (1.f / 16.f); acc.w *= (1.f / 16.f);
  float sq = acc.x * acc.x + acc.y * acc.y + acc.z * acc.z + acc.w * acc.w;
#pragma unroll
  for (int mk = 1; mk <= 8; mk <<= 1) sq += __shfl_xor(sq, mk, 64);
  if ((l >> 4) == 0) {
    float inv = 1.f / sqrtf(sq);
    int s4 = (l & 15) * 4;
    float vv[4] = {acc.x * inv, acc.y * inv, acc.z * inv, acc.w * inv};
    u16 hw[4], lw[4];
#pragma unroll
    for (int e = 0; e < 4; ++e) {
      __hip_bfloat16 hi = __float2bfloat16(vv[e]);
      float hif = __bfloat162float(hi);
      __hip_bfloat16 lo = __float2bfloat16(vv[e] - hif);
      hw[e] = *(u16*)&hi; lw[e] = *(u16*)&lo;
    }
    ushort4 hi4 = {hw[0], hw[1], hw[2], hw[3]};
    ushort4 lo4 = {lw[0], lw[1], lw[2], lw[3]};
    *(ushort4*)(m2 + (size_t)tok * 128 + s4) = hi4;
    *(ushort4*)(m2 + (size_t)tok * 128 + 64 + s4) = lo4;
  }
}

// ---------------- scores via bf16x4 split-precision MFMA + per-(row, 64-col) argmax partials ----------------
__global__ __launch_bounds__(256) void score_mfma_kernel(const u16* __restrict__ M2,
                                                         int p, int p2, int jT2,
                                                         float* __restrict__ pm,
                                                         int* __restrict__ pi) {
  const int bi = blockIdx.x, ii = blockIdx.y, b = blockIdx.z;
  const int t = threadIdx.x, w = t >> 6, L = t & 63;
  const int wr = w >> 1, wc = w & 1;
  const int fr = L & 15, fo = (L >> 4) * 8;
  const u16* Mb = M2 + (size_t)b * p * 128;

  floatx4 acc[4][4];
#pragma unroll
  for (int mt = 0; mt < 4; ++mt)
#pragma unroll
    for (int nt = 0; nt < 4; ++nt) acc[mt][nt] = (floatx4){0.f, 0.f, 0.f, 0.f};

  const u16* arp[4];
  const u16* brp[4];
#pragma unroll
  for (int mt = 0; mt < 4; ++mt) {
    int i = ii * 128 + wr * 64 + mt * 16 + fr;
    int ta = 2 * i;
    if (ta > p - 2) ta = p - 2;
    arp[mt] = Mb + (size_t)ta * 128 + fo;
    int j = bi * 128 + wc * 64 + mt * 16 + fr;
    int tb = 2 * j + 1;
    if (tb > p - 1) tb = p - 1;
    brp[mt] = Mb + (size_t)tb * 128 + fo;
  }

#pragma unroll
  for (int ks = 0; ks < 2; ++ks) {
    short8 ah[4], al[4], bh[4], bl[4];
#pragma unroll
    for (int mt = 0; mt < 4; ++mt) {
      ah[mt] = *(const short8*)(arp[mt] + ks * 32);
      al[mt] = *(const short8*)(arp[mt] + ks * 32 + 64);
      bh[mt] = *(const short8*)(brp[mt] + ks * 32);
      bl[mt] = *(const short8*)(brp[mt] + ks * 32 + 64);
    }
#pragma unroll
    for (int mt = 0; mt < 4; ++mt)
#pragma unroll
      for (int nt = 0; nt < 4; ++nt) {
        acc[mt][nt] = __builtin_amdgcn_mfma_f32_16x16x32_bf16(ah[mt], bh[nt], acc[mt][nt], 0, 0, 0);
        acc[mt][nt] = __builtin_amdgcn_mfma_f32_16x16x32_bf16(ah[mt], bl[nt], acc[mt][nt], 0, 0, 0);
        acc[mt][nt] = __builtin_amdgcn_mfma_f32_16x16x32_bf16(al[mt], bh[nt], acc[mt][nt], 0, 0, 0);
        acc[mt][nt] = __builtin_amdgcn_mfma_f32_16x16x32_bf16(al[mt], bl[nt], acc[mt][nt], 0, 0, 0);
      }
  }

  const int gi4 = (L >> 4) * 4;
#pragma unroll
  for (int mt = 0; mt < 4; ++mt) {
#pragma unroll
    for (int reg = 0; reg < 4; ++reg) {
      int i = ii * 128 + wr * 64 + mt * 16 + gi4 + reg;
      float bm = -INFINITY;
      int bj = 0x7fffffff;
#pragma unroll
      for (int nt = 0; nt < 4; ++nt) {
        int j = bi * 128 + wc * 64 + nt * 16 + fr;
        float v = acc[mt][nt][reg];
        if (j < p2 && v > bm) { bm = v; bj = j; }
      }
#pragma unroll
      for (int mk = 1; mk < 16; mk <<= 1) {
        float om = __shfl_xor(bm, mk, 64);
        int oj = __shfl_xor(bj, mk, 64);
        if (om > bm || (om == bm && oj < bj)) { bm = om; bj = oj; }
      }
      if (fr == 0 && i < p2) {
        size_t o = ((size_t)b * 2304 + i) * jT2 + bi * 2 + wc;
        pm[o] = bm;
        pi[o] = bj;
      }
    }
  }
}

// argmax combine + build per-destination linked list (head[dst] -> chain via nxt[src])
__global__ void argmax_combine_kernel(const float* __restrict__ pm, const int* __restrict__ pi,
                                      int p2, int jT, int* __restrict__ head,
                                      int* __restrict__ nxt) {
  int g = blockIdx.x * 256 + threadIdx.x;
  if (g >= NB * p2) return;
  int b = g / p2, i = g - b * p2;
  const float* r = pm + ((size_t)b * 2304 + i) * jT;
  const int* ri = pi + ((size_t)b * 2304 + i) * jT;
  float best = r[0];
  int bidx = ri[0];
  for (int k = 1; k < jT; ++k) {
    if (r[k] > best || (r[k] == best && ri[k] < bidx)) { best = r[k]; bidx = ri[k]; }
  }
  int d = bidx;
  if ((unsigned)d >= (unsigned)p2) d = 0;
  nxt[g] = atomicExch(&head[(size_t)b * p2 + d], i);
}

// ---------------- fused merge (gather form) + fused next-iter metric ----------------
__global__ __launch_bounds__(256) void merge_gather_in(const void* __restrict__ x,
                                                       const void* __restrict__ pos,
                                                       const int* __restrict__ head,
                                                       const int* __restrict__ nxt,
                                                       float* __restrict__ xo,
                                                       float* __restrict__ so, int p2,
                                                       u16* __restrict__ m2out) {
  int tj = blockIdx.x;
  int b = tj / p2, j = tj - b * p2;
  int c = threadIdx.x * 4;
  int md = ((const uint32_t*)pos)[64] != 0u;
  __shared__ int sl[64];
  __shared__ int s_n, s_cur;
  __shared__ float mred[16][64];
  size_t xb = ((size_t)b * P0 + 2 * j + 1) * C0 + c;
  size_t pb = (size_t)(2 * j + 1) * C0 + c;
  float4 xa = load4(x, xb, md), pa = load4(pos, pb, md);
  float4 acc = {xa.x + pa.x, xa.y + pa.y, xa.z + pa.z, xa.w + pa.w};
  float cnt = 1.f;
  if (threadIdx.x == 0) s_cur = head[tj];
  __syncthreads();
  int cur = s_cur;
  while (cur != -1) {
    if (threadIdx.x == 0) {
      int n = 0, cc = cur;
      while (cc != -1 && n < 64) {
        sl[n++] = cc;
        cc = nxt[(size_t)b * p2 + cc];
      }
      s_n = n;
      s_cur = cc;
    }
    __syncthreads();
    int n = s_n;
    cur = s_cur;
    for (int k = 0; k < n; ++k) {
      int i = sl[k];
      size_t exb = ((size_t)b * P0 + 2 * i) * C0 + c;
      size_t epb = (size_t)(2 * i) * C0 + c;
      float4 ea = load4(x, exb, md), ep = load4(pos, epb, md);
      acc.x += ea.x + ep.x;
      acc.y += ea.y + ep.y;
      acc.z += ea.z + ep.z;
      acc.w += ea.w + ep.w;
      cnt += 1.f;
    }
    __syncthreads();
  }
  float inv = 1.f / cnt;
  float4 o = {acc.x * inv, acc.y * inv, acc.z * inv, acc.w * inv};
  *(float4*)(xo + (size_t)tj * C0 + c) = o;
  if (threadIdx.x == 0) so[tj] = cnt;
  {
    int hq = threadIdx.x >> 4, dq = (threadIdx.x & 15) * 4;
    mred[hq][dq + 0] = o.x;
    mred[hq][dq + 1] = o.y;
    mred[hq][dq + 2] = o.z;
    mred[hq][dq + 3] = o.w;
  }
  __syncthreads();
  if (threadIdx.x < 64) {
    float s = 0.f;
#pragma unroll
    for (int h = 0; h < 16; ++h) s += mred[h][threadIdx.x];
    s *= (1.f / 16.f);
    float sq = s * s;
#pragma unroll
    for (int off = 1; off < 64; off <<= 1) sq += __shfl_xor(sq, off, 64);
    write_hilo(m2out, (size_t)tj, threadIdx.x, s / sqrtf(sq));
  }
}

__global__ __launch_bounds__(256) void merge_gather_f(const float* __restrict__ xi,
                                                      const float* __restrict__ si,
                                                      const int* __restrict__ head,
                                                      const int* __restrict__ nxt,
                                                      float* __restrict__ xo,
                                                      float* __restrict__ so, int p, int p2,
                                                      u16* __restrict__ m2out) {
  int tj = blockIdx.x;
  int b = tj / p2, j = tj - b * p2;
  int c = threadIdx.x * 4;
  __shared__ int sl[64];
  __shared__ int s_n, s_cur;
  __shared__ float mred[16][64];
  float sz = si[(size_t)b * p + 2 * j + 1];
  float4 v = *(const float4*)(xi + ((size_t)b * p + 2 * j + 1) * C0 + c);
  float4 acc = {v.x * sz, v.y * sz, v.z * sz, v.w * sz};
  float ssum = sz;
  if (threadIdx.x == 0) s_cur = head[tj];
  __syncthreads();
  int cur = s_cur;
  while (cur != -1) {
    if (threadIdx.x == 0) {
      int n = 0, cc = cur;
      while (cc != -1 && n < 64) {
        sl[n++] = cc;
        cc = nxt[(size_t)b * p2 + cc];
      }
      s_n = n;
      s_cur = cc;
    }
    __syncthreads();
    int n = s_n;
    cur = s_cur;
    for (int k = 0; k < n; ++k) {
      int i = sl[k];
      float szi = si[(size_t)b * p + 2 * i];
      float4 e = *(const float4*)(xi + ((size_t)b * p + 2 * i) * C0 + c);
      acc.x += e.x * szi;
      acc.y += e.y * szi;
      acc.z += e.z * szi;
      acc.w += e.w * szi;
      ssum += szi;
    }
    __syncthreads();
  }
  float inv = 1.f / ssum;
  float4 o = {acc.x * inv, acc.y * inv, acc.z * inv, acc.w * inv};
  *(float4*)(xo + (size_t)tj * C0 + c) = o;
  if (threadIdx.x == 0) so[tj] = ssum;
  {
    int hq = threadIdx.x >> 4, dq = (threadIdx.x & 15) * 4;
    mred[hq][dq + 0] = o.x;
    mred[hq][dq + 1] = o.y;
    mred[hq][dq + 2] = o.z;
    mred[hq][dq + 3] = o.w;
  }
  __syncthreads();
  if (threadIdx.x < 64) {
    float s = 0.f;
#pragma unroll
    for (int h = 0; h < 16; ++h) s += mred[h][threadIdx.x];
    s *= (1.f / 16.f);
    float sq = s * s;
#pragma unroll
    for (int off = 1; off < 64; off <<= 1) sq += __shfl_xor(sq, off, 64);
    write_hilo(m2out, (size_t)tj, threadIdx.x, s / sqrtf(sq));
  }
}

// ---------------- iter 6 fused: score (p=144, one block/batch) + combine + stable rank ----------------
__global__ __launch_bounds__(256) void score6_rank_kernel(const u16* __restrict__ M2,
                                                          int* __restrict__ unm_map,
                                                          int* __restrict__ src_ord,
                                                          int* __restrict__ src_dst) {
  const int b = blockIdx.x;
  const int t = threadIdx.x, w = t >> 6, L = t & 63;
  const int wr = w >> 1, wc = w & 1;
  const int fr = L & 15, fo = (L >> 4) * 8;
  const int p = 144, p2 = 72;
  const u16* Mb = M2 + (size_t)b * p * 128;
  __shared__ float smax[2][72];
  __shared__ int sjdx[2][72];

  floatx4 acc[4][4];
#pragma unroll
  for (int mt = 0; mt < 4; ++mt)
#pragma unroll
    for (int nt = 0; nt < 4; ++nt) acc[mt][nt] = (floatx4){0.f, 0.f, 0.f, 0.f};

  const u16* arp[4];
  const u16* brp[4];
#pragma unroll
  for (int mt = 0; mt < 4; ++mt) {
    int i = wr * 64 + mt * 16 + fr;
    int ta = 2 * i;
    if (ta > p - 2) ta = p - 2;
    arp[mt] = Mb + (size_t)ta * 128 + fo;
    int j = wc * 64 + mt * 16 + fr;
    int tb = 2 * j + 1;
    if (tb > p - 1) tb = p - 1;
    brp[mt] = Mb + (size_t)tb * 128 + fo;
  }

#pragma unroll
  for (int ks = 0; ks < 2; ++ks) {
    short8 ah[4], al[4], bh[4], bl[4];
#pragma unroll
    for (int mt = 0; mt < 4; ++mt) {
      ah[mt] = *(const short8*)(arp[mt] + ks * 32);
      al[mt] = *(const short8*)(arp[mt] + ks * 32 + 64);
      bh[mt] = *(const short8*)(brp[mt] + ks * 32);
      bl[mt] = *(const short8*)(brp[mt] + ks * 32 + 64);
    }
#pragma unroll
    for (int mt = 0; mt < 4; ++mt)
#pragma unroll
      for (int nt = 0; nt < 4; ++nt) {
        acc[mt][nt] = __builtin_amdgcn_mfma_f32_16x16x32_bf16(ah[mt], bh[nt], acc[mt][nt], 0, 0, 0);
        acc[mt][nt] = __builtin_amdgcn_mfma_f32_16x16x32_bf16(ah[mt], bl[nt], acc[mt][nt], 0, 0, 0);
        acc[mt][nt] = __builtin_amdgcn_mfma_f32_16x16x32_bf16(al[mt], bh[nt], acc[mt][nt], 0, 0, 0);
        acc[mt][nt] = __builtin_amdgcn_mfma_f32_16x16x32_bf16(al[mt], bl[nt], acc[mt][nt], 0, 0, 0);
      }
  }

  const int gi4 = (L >> 4) * 4;
#pragma unroll
  for (int mt = 0; mt < 4; ++mt) {
#pragma unroll
    for (int reg = 0; reg < 4; ++reg) {
      int i = wr * 64 + mt * 16 + gi4 + reg;
      float bm = -INFINITY;
      int bj = 0x7fffffff;
#pragma unroll
      for (int nt = 0; nt < 4; ++nt) {
        int j = wc * 64 + nt * 16 + fr;
        float v = acc[mt][nt][reg];
        if (j < p2 && v > bm) { bm = v; bj = j; }
      }
#pragma unroll
      for (int mk = 1; mk < 16; mk <<= 1) {
        float om = __shfl_xor(bm, mk, 64);
        int oj = __shfl_xor(bj, mk, 64);
        if (om > bm || (om == bm && oj < bj)) { bm = om; bj = oj; }
      }
      if (fr == 0 && i < p2) {
        smax[wc][i] = bm;
        sjdx[wc][i] = bj;
      }
    }
  }
  __syncthreads();
  // combine the two 64-col partials (same order/tie-break as argmax_combine with jT=2)
  if (t < 72) {
    float best = smax[0][t];
    int bidx = sjdx[0][t];
    float b1v = smax[1][t];
    int b1i = sjdx[1][t];
    if (b1v > best || (b1v == best && b1i < bidx)) { best = b1v; bidx = b1i; }
    smax[0][t] = best;
    sjdx[0][t] = bidx;
  }
  __syncthreads();
  if (t < 72) {
    float vi = smax[0][t];
    int rank = 0;
    for (int k = 0; k < 72; ++k) {
      float vk = smax[0][k];
      rank += (vk > vi) || (vk == vi && k < t);
    }
    if (rank < 16) {
      int d = sjdx[0][t];
      if ((unsigned)d >= 72u) d = 0;
      src_ord[b * 16 + rank] = t;
      src_dst[b * 16 + rank] = d;
    } else {
      unm_map[b * 56 + (rank - 16)] = t;
    }
  }
}

// ---------------- fused final gather: init + merge (scan 16-entry src table) + div + bf16 cvt ----------------
__global__ __launch_bounds__(256) void final_gather(const float* __restrict__ x5,
                                                    const float* __restrict__ s5,
                                                    const int* __restrict__ unm_map,
                                                    const int* __restrict__ src_ord,
                                                    const int* __restrict__ src_dst,
                                                    __hip_bfloat16* __restrict__ xb) {
  int bt = blockIdx.x;
  int b = bt >> 7, tk = bt & 127;
  int c = threadIdx.x * 4;
  __shared__ int sord[16], sdst[16];
  if (threadIdx.x < 16) {
    sord[threadIdx.x] = src_ord[b * 16 + threadIdx.x];
    sdst[threadIdx.x] = src_dst[b * 16 + threadIdx.x];
  }
  __syncthreads();
  float4 o;
  if (tk < 56) {
    int se = unm_map[b * 56 + tk];
    if ((unsigned)se >= 72u) se = 0;
    o = *(const float4*)(x5 + ((size_t)b * 144 + 2 * se) * C0 + c);
  } else {
    int j = tk - 56;
    float sz = s5[b * 144 + 2 * j + 1];
    float4 v = *(const float4*)(x5 + ((size_t)b * 144 + 2 * j + 1) * C0 + c);
    float4 acc = {v.x * sz, v.y * sz, v.z * sz, v.w * sz};
    float ssum = sz;
#pragma unroll
    for (int k = 0; k < 16; ++k) {
      if (sdst[k] == j) {
        int st = sord[k];
        if ((unsigned)st >= 72u) st = 0;
        float szi = s5[b * 144 + 2 * st];
        float4 e = *(const float4*)(x5 + ((size_t)b * 144 + 2 * st) * C0 + c);
        acc.x += e.x * szi;
        acc.y += e.y * szi;
        acc.z += e.z * szi;
        acc.w += e.w * szi;
        ssum += szi;
      }
    }
    float inv = 1.f / ssum;
    o.x = acc.x * inv; o.y = acc.y * inv; o.z = acc.z * inv; o.w = acc.w * inv;
  }
  __hip_bfloat16* op = xb + (size_t)bt * C0 + c;
  op[0] = __float2bfloat16(o.x);
  op[1] = __float2bfloat16(o.y);
  op[2] = __float2bfloat16(o.z);
  op[3] = __float2bfloat16(o.w);
}

// ---------------- fused dual-weight transpose (KxN -> NxK), output bf16 ----------------
__global__ void transpose_both(const void* __restrict__ W1, const void* __restrict__ W2,
                               const uint32_t* __restrict__ pe_w, u16* __restrict__ w1t,
                               u16* __restrict__ w2t) {
  __shared__ u16 tile[64][65];
  int md = pe_w[64] != 0u;
  const void* in;
  u16* out;
  int K, k0;
  int n0 = blockIdx.x * 64;
  if (blockIdx.y < 16) {
    in = W1; out = w1t; K = 1024; k0 = blockIdx.y * 64;
  } else {
    in = W2; out = w2t; K = 4096; k0 = (blockIdx.y - 16) * 64;
  }
  const int N = 4096;
  int t = threadIdx.x;
  int r = t >> 4, c4 = (t & 15) * 4;
  if (md) {
#pragma unroll
    for (int pass = 0; pass < 4; ++pass) {
      int row = r + pass * 16;
      ushort4 u = *(const ushort4*)((const u16*)in + (size_t)(k0 + row) * N + n0 + c4);
      tile[row][c4 + 0] = u.x;
      tile[row][c4 + 1] = u.y;
      tile[row][c4 + 2] = u.z;
      tile[row][c4 + 3] = u.w;
    }
  } else {
#pragma unroll
    for (int pass = 0; pass < 4; ++pass) {
      int row = r + pass * 16;
      float4 v = *(const float4*)((const float*)in + (size_t)(k0 + row) * N + n0 + c4);
      __hip_bfloat16 b0 = __float2bfloat16(v.x), b1 = __float2bfloat16(v.y);
      __hip_bfloat16 b2 = __float2bfloat16(v.z), b3 = __float2bfloat16(v.w);
      tile[row][c4 + 0] = *(u16*)&b0;
      tile[row][c4 + 1] = *(u16*)&b1;
      tile[row][c4 + 2] = *(u16*)&b2;
      tile[row][c4 + 3] = *(u16*)&b3;
    }
  }
  __syncthreads();
#pragma unroll
  for (int pass = 0; pass < 4; ++pass) {
    int row = r + pass * 16;
    ushort4 o;
    o.x = tile[c4][row]; o.y = tile[c4 + 1][row]; o.z = tile[c4 + 2][row]; o.w = tile[c4 + 3][row];
    *(ushort4*)(out + (size_t)(n0 + row) * K + k0 + c4) = o;
  }
}

// ---------------- bf16 MFMA GEMM, B pre-transposed (NT), 64x128 tile ----------------
// 3-stage dbuf, 2 tiles prefetched ahead, counted vmcnt(12/6/0) + XOR LDS swizzle via
// pre-swizzled global source (rule-21) + setprio.
#define GL2LDS(gp, lp)                                                                   \
  __builtin_amdgcn_global_load_lds((const __attribute__((address_space(1))) uint32_t*)(gp), \
                                   (__attribute__((address_space(3))) uint32_t*)(lp), 16, 0, 0)

__global__ __launch_bounds__(256, 2) void gemm_bt(const u16* __restrict__ A,
                                                  const u16* __restrict__ BT,
                                                  const void* __restrict__ bias,
                                                  const uint32_t* __restrict__ pe_w,
                                                  void* __restrict__ C, int M, int N,
                                                  int K, int act, int out_sel) {
  __shared__ __align__(16) u16 As[3 * 64 * 64];
  __shared__ __align__(16) u16 Bs[3 * 128 * 64];
  const int t = threadIdx.x, w = t >> 6, L = t & 63;
  const int m0 = blockIdx.y * 64, n0 = blockIdx.x * 128;
  const int wr = w >> 1, wc = w & 1;
  const int md = pe_w[64] != 0u;
  const int fr = L & 15;
  floatx4 acc[2][4];
#pragma unroll
  for (int a = 0; a < 2; ++a)
#pragma unroll
    for (int bb = 0; bb < 4; ++bb) acc[a][bb] = (floatx4){0.f, 0.f, 0.f, 0.f};

  auto stage = [&](int buf, int kk) {
#pragma unroll
    for (int q = 0; q < 2; ++q) {
      int g = q * 256 + t;
      int row = g >> 3, colg = (g & 7) ^ (row & 7);
      GL2LDS(A + (size_t)(m0 + row) * K + kk + colg * 8, As + buf * 4096 + g * 8);
    }
#pragma unroll
    for (int q = 0; q < 4; ++q) {
      int g = q * 256 + t;
      int row = g >> 3, colg = (g & 7) ^ (row & 7);
      GL2LDS(BT + (size_t)(n0 + row) * K + kk + colg * 8, Bs + buf * 8192 + g * 8);
    }
  };

  const int NT = K >> 6;
  stage(0, 0);
  stage(1, 64);  // 12 loads in flight
  int cur = 0;
  for (int it = 0; it < NT; ++it) {
    if (it + 2 < NT) {
      int b2 = cur + 2;
      if (b2 >= 3) b2 -= 3;
      stage(b2, (it + 2) << 6);                          // +6 loads
      asm volatile("s_waitcnt vmcnt(12)" ::: "memory");  // tile it landed; it+1/it+2 fly on
    } else if (it + 1 < NT) {
      asm volatile("s_waitcnt vmcnt(6)" ::: "memory");
    } else {
      asm volatile("s_waitcnt vmcnt(0)" ::: "memory");
    }
    __builtin_amdgcn_s_barrier();  // all waves: current tile LDS complete
    const u16* Ab = As + cur * 4096;
    const u16* Bb = Bs + cur * 8192;
    __builtin_amdgcn_s_setprio(1);
#pragma unroll
    for (int kh = 0; kh < 2; ++kh) {
      short8 af[2], bfr[4];
#pragma unroll
      for (int mt = 0; mt < 2; ++mt) {
        int ra = wr * 32 + mt * 16 + fr;
        int cg = (kh * 4 + (L >> 4)) ^ (ra & 7);
        af[mt] = *(const short8*)(Ab + ra * 64 + cg * 8);
      }
#pragma unroll
      for (int nt = 0; nt < 4; ++nt) {
        int rb = wc * 64 + nt * 16 + fr;
        int cg = (kh * 4 + (L >> 4)) ^ (rb & 7);
        bfr[nt] = *(const short8*)(Bb + rb * 64 + cg * 8);
      }
#pragma unroll
      for (int mt = 0; mt < 2; ++mt)
#pragma unroll
        for (int nt = 0; nt < 4; ++nt)
          acc[mt][nt] =
              __builtin_amdgcn_mfma_f32_16x16x32_bf16(af[mt], bfr[nt], acc[mt][nt], 0, 0, 0);
    }
    __builtin_amdgcn_s_setprio(0);
    __builtin_amdgcn_s_barrier();  // done reading cur -> it+2 staging may overwrite it-1's buf
    cur = (cur + 1 == 3) ? 0 : cur + 1;
  }
  const int gi4 = (L >> 4) * 4;
#pragma unroll
  for (int mt = 0; mt < 2; ++mt)
#pragma unroll
    for (int nt = 0; nt < 4; ++nt) {
      int n = n0 + wc * 64 + nt * 16 + fr;
      float bz = load_in(bias, n, md);
#pragma unroll
      for (int rr = 0; rr < 4; ++rr) {
        int m = m0 + wr * 32 + mt * 16 + gi4 + rr;
        float v = acc[mt][nt][rr] + bz;
        if (act) v = 0.5f * v * (1.f + erff(v * 0.70710678118654752f));
        size_t idx = (size_t)m * N + n;
        if (out_sel == 0 || md) {
          __hip_bfloat16 bv = __float2bfloat16(v);
          ((u16*)C)[idx] = *(u16*)&bv;
        } else {
          ((float*)C)[idx] = v;
        }
      }
    }
}

// ---------------- host ----------------
extern "C" void kernel_launch(void* const* d_in, const int* in_sizes, int n_in, void* d_out,
                              int out_size, void* d_ws, size_t ws_size, hipStream_t stream) {
  const void* x = d_in[0];
  const void* pe = d_in[1];
  const void* W1 = d_in[2];
  const void* b1 = d_in[3];
  const void* W2 = d_in[4];
  const void* b2 = d_in[5];

  char* base = (char*)d_ws;
  size_t off = 0;
  auto alloc = [&](size_t bytes) -> void* {
    void* p = base + off;
    off += (bytes + 255) & ~(size_t)255;
    return p;
  };
  u16* m2 = (u16*)alloc((size_t)NB * 4608 * 128 * 2);  // bf16 hi/lo split metric
  float* pm = (float*)alloc((size_t)NB * 2304 * 36 * 4);
  int* pi = (int*)alloc((size_t)NB * 2304 * 36 * 4);
  float* bufA = (float*)alloc((size_t)NB * 2304 * C0 * 4);
  float* bufB = (float*)alloc((size_t)NB * 1152 * C0 * 4);
  float* s1 = (float*)alloc((size_t)NB * 2304 * 4);
  float* s2 = (float*)alloc((size_t)NB * 1152 * 4);
  float* s3 = (float*)alloc((size_t)NB * 576 * 4);
  float* s4 = (float*)alloc((size_t)NB * 288 * 4);
  float* s5 = (float*)alloc((size_t)NB * 144 * 4);
  int* unm_map = (int*)alloc((size_t)NB * 56 * 4);
  int* src_ord = (int*)alloc((size_t)NB * 16 * 4);
  int* src_dst = (int*)alloc((size_t)NB * 16 * 4);
  u16* xfb = (u16*)alloc((size_t)NB * 128 * C0 * 2);
  u16* hbuf = (u16*)alloc((size_t)1024 * H0 * 2);
  u16* w1t = (u16*)alloc((size_t)H0 * C0 * 2);
  u16* w2t = (u16*)alloc((size_t)H0 * H0 * 2);
  // linked-list buffers: heads per iteration (2304+1152+576+288 = 4320 +144... iters 1-5 = 4464)
  int* heads = (int*)alloc((size_t)NB * 4464 * 4);
  int* nxt = (int*)alloc((size_t)NB * 2304 * 4);
  if (off > ws_size) return;

  int* h_it[5];
  h_it[0] = heads;
  h_it[1] = h_it[0] + NB * 2304;
  h_it[2] = h_it[1] + NB * 1152;
  h_it[3] = h_it[2] + NB * 576;
  h_it[4] = h_it[3] + NB * 288;

  float* x1 = bufA;
  float* x2 = bufB;
  float* x3 = bufA;
  float* x4 = bufB;
  float* x5 = bufA;

  // ---- iter 1: p=4608 -> p2=2304 (metric fuses heads-init; mode derived from pe everywhere)
  metric_in_kernel<<<NB * P0 / 4, 256, 0, stream>>>(x, pe, m2, heads, NB * 4464);
  score_mfma_kernel<<<dim3(18, 18, NB), 256, 0, stream>>>(m2, 4608, 2304, 36, pm, pi);
  argmax_combine_kernel<<<(NB * 2304 + 255) / 256, 256, 0, stream>>>(pm, pi, 2304, 36,
                                                                     h_it[0], nxt);
  merge_gather_in<<<NB * 2304, 256, 0, stream>>>(x, pe, h_it[0], nxt, x1, s1, 2304, m2);

  // ---- iters 2..5 (generic all-evens-merge); metric fused into the previous gather
  float* xs_in[4] = {x1, x2, x3, x4};
  float* ss_in[4] = {s1, s2, s3, s4};
  float* xs_out[4] = {x2, x3, x4, x5};
  float* ss_out[4] = {s2, s3, s4, s5};
  int ps[5] = {2304, 1152, 576, 288, 144};
  for (int it = 0; it < 4; ++it) {
    int p = ps[it], p2 = ps[it + 1];
    int iT = (p2 + 127) / 128, jT = (p2 + 127) / 128;
    score_mfma_kernel<<<dim3(jT, iT, NB), 256, 0, stream>>>(m2, p, p2, 2 * jT, pm, pi);
    argmax_combine_kernel<<<(NB * p2 + 255) / 256, 256, 0, stream>>>(pm, pi, p2, 2 * jT,
                                                                     h_it[it + 1], nxt);
    merge_gather_f<<<NB * p2, 256, 0, stream>>>(xs_in[it], ss_in[it], h_it[it + 1], nxt,
                                                xs_out[it], ss_out[it], p, p2, m2);
  }

  // ---- iter 6: fused score+combine+rank (one block per batch), then fused final gather
  score6_rank_kernel<<<NB, 256, 0, stream>>>(m2, unm_map, src_ord, src_dst);
  final_gather<<<NB * 128, 256, 0, stream>>>(x5, s5, unm_map, src_ord, src_dst,
                                             (__hip_bfloat16*)xfb);

  // ---- weight transposes (late: w1t/w2t stay L2/L3-warm for the GEMMs)
  transpose_both<<<dim3(64, 80), 256, 0, stream>>>(W1, W2, (const uint32_t*)pe, w1t, w2t);

  // ---- MLP: h = gelu(x@W1 + b1); out = h@W2 + b2
  gemm_bt<<<dim3(4096 / 128, 1024 / 64), 256, 0, stream>>>(xfb, w1t, b1, (const uint32_t*)pe,
                                                           hbuf, 1024, 4096, 1024, 1, 0);
  gemm_bt<<<dim3(4096 / 128, 1024 / 64), 256, 0, stream>>>(hbuf, w2t, b2, (const uint32_t*)pe,
                                                           d_out, 1024, 4096, 4096, 0, 1);
}